// Round 1
// baseline (2935.758 us; speedup 1.0000x reference)
//
#include <hip/hip_runtime.h>
#include <hip/hip_bf16.h>
#include <cmath>

// Problem constants (match reference)
constexpr int IN_DIM = 184;
constexpr int HID    = 64;
constexpr int HEADS  = 4;
constexpr int F1     = HEADS * HID;   // 256
constexpr float SLOPE = 0.2f;
constexpr float LN_EPS = 1e-5f;

// ---- float <-> monotone unsigned mapping for atomicMax on floats ----
__device__ inline unsigned f2ord(float f) {
    unsigned u = __float_as_uint(f);
    return (u & 0x80000000u) ? ~u : (u | 0x80000000u);
}
__device__ inline float ord2f(unsigned u) {
    return (u & 0x80000000u) ? __uint_as_float(u & 0x7fffffffu) : __uint_as_float(~u);
}

// ---------------- GEMM: Y[M,NC] = X[M,K] @ W[K,NC] (+bias) ----------------
template<int K, int NC, bool BIAS>
__global__ __launch_bounds__(256) void gemm_k(const float* __restrict__ X,
                                              const float* __restrict__ W,
                                              const float* __restrict__ bias,
                                              float* __restrict__ Y, int M) {
    constexpr int ROWS = 256 / NC;          // nodes per block
    __shared__ float xs[ROWS][K];
    int base = blockIdx.x * ROWS;
    for (int i = threadIdx.x; i < ROWS * K; i += 256) {
        int rr = i / K, kk = i - rr * K;
        int gr = base + rr;
        xs[rr][kk] = (gr < M) ? X[(size_t)gr * K + kk] : 0.f;
    }
    __syncthreads();
    int rloc = threadIdx.x / NC;
    int c    = threadIdx.x % NC;
    int r    = base + rloc;
    if (r >= M) return;
    float acc = BIAS ? bias[c] : 0.f;
#pragma unroll 8
    for (int k = 0; k < K; ++k) acc = fmaf(xs[rloc][k], W[k * NC + c], acc);
    Y[(size_t)r * NC + c] = acc;
}

// ---------------- attention logits for H=4, C=64 (one block per node) ----------------
__global__ __launch_bounds__(256) void attn_logits(const float* __restrict__ feat,
                                                   const float* __restrict__ as_,
                                                   const float* __restrict__ ad_,
                                                   float* __restrict__ als,
                                                   float* __restrict__ ald) {
    int n = blockIdx.x;
    int t = threadIdx.x;
    int w = t >> 6, l = t & 63;
    float f  = feat[(size_t)n * F1 + t];
    float vs = f * as_[t];   // as[h][c] laid out h*64+c == t
    float vd = f * ad_[t];
    for (int off = 32; off; off >>= 1) {
        vs += __shfl_down(vs, off);
        vd += __shfl_down(vd, off);
    }
    if (l == 0) { als[n * HEADS + w] = vs; ald[n * HEADS + w] = vd; }
}

// ---------------- edge helpers ----------------
__device__ inline void edge_sd(const int* __restrict__ ei, int E, int idx, int& s, int& d) {
    if (idx < E) { s = ei[idx]; d = ei[E + idx]; }
    else         { s = idx - E; d = idx - E; }     // self loops appended
}

template<int H>
__global__ __launch_bounds__(256) void edge_max(const int* __restrict__ ei, int E, int Etot,
                                                const float* __restrict__ als,
                                                const float* __restrict__ ald,
                                                unsigned* __restrict__ m) {
    int idx = blockIdx.x * 256 + threadIdx.x;
    if (idx >= Etot) return;
    int s, d; edge_sd(ei, E, idx, s, d);
#pragma unroll
    for (int h = 0; h < H; ++h) {
        float e = als[s * H + h] + ald[d * H + h];
        e = e > 0.f ? e : SLOPE * e;
        atomicMax(&m[d * H + h], f2ord(e));
    }
}

template<int H>
__global__ __launch_bounds__(256) void edge_exp(const int* __restrict__ ei, int E, int Etot,
                                                const float* __restrict__ als,
                                                const float* __restrict__ ald,
                                                const unsigned* __restrict__ m,
                                                float* __restrict__ den,
                                                float* __restrict__ exb) {
    int idx = blockIdx.x * 256 + threadIdx.x;
    if (idx >= Etot) return;
    int s, d; edge_sd(ei, E, idx, s, d);
#pragma unroll
    for (int h = 0; h < H; ++h) {
        float e = als[s * H + h] + ald[d * H + h];
        e = e > 0.f ? e : SLOPE * e;
        float ex = expf(e - ord2f(m[d * H + h]));
        exb[(size_t)idx * H + h] = ex;
        atomicAdd(&den[d * H + h], ex);
    }
}

// one block (256 threads) per edge; 256 features
__global__ __launch_bounds__(256) void scatter256(const int* __restrict__ ei, int E,
                                                  const float* __restrict__ feat,
                                                  const float* __restrict__ exb,
                                                  const float* __restrict__ den,
                                                  float* __restrict__ O) {
    int idx = blockIdx.x;
    int t = threadIdx.x;
    int s, d; edge_sd(ei, E, idx, s, d);
    int h = t >> 6;
    float alpha = exb[(size_t)idx * HEADS + h] / (den[d * HEADS + h] + 1e-16f);
    atomicAdd(&O[(size_t)d * F1 + t], feat[(size_t)s * F1 + t] * alpha);
}

// layer2 scatter: thread per edge, 2 features
__global__ __launch_bounds__(256) void scatter2(const int* __restrict__ ei, int E, int Etot,
                                                const float* __restrict__ f2,
                                                const float* __restrict__ exb,
                                                const float* __restrict__ den,
                                                float* __restrict__ out) {
    int idx = blockIdx.x * 256 + threadIdx.x;
    if (idx >= Etot) return;
    int s, d; edge_sd(ei, E, idx, s, d);
    float alpha = exb[idx] / (den[d] + 1e-16f);
    atomicAdd(&out[(size_t)d * 2 + 0], f2[(size_t)s * 2 + 0] * alpha);
    atomicAdd(&out[(size_t)d * 2 + 1], f2[(size_t)s * 2 + 1] * alpha);
}

// ---------------- LayerNorm(+bias in)(+residual)+ELU, one block per row ----------------
template<bool RES>
__global__ __launch_bounds__(256) void ln_elu(const float* __restrict__ O,
                                              const float* __restrict__ bias,
                                              const float* __restrict__ g,
                                              const float* __restrict__ bln,
                                              const float* __restrict__ res,
                                              float* __restrict__ out) {
    int n = blockIdx.x, t = threadIdx.x;
    int w = t >> 6, l = t & 63;
    __shared__ float sred[4];
    float v = O[(size_t)n * F1 + t] + bias[t];
    float s = v;
    for (int off = 32; off; off >>= 1) s += __shfl_down(s, off);
    if (l == 0) sred[w] = s;
    __syncthreads();
    float mu = (sred[0] + sred[1] + sred[2] + sred[3]) * (1.f / F1);
    __syncthreads();
    float dv = (v - mu) * (v - mu);
    for (int off = 32; off; off >>= 1) dv += __shfl_down(dv, off);
    if (l == 0) sred[w] = dv;
    __syncthreads();
    float var = (sred[0] + sred[1] + sred[2] + sred[3]) * (1.f / F1);
    float y = (v - mu) * rsqrtf(var + LN_EPS) * g[t] + bln[t];
    if (RES) y += res[(size_t)n * F1 + t];
    out[(size_t)n * F1 + t] = y > 0.f ? y : expm1f(y);
}

// ---------------- layer2 features + logits (block per node) ----------------
__global__ __launch_bounds__(256) void feat2_logits(const float* __restrict__ Hin,
                                                    const float* __restrict__ W2,
                                                    const float* __restrict__ as2,
                                                    const float* __restrict__ ad2,
                                                    float* __restrict__ f2,
                                                    float* __restrict__ als,
                                                    float* __restrict__ ald) {
    int n = blockIdx.x, t = threadIdx.x;
    int w = t >> 6, l = t & 63;
    __shared__ float s0[4], s1[4];
    float hv = Hin[(size_t)n * F1 + t];
    float c0 = hv * W2[t * 2 + 0];
    float c1 = hv * W2[t * 2 + 1];
    for (int off = 32; off; off >>= 1) {
        c0 += __shfl_down(c0, off);
        c1 += __shfl_down(c1, off);
    }
    if (l == 0) { s0[w] = c0; s1[w] = c1; }
    __syncthreads();
    if (t == 0) {
        float f0 = s0[0] + s0[1] + s0[2] + s0[3];
        float f1 = s1[0] + s1[1] + s1[2] + s1[3];
        f2[(size_t)n * 2 + 0] = f0;
        f2[(size_t)n * 2 + 1] = f1;
        als[n] = f0 * as2[0] + f1 * as2[1];
        ald[n] = f0 * ad2[0] + f1 * ad2[1];
    }
}

__global__ __launch_bounds__(256) void init_out(float* __restrict__ out,
                                                const float* __restrict__ b2, int n2) {
    int i = blockIdx.x * 256 + threadIdx.x;
    if (i < n2) out[i] = b2[i & 1];
}

extern "C" void kernel_launch(void* const* d_in, const int* in_sizes, int n_in,
                              void* d_out, int out_size, void* d_ws, size_t ws_size,
                              hipStream_t stream) {
    const float* x    = (const float*)d_in[0];
    const int*   ei   = (const int*)d_in[1];
    const float* Wp   = (const float*)d_in[2];
    const float* bp   = (const float*)d_in[3];
    const float* W0   = (const float*)d_in[4];
    const float* as0  = (const float*)d_in[5];
    const float* ad0  = (const float*)d_in[6];
    const float* b0   = (const float*)d_in[7];
    const float* W1   = (const float*)d_in[8];
    const float* as1  = (const float*)d_in[9];
    const float* ad1  = (const float*)d_in[10];
    const float* b1   = (const float*)d_in[11];
    const float* W2   = (const float*)d_in[12];
    const float* as2  = (const float*)d_in[13];
    const float* ad2  = (const float*)d_in[14];
    const float* b2   = (const float*)d_in[15];
    const float* ln_g = (const float*)d_in[16];
    const float* ln_b = (const float*)d_in[17];
    float* out = (float*)d_out;

    const int N    = in_sizes[0] / IN_DIM;   // 50000
    const int E    = in_sizes[1] / 2;        // 800000
    const int Etot = E + N;                  // self loops appended

    // -------- workspace carve --------
    char* wptr = (char*)d_ws;
    auto alloc = [&](size_t bytes) -> void* {
        void* p = wptr;
        wptr += (bytes + 255) & ~(size_t)255;
        return p;
    };
    float*    P   = (float*)alloc(sizeof(float) * (size_t)N * HID);
    float*    F   = (float*)alloc(sizeof(float) * (size_t)N * F1);
    float*    O   = (float*)alloc(sizeof(float) * (size_t)N * F1);
    float*    A   = (float*)alloc(sizeof(float) * (size_t)N * F1);
    float*    als = (float*)alloc(sizeof(float) * (size_t)N * HEADS);
    float*    ald = (float*)alloc(sizeof(float) * (size_t)N * HEADS);
    float*    den = (float*)alloc(sizeof(float) * (size_t)N * HEADS);
    unsigned* mbf = (unsigned*)alloc(sizeof(unsigned) * (size_t)N * HEADS);
    float*    exb = (float*)alloc(sizeof(float) * (size_t)Etot * HEADS);
    float*    f2  = (float*)alloc(sizeof(float) * (size_t)N * 2);

    const int eb = (Etot + 255) / 256;

    // -------- input projection: P = x @ Wp + bp --------
    gemm_k<IN_DIM, HID, true><<<(N + 3) / 4, 256, 0, stream>>>(x, Wp, bp, P, N);

    // ================= layer 0 =================
    gemm_k<HID, F1, false><<<N, 256, 0, stream>>>(P, W0, nullptr, F, N);
    attn_logits<<<N, 256, 0, stream>>>(F, as0, ad0, als, ald);
    hipMemsetAsync(mbf, 0, sizeof(unsigned) * (size_t)N * HEADS, stream);
    hipMemsetAsync(den, 0, sizeof(float) * (size_t)N * HEADS, stream);
    hipMemsetAsync(O,   0, sizeof(float) * (size_t)N * F1, stream);
    edge_max<HEADS><<<eb, 256, 0, stream>>>(ei, E, Etot, als, ald, mbf);
    edge_exp<HEADS><<<eb, 256, 0, stream>>>(ei, E, Etot, als, ald, mbf, den, exb);
    scatter256<<<Etot, 256, 0, stream>>>(ei, E, F, exb, den, O);
    ln_elu<false><<<N, 256, 0, stream>>>(O, b0, ln_g, ln_b, nullptr, A);

    // ================= layer 1 =================
    gemm_k<F1, F1, false><<<N, 256, 0, stream>>>(A, W1, nullptr, F, N);
    attn_logits<<<N, 256, 0, stream>>>(F, as1, ad1, als, ald);
    hipMemsetAsync(mbf, 0, sizeof(unsigned) * (size_t)N * HEADS, stream);
    hipMemsetAsync(den, 0, sizeof(float) * (size_t)N * HEADS, stream);
    hipMemsetAsync(O,   0, sizeof(float) * (size_t)N * F1, stream);
    edge_max<HEADS><<<eb, 256, 0, stream>>>(ei, E, Etot, als, ald, mbf);
    edge_exp<HEADS><<<eb, 256, 0, stream>>>(ei, E, Etot, als, ald, mbf, den, exb);
    scatter256<<<Etot, 256, 0, stream>>>(ei, E, F, exb, den, O);
    ln_elu<true><<<N, 256, 0, stream>>>(O, b1, ln_g, ln_b, A, F);   // result -> F

    // ================= layer 2 (heads=1, C=2) =================
    feat2_logits<<<N, 256, 0, stream>>>(F, W2, as2, ad2, f2, als, ald);
    hipMemsetAsync(mbf, 0, sizeof(unsigned) * (size_t)N, stream);
    hipMemsetAsync(den, 0, sizeof(float) * (size_t)N, stream);
    init_out<<<(2 * N + 255) / 256, 256, 0, stream>>>(out, b2, 2 * N);
    edge_max<1><<<eb, 256, 0, stream>>>(ei, E, Etot, als, ald, mbf);
    edge_exp<1><<<eb, 256, 0, stream>>>(ei, E, Etot, als, ald, mbf, den, exb);
    scatter2<<<eb, 256, 0, stream>>>(ei, E, Etot, f2, exb, den, out);
}

// Round 2
// 922.449 us; speedup vs baseline: 3.1826x; 3.1826x over previous
//
#include <hip/hip_runtime.h>
#include <hip/hip_bf16.h>
#include <cmath>

constexpr int IN_DIM = 184;
constexpr int HID    = 64;
constexpr int HEADS  = 4;
constexpr int F1     = HEADS * HID;   // 256
constexpr float SLOPE = 0.2f;
constexpr float LN_EPS = 1e-5f;

// ---------------- generic small GEMM (used for input projection) ----------------
template<int K, int NC, bool BIAS>
__global__ __launch_bounds__(256) void gemm_k(const float* __restrict__ X,
                                              const float* __restrict__ W,
                                              const float* __restrict__ bias,
                                              float* __restrict__ Y, int M) {
    constexpr int ROWS = 256 / NC;
    __shared__ float xs[ROWS][K];
    int base = blockIdx.x * ROWS;
    for (int i = threadIdx.x; i < ROWS * K; i += 256) {
        int rr = i / K, kk = i - rr * K;
        int gr = base + rr;
        xs[rr][kk] = (gr < M) ? X[(size_t)gr * K + kk] : 0.f;
    }
    __syncthreads();
    int rloc = threadIdx.x / NC;
    int c    = threadIdx.x % NC;
    int r    = base + rloc;
    if (r >= M) return;
    float acc = BIAS ? bias[c] : 0.f;
#pragma unroll 8
    for (int k = 0; k < K; ++k) acc = fmaf(xs[rloc][k], W[k * NC + c], acc);
    Y[(size_t)r * NC + c] = acc;
}

// ---------------- GEMM NC=256, 8 rows per block ----------------
template<int K>
__global__ __launch_bounds__(256) void gemm256(const float* __restrict__ X,
                                               const float* __restrict__ W,
                                               float* __restrict__ Y, int M) {
    __shared__ __align__(16) float xs[8][K];
    int base = blockIdx.x * 8;
    for (int i = threadIdx.x; i < 8 * K; i += 256) {
        int r = i / K, k = i - r * K;
        int gr = base + r;
        xs[r][k] = (gr < M) ? X[(size_t)gr * K + k] : 0.f;
    }
    __syncthreads();
    int c = threadIdx.x;
    float acc[8] = {0, 0, 0, 0, 0, 0, 0, 0};
    const float4 (*xs4)[K / 4] = reinterpret_cast<const float4 (*)[K / 4]>(xs);
    for (int k4 = 0; k4 < K / 4; ++k4) {
        int k = k4 * 4;
        float w0 = W[(size_t)(k + 0) * 256 + c];
        float w1 = W[(size_t)(k + 1) * 256 + c];
        float w2 = W[(size_t)(k + 2) * 256 + c];
        float w3 = W[(size_t)(k + 3) * 256 + c];
#pragma unroll
        for (int r = 0; r < 8; ++r) {
            float4 xv = xs4[r][k4];
            acc[r] = fmaf(xv.x, w0, acc[r]);
            acc[r] = fmaf(xv.y, w1, acc[r]);
            acc[r] = fmaf(xv.z, w2, acc[r]);
            acc[r] = fmaf(xv.w, w3, acc[r]);
        }
    }
    for (int r = 0; r < 8; ++r) {
        int gr = base + r;
        if (gr < M) Y[(size_t)gr * 256 + c] = acc[r];
    }
}

// ---------------- attention logits H=4,C=64 ----------------
__global__ __launch_bounds__(256) void attn_logits(const float* __restrict__ feat,
                                                   const float* __restrict__ as_,
                                                   const float* __restrict__ ad_,
                                                   float* __restrict__ als,
                                                   float* __restrict__ ald) {
    int n = blockIdx.x;
    int t = threadIdx.x;
    int w = t >> 6, l = t & 63;
    float f  = feat[(size_t)n * F1 + t];
    float vs = f * as_[t];
    float vd = f * ad_[t];
    for (int off = 32; off; off >>= 1) {
        vs += __shfl_down(vs, off);
        vd += __shfl_down(vd, off);
    }
    if (l == 0) { als[n * HEADS + w] = vs; ald[n * HEADS + w] = vd; }
}

// ---------------- CSR build ----------------
__device__ inline void edge_sd(const int* __restrict__ ei, int E, int idx, int& s, int& d) {
    if (idx < E) { s = ei[idx]; d = ei[E + idx]; }
    else         { s = idx - E; d = idx - E; }
}

__global__ __launch_bounds__(256) void csr_count(const int* __restrict__ ei, int E, int Etot,
                                                 int* __restrict__ deg) {
    int idx = blockIdx.x * 256 + threadIdx.x;
    if (idx >= Etot) return;
    int s, d; edge_sd(ei, E, idx, s, d);
    atomicAdd(&deg[d], 1);
}

// inclusive scan, 1024 elems per block (256 threads x 4)
__global__ __launch_bounds__(256) void scan1(const int* __restrict__ deg, int* __restrict__ out,
                                             int* __restrict__ csum, int N) {
    __shared__ int s[256];
    int t = threadIdx.x;
    int base = blockIdx.x * 1024;
    int idx0 = base + t * 4;
    int v[4];
#pragma unroll
    for (int i = 0; i < 4; ++i) { int id = idx0 + i; v[i] = (id < N) ? deg[id] : 0; }
    int sum = v[0] + v[1] + v[2] + v[3];
    s[t] = sum; __syncthreads();
    for (int off = 1; off < 256; off <<= 1) {
        int x = (t >= off) ? s[t - off] : 0;
        __syncthreads();
        s[t] += x;
        __syncthreads();
    }
    int run = (t == 0) ? 0 : s[t - 1];
#pragma unroll
    for (int i = 0; i < 4; ++i) {
        run += v[i];
        int id = idx0 + i;
        if (id < N) out[id] = run;
    }
    if (t == 255) csum[blockIdx.x] = s[255];
}

__global__ __launch_bounds__(256) void scan2(int* __restrict__ csum, int M) {
    __shared__ int s[256];
    int t = threadIdx.x;
    s[t] = (t < M) ? csum[t] : 0;
    __syncthreads();
    for (int off = 1; off < 256; off <<= 1) {
        int x = (t >= off) ? s[t - off] : 0;
        __syncthreads();
        s[t] += x;
        __syncthreads();
    }
    if (t < M) csum[t] = s[t];
}

// add chunk offsets -> rend (inclusive); also wcur = rend - deg (row start)
__global__ __launch_bounds__(256) void scan3(const int* __restrict__ deg, int* __restrict__ rend,
                                             const int* __restrict__ csum, int* __restrict__ wcur, int N) {
    int id = blockIdx.x * 256 + threadIdx.x;
    if (id >= N) return;
    int chunk = id >> 10;
    int off = (chunk == 0) ? 0 : csum[chunk - 1];
    int e = rend[id] + off;
    rend[id] = e;
    wcur[id] = e - deg[id];
}

__global__ __launch_bounds__(256) void csr_fill(const int* __restrict__ ei, int E, int Etot,
                                                int* __restrict__ wcur, int* __restrict__ csr_src) {
    int idx = blockIdx.x * 256 + threadIdx.x;
    if (idx >= Etot) return;
    int s, d; edge_sd(ei, E, idx, s, d);
    int pos = atomicAdd(&wcur[d], 1);
    csr_src[pos] = s;
}

// ---------------- per-node softmax (H=4), wave per node ----------------
__global__ __launch_bounds__(256) void node_softmax4(const int* __restrict__ csr_src,
                                                     const int* __restrict__ rend,
                                                     const int* __restrict__ deg,
                                                     const float* __restrict__ als,
                                                     const float* __restrict__ ald,
                                                     float* __restrict__ exb,
                                                     float* __restrict__ invden, int N) {
    int n = blockIdx.x * 4 + (threadIdx.x >> 6);
    int l = threadIdx.x & 63;
    if (n >= N) return;
    int end = rend[n], dg = deg[n], start = end - dg;
    const float4 ad4 = reinterpret_cast<const float4*>(ald)[n];
    float m0 = -3.4e38f, m1 = -3.4e38f, m2 = -3.4e38f, m3 = -3.4e38f;
    for (int i = l; i < dg; i += 64) {
        int s = csr_src[start + i];
        float4 a = reinterpret_cast<const float4*>(als)[s];
        float e0 = a.x + ad4.x; e0 = e0 > 0.f ? e0 : SLOPE * e0;
        float e1 = a.y + ad4.y; e1 = e1 > 0.f ? e1 : SLOPE * e1;
        float e2 = a.z + ad4.z; e2 = e2 > 0.f ? e2 : SLOPE * e2;
        float e3 = a.w + ad4.w; e3 = e3 > 0.f ? e3 : SLOPE * e3;
        m0 = fmaxf(m0, e0); m1 = fmaxf(m1, e1); m2 = fmaxf(m2, e2); m3 = fmaxf(m3, e3);
    }
    for (int off = 32; off; off >>= 1) {
        m0 = fmaxf(m0, __shfl_xor(m0, off));
        m1 = fmaxf(m1, __shfl_xor(m1, off));
        m2 = fmaxf(m2, __shfl_xor(m2, off));
        m3 = fmaxf(m3, __shfl_xor(m3, off));
    }
    float s0 = 0.f, s1 = 0.f, s2 = 0.f, s3 = 0.f;
    for (int i = l; i < dg; i += 64) {
        int s = csr_src[start + i];
        float4 a = reinterpret_cast<const float4*>(als)[s];
        float e0 = a.x + ad4.x; e0 = e0 > 0.f ? e0 : SLOPE * e0;
        float e1 = a.y + ad4.y; e1 = e1 > 0.f ? e1 : SLOPE * e1;
        float e2 = a.z + ad4.z; e2 = e2 > 0.f ? e2 : SLOPE * e2;
        float e3 = a.w + ad4.w; e3 = e3 > 0.f ? e3 : SLOPE * e3;
        float4 ex = { expf(e0 - m0), expf(e1 - m1), expf(e2 - m2), expf(e3 - m3) };
        reinterpret_cast<float4*>(exb)[start + i] = ex;
        s0 += ex.x; s1 += ex.y; s2 += ex.z; s3 += ex.w;
    }
    for (int off = 32; off; off >>= 1) {
        s0 += __shfl_xor(s0, off);
        s1 += __shfl_xor(s1, off);
        s2 += __shfl_xor(s2, off);
        s3 += __shfl_xor(s3, off);
    }
    if (l == 0) {
        float4 iv = { 1.f / (s0 + 1e-16f), 1.f / (s1 + 1e-16f),
                      1.f / (s2 + 1e-16f), 1.f / (s3 + 1e-16f) };
        reinterpret_cast<float4*>(invden)[n] = iv;
    }
}

// ---------------- per-node softmax (H=1), wave per node ----------------
__global__ __launch_bounds__(256) void node_softmax1(const int* __restrict__ csr_src,
                                                     const int* __restrict__ rend,
                                                     const int* __restrict__ deg,
                                                     const float* __restrict__ als,
                                                     const float* __restrict__ ald,
                                                     float* __restrict__ exb,
                                                     float* __restrict__ invden, int N) {
    int n = blockIdx.x * 4 + (threadIdx.x >> 6);
    int l = threadIdx.x & 63;
    if (n >= N) return;
    int end = rend[n], dg = deg[n], start = end - dg;
    float ad = ald[n];
    float m = -3.4e38f;
    for (int i = l; i < dg; i += 64) {
        int s = csr_src[start + i];
        float e = als[s] + ad; e = e > 0.f ? e : SLOPE * e;
        m = fmaxf(m, e);
    }
    for (int off = 32; off; off >>= 1) m = fmaxf(m, __shfl_xor(m, off));
    float sum = 0.f;
    for (int i = l; i < dg; i += 64) {
        int s = csr_src[start + i];
        float e = als[s] + ad; e = e > 0.f ? e : SLOPE * e;
        float ex = expf(e - m);
        exb[start + i] = ex;
        sum += ex;
    }
    for (int off = 32; off; off >>= 1) sum += __shfl_xor(sum, off);
    if (l == 0) invden[n] = 1.f / (sum + 1e-16f);
}

// ---------------- aggregate (block per node) + bias + LN + ELU (+res) ----------------
template<bool RES>
__global__ __launch_bounds__(256) void aggregate_ln(const int* __restrict__ csr_src,
                                                    const int* __restrict__ rend,
                                                    const int* __restrict__ deg,
                                                    const float* __restrict__ feat,
                                                    const float* __restrict__ exb,
                                                    const float* __restrict__ invden,
                                                    const float* __restrict__ bias,
                                                    const float* __restrict__ g,
                                                    const float* __restrict__ bln,
                                                    const float* __restrict__ res,
                                                    float* __restrict__ out, int N) {
    int n = blockIdx.x;
    int t = threadIdx.x;
    int h = t >> 6, l = t & 63;
    int end = rend[n], dg = deg[n], start = end - dg;
    float iv = invden[n * HEADS + h];
    float acc = 0.f;
    for (int c0 = start; c0 < end; c0 += 64) {
        int cnt = min(64, end - c0);
        int sp = 0; float ap = 0.f;
        if (l < cnt) {
            sp = csr_src[c0 + l];
            ap = exb[(size_t)(c0 + l) * HEADS + h] * iv;
        }
        int i = 0;
        for (; i + 4 <= cnt; i += 4) {
            int   s0 = __shfl(sp, i),     s1 = __shfl(sp, i + 1);
            int   s2 = __shfl(sp, i + 2), s3 = __shfl(sp, i + 3);
            float a0 = __shfl(ap, i),     a1 = __shfl(ap, i + 1);
            float a2 = __shfl(ap, i + 2), a3 = __shfl(ap, i + 3);
            float f0 = feat[(size_t)s0 * F1 + t];
            float f1 = feat[(size_t)s1 * F1 + t];
            float f2 = feat[(size_t)s2 * F1 + t];
            float f3 = feat[(size_t)s3 * F1 + t];
            acc = fmaf(f0, a0, acc);
            acc = fmaf(f1, a1, acc);
            acc = fmaf(f2, a2, acc);
            acc = fmaf(f3, a3, acc);
        }
        for (; i < cnt; ++i) {
            int   s = __shfl(sp, i);
            float a = __shfl(ap, i);
            acc = fmaf(feat[(size_t)s * F1 + t], a, acc);
        }
    }
    __shared__ float sred[4];
    float v = acc + bias[t];
    float sm = v;
    for (int off = 32; off; off >>= 1) sm += __shfl_down(sm, off);
    if (l == 0) sred[h] = sm;
    __syncthreads();
    float mu = (sred[0] + sred[1] + sred[2] + sred[3]) * (1.f / F1);
    __syncthreads();
    float dv = (v - mu) * (v - mu);
    for (int off = 32; off; off >>= 1) dv += __shfl_down(dv, off);
    if (l == 0) sred[h] = dv;
    __syncthreads();
    float var = (sred[0] + sred[1] + sred[2] + sred[3]) * (1.f / F1);
    float y = (v - mu) * rsqrtf(var + LN_EPS) * g[t] + bln[t];
    if (RES) y += res[(size_t)n * F1 + t];
    out[(size_t)n * F1 + t] = y > 0.f ? y : expm1f(y);
}

// ---------------- layer2 features + logits ----------------
__global__ __launch_bounds__(256) void feat2_logits(const float* __restrict__ Hin,
                                                    const float* __restrict__ W2,
                                                    const float* __restrict__ as2,
                                                    const float* __restrict__ ad2,
                                                    float* __restrict__ f2,
                                                    float* __restrict__ als,
                                                    float* __restrict__ ald) {
    int n = blockIdx.x, t = threadIdx.x;
    int w = t >> 6, l = t & 63;
    __shared__ float s0[4], s1[4];
    float hv = Hin[(size_t)n * F1 + t];
    float c0 = hv * W2[t * 2 + 0];
    float c1 = hv * W2[t * 2 + 1];
    for (int off = 32; off; off >>= 1) {
        c0 += __shfl_down(c0, off);
        c1 += __shfl_down(c1, off);
    }
    if (l == 0) { s0[w] = c0; s1[w] = c1; }
    __syncthreads();
    if (t == 0) {
        float f0 = s0[0] + s0[1] + s0[2] + s0[3];
        float f1 = s1[0] + s1[1] + s1[2] + s1[3];
        f2[(size_t)n * 2 + 0] = f0;
        f2[(size_t)n * 2 + 1] = f1;
        als[n] = f0 * as2[0] + f1 * as2[1];
        ald[n] = f0 * ad2[0] + f1 * ad2[1];
    }
}

// ---------------- layer2 aggregation: wave per node, 2 features ----------------
__global__ __launch_bounds__(256) void aggregate2(const int* __restrict__ csr_src,
                                                  const int* __restrict__ rend,
                                                  const int* __restrict__ deg,
                                                  const float* __restrict__ f2,
                                                  const float* __restrict__ exb,
                                                  const float* __restrict__ invden,
                                                  const float* __restrict__ b2,
                                                  float* __restrict__ out, int N) {
    int n = blockIdx.x * 4 + (threadIdx.x >> 6);
    int l = threadIdx.x & 63;
    if (n >= N) return;
    int end = rend[n], dg = deg[n], start = end - dg;
    float iv = invden[n];
    float a0 = 0.f, a1 = 0.f;
    for (int i = l; i < dg; i += 64) {
        int s = csr_src[start + i];
        float a = exb[start + i] * iv;
        float2 f = reinterpret_cast<const float2*>(f2)[s];
        a0 = fmaf(f.x, a, a0);
        a1 = fmaf(f.y, a, a1);
    }
    for (int off = 32; off; off >>= 1) {
        a0 += __shfl_xor(a0, off);
        a1 += __shfl_xor(a1, off);
    }
    if (l == 0) {
        out[(size_t)n * 2 + 0] = a0 + b2[0];
        out[(size_t)n * 2 + 1] = a1 + b2[1];
    }
}

extern "C" void kernel_launch(void* const* d_in, const int* in_sizes, int n_in,
                              void* d_out, int out_size, void* d_ws, size_t ws_size,
                              hipStream_t stream) {
    const float* x    = (const float*)d_in[0];
    const int*   ei   = (const int*)d_in[1];
    const float* Wp   = (const float*)d_in[2];
    const float* bp   = (const float*)d_in[3];
    const float* W0   = (const float*)d_in[4];
    const float* as0  = (const float*)d_in[5];
    const float* ad0  = (const float*)d_in[6];
    const float* b0   = (const float*)d_in[7];
    const float* W1   = (const float*)d_in[8];
    const float* as1  = (const float*)d_in[9];
    const float* ad1  = (const float*)d_in[10];
    const float* b1   = (const float*)d_in[11];
    const float* W2   = (const float*)d_in[12];
    const float* as2  = (const float*)d_in[13];
    const float* ad2  = (const float*)d_in[14];
    const float* b2   = (const float*)d_in[15];
    const float* ln_g = (const float*)d_in[16];
    const float* ln_b = (const float*)d_in[17];
    float* out = (float*)d_out;

    const int N    = in_sizes[0] / IN_DIM;   // 50000
    const int E    = in_sizes[1] / 2;        // 800000
    const int Etot = E + N;

    // -------- workspace carve --------
    char* wptr = (char*)d_ws;
    auto alloc = [&](size_t bytes) -> void* {
        void* p = wptr;
        wptr += (bytes + 255) & ~(size_t)255;
        return p;
    };
    float* P      = (float*)alloc(sizeof(float) * (size_t)N * HID);
    float* F      = (float*)alloc(sizeof(float) * (size_t)N * F1);
    float* A      = (float*)alloc(sizeof(float) * (size_t)N * F1);   // layer0 out
    float* H2     = (float*)alloc(sizeof(float) * (size_t)N * F1);   // layer1 out
    float* als    = (float*)alloc(sizeof(float) * (size_t)N * HEADS);
    float* ald    = (float*)alloc(sizeof(float) * (size_t)N * HEADS);
    float* invden = (float*)alloc(sizeof(float) * (size_t)N * HEADS);
    float* exb    = (float*)alloc(sizeof(float) * (size_t)Etot * HEADS);
    float* f2     = (float*)alloc(sizeof(float) * (size_t)N * 2);
    int*   deg    = (int*)alloc(sizeof(int) * (size_t)N);
    int*   rend   = (int*)alloc(sizeof(int) * (size_t)N);
    int*   wcur   = (int*)alloc(sizeof(int) * (size_t)N);
    int*   csum   = (int*)alloc(sizeof(int) * 256);
    int*   csrs   = (int*)alloc(sizeof(int) * (size_t)Etot);

    const int eb  = (Etot + 255) / 256;
    const int nb  = (N + 255) / 256;
    const int nb4 = (N + 3) / 4;
    const int nchunks = (N + 1023) / 1024;

    // -------- CSR build (once, reused for all 3 layers) --------
    hipMemsetAsync(deg, 0, sizeof(int) * (size_t)N, stream);
    csr_count<<<eb, 256, 0, stream>>>(ei, E, Etot, deg);
    scan1<<<nchunks, 256, 0, stream>>>(deg, rend, csum, N);
    scan2<<<1, 256, 0, stream>>>(csum, nchunks);
    scan3<<<nb, 256, 0, stream>>>(deg, rend, csum, wcur, N);
    csr_fill<<<eb, 256, 0, stream>>>(ei, E, Etot, wcur, csrs);

    // -------- input projection --------
    gemm_k<IN_DIM, HID, true><<<(N + 3) / 4, 256, 0, stream>>>(x, Wp, bp, P, N);

    // ================= layer 0 =================
    gemm256<HID><<<(N + 7) / 8, 256, 0, stream>>>(P, W0, F, N);
    attn_logits<<<N, 256, 0, stream>>>(F, as0, ad0, als, ald);
    node_softmax4<<<nb4, 256, 0, stream>>>(csrs, rend, deg, als, ald, exb, invden, N);
    aggregate_ln<false><<<N, 256, 0, stream>>>(csrs, rend, deg, F, exb, invden,
                                               b0, ln_g, ln_b, nullptr, A, N);

    // ================= layer 1 =================
    gemm256<F1><<<(N + 7) / 8, 256, 0, stream>>>(A, W1, F, N);
    attn_logits<<<N, 256, 0, stream>>>(F, as1, ad1, als, ald);
    node_softmax4<<<nb4, 256, 0, stream>>>(csrs, rend, deg, als, ald, exb, invden, N);
    aggregate_ln<true><<<N, 256, 0, stream>>>(csrs, rend, deg, F, exb, invden,
                                              b1, ln_g, ln_b, A, H2, N);

    // ================= layer 2 (heads=1, C=2) =================
    feat2_logits<<<N, 256, 0, stream>>>(H2, W2, as2, ad2, f2, als, ald);
    node_softmax1<<<nb4, 256, 0, stream>>>(csrs, rend, deg, als, ald, exb, invden, N);
    aggregate2<<<nb4, 256, 0, stream>>>(csrs, rend, deg, f2, exb, invden, b2, out, N);
}

// Round 4
// 683.337 us; speedup vs baseline: 4.2962x; 1.3499x over previous
//
#include <hip/hip_runtime.h>
#include <hip/hip_bf16.h>
#include <cmath>

constexpr int IN_DIM = 184;
constexpr int HID    = 64;
constexpr int HEADS  = 4;
constexpr int F1     = HEADS * HID;   // 256
constexpr float SLOPE = 0.2f;
constexpr float LN_EPS = 1e-5f;

// ================= tiled f32 GEMM =================
// Y[M,N] = X[M,K] @ W[K,N] (+bias). BM=64, BN=64, BK=32; 256 thr, 4x4/thread.
// LOGITS: N==256, blockIdx.y==head h; epilogue computes
//   als[n*4+h] = sum_c Y[n][h*64+c]*as[h][c], ald likewise (no atomics).
template<bool BIAS, bool LOGITS>
__global__ __launch_bounds__(256) void gemm_tile(const float* __restrict__ X,
                                                 const float* __restrict__ W,
                                                 const float* __restrict__ bias,
                                                 const float* __restrict__ as_,
                                                 const float* __restrict__ ad_,
                                                 float* __restrict__ Y,
                                                 float* __restrict__ als,
                                                 float* __restrict__ ald,
                                                 int M, int N, int K) {
    __shared__ __align__(16) float xs[32][68];   // k-major, padded
    __shared__ __align__(16) float ws[32][68];
    const int row0 = blockIdx.x * 64;
    const int n0   = blockIdx.y * 64;
    const int tid  = threadIdx.x;
    const int tx   = tid & 15, ty = tid >> 4;

    float acc[4][4] = {};

    for (int k0 = 0; k0 < K; k0 += 32) {
        // stage X tile (transposed to k-major)
        for (int i = tid; i < 64 * 32; i += 256) {
            int r = i >> 5, kk = i & 31;
            int gr = row0 + r, gk = k0 + kk;
            xs[kk][r] = (gr < M && gk < K) ? X[(size_t)gr * K + gk] : 0.f;
        }
        // stage W tile
        for (int i = tid; i < 32 * 64; i += 256) {
            int kk = i >> 6, c = i & 63;
            int gk = k0 + kk;
            ws[kk][c] = (gk < K) ? W[(size_t)gk * N + n0 + c] : 0.f;
        }
        __syncthreads();
#pragma unroll 4
        for (int kk = 0; kk < 32; ++kk) {
            float4 xv = *(const float4*)&xs[kk][ty * 4];
            float4 wv = *(const float4*)&ws[kk][tx * 4];
            acc[0][0] = fmaf(xv.x, wv.x, acc[0][0]);
            acc[0][1] = fmaf(xv.x, wv.y, acc[0][1]);
            acc[0][2] = fmaf(xv.x, wv.z, acc[0][2]);
            acc[0][3] = fmaf(xv.x, wv.w, acc[0][3]);
            acc[1][0] = fmaf(xv.y, wv.x, acc[1][0]);
            acc[1][1] = fmaf(xv.y, wv.y, acc[1][1]);
            acc[1][2] = fmaf(xv.y, wv.z, acc[1][2]);
            acc[1][3] = fmaf(xv.y, wv.w, acc[1][3]);
            acc[2][0] = fmaf(xv.z, wv.x, acc[2][0]);
            acc[2][1] = fmaf(xv.z, wv.y, acc[2][1]);
            acc[2][2] = fmaf(xv.z, wv.z, acc[2][2]);
            acc[2][3] = fmaf(xv.z, wv.w, acc[2][3]);
            acc[3][0] = fmaf(xv.w, wv.x, acc[3][0]);
            acc[3][1] = fmaf(xv.w, wv.y, acc[3][1]);
            acc[3][2] = fmaf(xv.w, wv.z, acc[3][2]);
            acc[3][3] = fmaf(xv.w, wv.w, acc[3][3]);
        }
        __syncthreads();
    }

    float bv[4];
#pragma unroll
    for (int j = 0; j < 4; ++j) bv[j] = BIAS ? bias[n0 + tx * 4 + j] : 0.f;

#pragma unroll
    for (int i = 0; i < 4; ++i) {
        int gr = row0 + ty * 4 + i;
        if (gr < M) {
            float4 o = { acc[i][0] + bv[0], acc[i][1] + bv[1],
                         acc[i][2] + bv[2], acc[i][3] + bv[3] };
            *(float4*)&Y[(size_t)gr * N + n0 + tx * 4] = o;
        }
    }

    if (LOGITS) {
        const int h = blockIdx.y;
        float asv[4], adv[4];
#pragma unroll
        for (int j = 0; j < 4; ++j) {
            asv[j] = as_[h * 64 + tx * 4 + j];
            adv[j] = ad_[h * 64 + tx * 4 + j];
        }
#pragma unroll
        for (int i = 0; i < 4; ++i) {
            float ls = acc[i][0] * asv[0] + acc[i][1] * asv[1] +
                       acc[i][2] * asv[2] + acc[i][3] * asv[3];
            float ld = acc[i][0] * adv[0] + acc[i][1] * adv[1] +
                       acc[i][2] * adv[2] + acc[i][3] * adv[3];
            for (int off = 8; off; off >>= 1) {   // reduce over tx (16 lanes)
                ls += __shfl_xor(ls, off);
                ld += __shfl_xor(ld, off);
            }
            int gr = row0 + ty * 4 + i;
            if (tx == 0 && gr < M) {
                als[gr * HEADS + h] = ls;
                ald[gr * HEADS + h] = ld;
            }
        }
    }
}

// ---------------- CSR build ----------------
__device__ inline void edge_sd(const int* __restrict__ ei, int E, int idx, int& s, int& d) {
    if (idx < E) { s = ei[idx]; d = ei[E + idx]; }
    else         { s = idx - E; d = idx - E; }
}

__global__ __launch_bounds__(256) void csr_count(const int* __restrict__ ei, int E, int Etot,
                                                 int* __restrict__ deg) {
    int idx = blockIdx.x * 256 + threadIdx.x;
    if (idx >= Etot) return;
    int s, d; edge_sd(ei, E, idx, s, d);
    atomicAdd(&deg[d], 1);
}

__global__ __launch_bounds__(256) void scan1(const int* __restrict__ deg, int* __restrict__ out,
                                             int* __restrict__ csum, int N) {
    __shared__ int s[256];
    int t = threadIdx.x;
    int idx0 = blockIdx.x * 1024 + t * 4;
    int v[4];
#pragma unroll
    for (int i = 0; i < 4; ++i) { int id = idx0 + i; v[i] = (id < N) ? deg[id] : 0; }
    int sum = v[0] + v[1] + v[2] + v[3];
    s[t] = sum; __syncthreads();
    for (int off = 1; off < 256; off <<= 1) {
        int x = (t >= off) ? s[t - off] : 0;
        __syncthreads();
        s[t] += x;
        __syncthreads();
    }
    int run = (t == 0) ? 0 : s[t - 1];
#pragma unroll
    for (int i = 0; i < 4; ++i) {
        run += v[i];
        int id = idx0 + i;
        if (id < N) out[id] = run;
    }
    if (t == 255) csum[blockIdx.x] = s[255];
}

__global__ __launch_bounds__(256) void scan2(int* __restrict__ csum, int M) {
    __shared__ int s[256];
    int t = threadIdx.x;
    s[t] = (t < M) ? csum[t] : 0;
    __syncthreads();
    for (int off = 1; off < 256; off <<= 1) {
        int x = (t >= off) ? s[t - off] : 0;
        __syncthreads();
        s[t] += x;
        __syncthreads();
    }
    if (t < M) csum[t] = s[t];
}

__global__ __launch_bounds__(256) void scan3(const int* __restrict__ deg, int* __restrict__ rend,
                                             const int* __restrict__ csum, int* __restrict__ wcur, int N) {
    int id = blockIdx.x * 256 + threadIdx.x;
    if (id >= N) return;
    int chunk = id >> 10;
    int off = (chunk == 0) ? 0 : csum[chunk - 1];
    int e = rend[id] + off;
    rend[id] = e;
    wcur[id] = e - deg[id];
}

__global__ __launch_bounds__(256) void csr_fill(const int* __restrict__ ei, int E, int Etot,
                                                int* __restrict__ wcur, int* __restrict__ csr_src) {
    int idx = blockIdx.x * 256 + threadIdx.x;
    if (idx >= Etot) return;
    int s, d; edge_sd(ei, E, idx, s, d);
    int pos = atomicAdd(&wcur[d], 1);
    csr_src[pos] = s;
}

// ---------------- per-node softmax (H=4), wave per node ----------------
__global__ __launch_bounds__(256) void node_softmax4(const int* __restrict__ csr_src,
                                                     const int* __restrict__ rend,
                                                     const int* __restrict__ deg,
                                                     const float* __restrict__ als,
                                                     const float* __restrict__ ald,
                                                     float* __restrict__ exb,
                                                     float* __restrict__ invden, int N) {
    int n = blockIdx.x * 4 + (threadIdx.x >> 6);
    int l = threadIdx.x & 63;
    if (n >= N) return;
    int end = rend[n], dg = deg[n], start = end - dg;
    const float4 ad4 = reinterpret_cast<const float4*>(ald)[n];
    float m0 = -3.4e38f, m1 = -3.4e38f, m2 = -3.4e38f, m3 = -3.4e38f;
    for (int i = l; i < dg; i += 64) {
        int s = csr_src[start + i];
        float4 a = reinterpret_cast<const float4*>(als)[s];
        float e0 = a.x + ad4.x; e0 = e0 > 0.f ? e0 : SLOPE * e0;
        float e1 = a.y + ad4.y; e1 = e1 > 0.f ? e1 : SLOPE * e1;
        float e2 = a.z + ad4.z; e2 = e2 > 0.f ? e2 : SLOPE * e2;
        float e3 = a.w + ad4.w; e3 = e3 > 0.f ? e3 : SLOPE * e3;
        m0 = fmaxf(m0, e0); m1 = fmaxf(m1, e1); m2 = fmaxf(m2, e2); m3 = fmaxf(m3, e3);
    }
    for (int off = 32; off; off >>= 1) {
        m0 = fmaxf(m0, __shfl_xor(m0, off));
        m1 = fmaxf(m1, __shfl_xor(m1, off));
        m2 = fmaxf(m2, __shfl_xor(m2, off));
        m3 = fmaxf(m3, __shfl_xor(m3, off));
    }
    float s0 = 0.f, s1 = 0.f, s2 = 0.f, s3 = 0.f;
    for (int i = l; i < dg; i += 64) {
        int s = csr_src[start + i];
        float4 a = reinterpret_cast<const float4*>(als)[s];
        float e0 = a.x + ad4.x; e0 = e0 > 0.f ? e0 : SLOPE * e0;
        float e1 = a.y + ad4.y; e1 = e1 > 0.f ? e1 : SLOPE * e1;
        float e2 = a.z + ad4.z; e2 = e2 > 0.f ? e2 : SLOPE * e2;
        float e3 = a.w + ad4.w; e3 = e3 > 0.f ? e3 : SLOPE * e3;
        float4 ex = { expf(e0 - m0), expf(e1 - m1), expf(e2 - m2), expf(e3 - m3) };
        reinterpret_cast<float4*>(exb)[start + i] = ex;
        s0 += ex.x; s1 += ex.y; s2 += ex.z; s3 += ex.w;
    }
    for (int off = 32; off; off >>= 1) {
        s0 += __shfl_xor(s0, off);
        s1 += __shfl_xor(s1, off);
        s2 += __shfl_xor(s2, off);
        s3 += __shfl_xor(s3, off);
    }
    if (l == 0) {
        float4 iv = { 1.f / (s0 + 1e-16f), 1.f / (s1 + 1e-16f),
                      1.f / (s2 + 1e-16f), 1.f / (s3 + 1e-16f) };
        reinterpret_cast<float4*>(invden)[n] = iv;
    }
}

// ---------------- per-node softmax (H=1) ----------------
__global__ __launch_bounds__(256) void node_softmax1(const int* __restrict__ csr_src,
                                                     const int* __restrict__ rend,
                                                     const int* __restrict__ deg,
                                                     const float* __restrict__ als,
                                                     const float* __restrict__ ald,
                                                     float* __restrict__ exb,
                                                     float* __restrict__ invden, int N) {
    int n = blockIdx.x * 4 + (threadIdx.x >> 6);
    int l = threadIdx.x & 63;
    if (n >= N) return;
    int end = rend[n], dg = deg[n], start = end - dg;
    float ad = ald[n];
    float m = -3.4e38f;
    for (int i = l; i < dg; i += 64) {
        int s = csr_src[start + i];
        float e = als[s] + ad; e = e > 0.f ? e : SLOPE * e;
        m = fmaxf(m, e);
    }
    for (int off = 32; off; off >>= 1) m = fmaxf(m, __shfl_xor(m, off));
    float sum = 0.f;
    for (int i = l; i < dg; i += 64) {
        int s = csr_src[start + i];
        float e = als[s] + ad; e = e > 0.f ? e : SLOPE * e;
        float ex = expf(e - m);
        exb[start + i] = ex;
        sum += ex;
    }
    for (int off = 32; off; off >>= 1) sum += __shfl_xor(sum, off);
    if (l == 0) invden[n] = 1.f / (sum + 1e-16f);
}

// -------- aggregate (block per node) + bias + LN (+res) + ELU; optional layer2 fusion --------
template<bool RES, bool FEAT2>
__global__ __launch_bounds__(256) void aggregate_ln(const int* __restrict__ csr_src,
                                                    const int* __restrict__ rend,
                                                    const int* __restrict__ deg,
                                                    const float* __restrict__ feat,
                                                    const float* __restrict__ exb,
                                                    const float* __restrict__ invden,
                                                    const float* __restrict__ bias,
                                                    const float* __restrict__ g,
                                                    const float* __restrict__ bln,
                                                    const float* __restrict__ res,
                                                    float* __restrict__ out,
                                                    const float* __restrict__ W2,
                                                    const float* __restrict__ as2,
                                                    const float* __restrict__ ad2,
                                                    float* __restrict__ f2,
                                                    float* __restrict__ als2,
                                                    float* __restrict__ ald2,
                                                    int N) {
    int n = blockIdx.x;
    int t = threadIdx.x;
    int h = t >> 6, l = t & 63;
    int end = rend[n], dg = deg[n], start = end - dg;
    float iv = invden[n * HEADS + h];
    float acc = 0.f;
    for (int c0 = start; c0 < end; c0 += 64) {
        int cnt = min(64, end - c0);
        int sp = 0; float ap = 0.f;
        if (l < cnt) {
            sp = csr_src[c0 + l];
            ap = exb[(size_t)(c0 + l) * HEADS + h] * iv;
        }
        int i = 0;
        for (; i + 4 <= cnt; i += 4) {
            int   s0 = __shfl(sp, i),     s1 = __shfl(sp, i + 1);
            int   s2 = __shfl(sp, i + 2), s3 = __shfl(sp, i + 3);
            float a0 = __shfl(ap, i),     a1 = __shfl(ap, i + 1);
            float a2 = __shfl(ap, i + 2), a3 = __shfl(ap, i + 3);
            float f0 = feat[(size_t)s0 * F1 + t];
            float f1 = feat[(size_t)s1 * F1 + t];
            float fv2 = feat[(size_t)s2 * F1 + t];
            float f3 = feat[(size_t)s3 * F1 + t];
            acc = fmaf(f0, a0, acc);
            acc = fmaf(f1, a1, acc);
            acc = fmaf(fv2, a2, acc);
            acc = fmaf(f3, a3, acc);
        }
        for (; i < cnt; ++i) {
            int   s = __shfl(sp, i);
            float a = __shfl(ap, i);
            acc = fmaf(feat[(size_t)s * F1 + t], a, acc);
        }
    }
    __shared__ float sred[4];
    __shared__ float s20[4], s21[4];
    float v = acc + bias[t];
    float sm = v;
    for (int off = 32; off; off >>= 1) sm += __shfl_down(sm, off);
    if (l == 0) sred[h] = sm;
    __syncthreads();
    float mu = (sred[0] + sred[1] + sred[2] + sred[3]) * (1.f / F1);
    __syncthreads();
    float dv = (v - mu) * (v - mu);
    for (int off = 32; off; off >>= 1) dv += __shfl_down(dv, off);
    if (l == 0) sred[h] = dv;
    __syncthreads();
    float var = (sred[0] + sred[1] + sred[2] + sred[3]) * (1.f / F1);
    float y = (v - mu) * rsqrtf(var + LN_EPS) * g[t] + bln[t];
    if (RES) y += res[(size_t)n * F1 + t];
    y = y > 0.f ? y : expm1f(y);
    if (!FEAT2) {
        out[(size_t)n * F1 + t] = y;
    } else {
        float c0 = y * W2[t * 2 + 0];
        float c1 = y * W2[t * 2 + 1];
        for (int off = 32; off; off >>= 1) {
            c0 += __shfl_down(c0, off);
            c1 += __shfl_down(c1, off);
        }
        if (l == 0) { s20[h] = c0; s21[h] = c1; }
        __syncthreads();
        if (t == 0) {
            float f0 = s20[0] + s20[1] + s20[2] + s20[3];
            float f1 = s21[0] + s21[1] + s21[2] + s21[3];
            f2[(size_t)n * 2 + 0] = f0;
            f2[(size_t)n * 2 + 1] = f1;
            als2[n] = f0 * as2[0] + f1 * as2[1];
            ald2[n] = f0 * ad2[0] + f1 * ad2[1];
        }
    }
}

// ---------------- layer2 aggregation: wave per node, 2 features ----------------
__global__ __launch_bounds__(256) void aggregate2(const int* __restrict__ csr_src,
                                                  const int* __restrict__ rend,
                                                  const int* __restrict__ deg,
                                                  const float* __restrict__ f2,
                                                  const float* __restrict__ exb,
                                                  const float* __restrict__ invden,
                                                  const float* __restrict__ b2,
                                                  float* __restrict__ out, int N) {
    int n = blockIdx.x * 4 + (threadIdx.x >> 6);
    int l = threadIdx.x & 63;
    if (n >= N) return;
    int end = rend[n], dg = deg[n], start = end - dg;
    float iv = invden[n];
    float a0 = 0.f, a1 = 0.f;
    for (int i = l; i < dg; i += 64) {
        int s = csr_src[start + i];
        float a = exb[start + i] * iv;
        float2 f = reinterpret_cast<const float2*>(f2)[s];
        a0 = fmaf(f.x, a, a0);
        a1 = fmaf(f.y, a, a1);
    }
    for (int off = 32; off; off >>= 1) {
        a0 += __shfl_xor(a0, off);
        a1 += __shfl_xor(a1, off);
    }
    if (l == 0) {
        out[(size_t)n * 2 + 0] = a0 + b2[0];
        out[(size_t)n * 2 + 1] = a1 + b2[1];
    }
}

extern "C" void kernel_launch(void* const* d_in, const int* in_sizes, int n_in,
                              void* d_out, int out_size, void* d_ws, size_t ws_size,
                              hipStream_t stream) {
    const float* x    = (const float*)d_in[0];
    const int*   ei   = (const int*)d_in[1];
    const float* Wp   = (const float*)d_in[2];
    const float* bp   = (const float*)d_in[3];
    const float* W0   = (const float*)d_in[4];
    const float* as0  = (const float*)d_in[5];
    const float* ad0  = (const float*)d_in[6];
    const float* b0   = (const float*)d_in[7];
    const float* W1   = (const float*)d_in[8];
    const float* as1  = (const float*)d_in[9];
    const float* ad1  = (const float*)d_in[10];
    const float* b1   = (const float*)d_in[11];
    const float* W2   = (const float*)d_in[12];
    const float* as2  = (const float*)d_in[13];
    const float* ad2  = (const float*)d_in[14];
    const float* b2   = (const float*)d_in[15];
    const float* ln_g = (const float*)d_in[16];
    const float* ln_b = (const float*)d_in[17];
    float* out = (float*)d_out;

    const int N    = in_sizes[0] / IN_DIM;   // 50000
    const int E    = in_sizes[1] / 2;        // 800000
    const int Etot = E + N;

    char* wptr = (char*)d_ws;
    auto alloc = [&](size_t bytes) -> void* {
        void* p = wptr;
        wptr += (bytes + 255) & ~(size_t)255;
        return p;
    };
    float* P      = (float*)alloc(sizeof(float) * (size_t)N * HID);
    float* F      = (float*)alloc(sizeof(float) * (size_t)N * F1);
    float* A      = (float*)alloc(sizeof(float) * (size_t)N * F1);   // layer0 activation
    float* als    = (float*)alloc(sizeof(float) * (size_t)N * HEADS);
    float* ald    = (float*)alloc(sizeof(float) * (size_t)N * HEADS);
    float* invden = (float*)alloc(sizeof(float) * (size_t)N * HEADS);
    float* exb    = (float*)alloc(sizeof(float) * (size_t)Etot * HEADS);
    float* f2     = (float*)alloc(sizeof(float) * (size_t)N * 2);
    int*   deg    = (int*)alloc(sizeof(int) * (size_t)N);
    int*   rend   = (int*)alloc(sizeof(int) * (size_t)N);
    int*   wcur   = (int*)alloc(sizeof(int) * (size_t)N);
    int*   csum   = (int*)alloc(sizeof(int) * 256);
    int*   csrs   = (int*)alloc(sizeof(int) * (size_t)Etot);

    const int eb  = (Etot + 255) / 256;
    const int nb  = (N + 255) / 256;
    const int nb4 = (N + 3) / 4;
    const int nchunks = (N + 1023) / 1024;
    const int mb  = (N + 63) / 64;

    // -------- CSR build --------
    hipMemsetAsync(deg, 0, sizeof(int) * (size_t)N, stream);
    csr_count<<<eb, 256, 0, stream>>>(ei, E, Etot, deg);
    scan1<<<nchunks, 256, 0, stream>>>(deg, rend, csum, N);
    scan2<<<1, 256, 0, stream>>>(csum, nchunks);
    scan3<<<nb, 256, 0, stream>>>(deg, rend, csum, wcur, N);
    csr_fill<<<eb, 256, 0, stream>>>(ei, E, Etot, wcur, csrs);

    // -------- input projection: P = x @ Wp + bp --------
    gemm_tile<true, false><<<dim3(mb, 1), 256, 0, stream>>>(
        x, Wp, bp, nullptr, nullptr, P, nullptr, nullptr, N, HID, IN_DIM);

    // ================= layer 0 =================
    gemm_tile<false, true><<<dim3(mb, 4), 256, 0, stream>>>(
        P, W0, nullptr, as0, ad0, F, als, ald, N, F1, HID);
    node_softmax4<<<nb4, 256, 0, stream>>>(csrs, rend, deg, als, ald, exb, invden, N);
    aggregate_ln<false, false><<<N, 256, 0, stream>>>(csrs, rend, deg, F, exb, invden,
        b0, ln_g, ln_b, nullptr, A, nullptr, nullptr, nullptr, nullptr, nullptr, nullptr, N);

    // ================= layer 1 =================
    gemm_tile<false, true><<<dim3(mb, 4), 256, 0, stream>>>(
        A, W1, nullptr, as1, ad1, F, als, ald, N, F1, F1);
    node_softmax4<<<nb4, 256, 0, stream>>>(csrs, rend, deg, als, ald, exb, invden, N);
    aggregate_ln<true, true><<<N, 256, 0, stream>>>(csrs, rend, deg, F, exb, invden,
        b1, ln_g, ln_b, A, nullptr, W2, as2, ad2, f2, als, ald, N);

    // ================= layer 2 (heads=1, C=2) =================
    node_softmax1<<<nb4, 256, 0, stream>>>(csrs, rend, deg, als, ald, exb, invden, N);
    aggregate2<<<nb4, 256, 0, stream>>>(csrs, rend, deg, f2, exb, invden, b2, out, N);
}

// Round 5
// 661.758 us; speedup vs baseline: 4.4363x; 1.0326x over previous
//
#include <hip/hip_runtime.h>
#include <hip/hip_bf16.h>
#include <cmath>

constexpr int IN_DIM = 184;
constexpr int HID    = 64;
constexpr int HEADS  = 4;
constexpr int F1     = HEADS * HID;   // 256
constexpr float SLOPE = 0.2f;
constexpr float LN_EPS = 1e-5f;

__device__ inline float bload(const ushort* __restrict__ p, size_t idx) {
    return __uint_as_float(((unsigned)p[idx]) << 16);   // bf16 -> f32 (exact)
}
__device__ inline ushort f2b(float f) {
    __hip_bfloat16 b = __float2bfloat16(f);             // RNE
    return *reinterpret_cast<ushort*>(&b);
}

// ================= tiled f32 GEMM =================
// Y[M,N] = X[M,K] @ W[K,N] (+bias). BM=64, BN=64, BK=32; 256 thr, 4x4/thread.
// OBF16: store output as bf16 (ushort). LOGITS: blockIdx.y==head h; epilogue
// computes als/ald row-dots from the exact f32 accumulators (no atomics).
template<bool BIAS, bool LOGITS, bool OBF16>
__global__ __launch_bounds__(256) void gemm_tile(const float* __restrict__ X,
                                                 const float* __restrict__ W,
                                                 const float* __restrict__ bias,
                                                 const float* __restrict__ as_,
                                                 const float* __restrict__ ad_,
                                                 void* __restrict__ Yv,
                                                 float* __restrict__ als,
                                                 float* __restrict__ ald,
                                                 int M, int N, int K) {
    __shared__ __align__(16) float xs[32][68];   // k-major, padded
    __shared__ __align__(16) float ws[32][68];
    const int row0 = blockIdx.x * 64;
    const int n0   = blockIdx.y * 64;
    const int tid  = threadIdx.x;
    const int tx   = tid & 15, ty = tid >> 4;

    float acc[4][4] = {};

    for (int k0 = 0; k0 < K; k0 += 32) {
        for (int i = tid; i < 64 * 32; i += 256) {
            int r = i >> 5, kk = i & 31;
            int gr = row0 + r, gk = k0 + kk;
            xs[kk][r] = (gr < M && gk < K) ? X[(size_t)gr * K + gk] : 0.f;
        }
        for (int i = tid; i < 32 * 64; i += 256) {
            int kk = i >> 6, c = i & 63;
            int gk = k0 + kk;
            ws[kk][c] = (gk < K) ? W[(size_t)gk * N + n0 + c] : 0.f;
        }
        __syncthreads();
#pragma unroll 4
        for (int kk = 0; kk < 32; ++kk) {
            float4 xv = *(const float4*)&xs[kk][ty * 4];
            float4 wv = *(const float4*)&ws[kk][tx * 4];
            acc[0][0] = fmaf(xv.x, wv.x, acc[0][0]);
            acc[0][1] = fmaf(xv.x, wv.y, acc[0][1]);
            acc[0][2] = fmaf(xv.x, wv.z, acc[0][2]);
            acc[0][3] = fmaf(xv.x, wv.w, acc[0][3]);
            acc[1][0] = fmaf(xv.y, wv.x, acc[1][0]);
            acc[1][1] = fmaf(xv.y, wv.y, acc[1][1]);
            acc[1][2] = fmaf(xv.y, wv.z, acc[1][2]);
            acc[1][3] = fmaf(xv.y, wv.w, acc[1][3]);
            acc[2][0] = fmaf(xv.z, wv.x, acc[2][0]);
            acc[2][1] = fmaf(xv.z, wv.y, acc[2][1]);
            acc[2][2] = fmaf(xv.z, wv.z, acc[2][2]);
            acc[2][3] = fmaf(xv.z, wv.w, acc[2][3]);
            acc[3][0] = fmaf(xv.w, wv.x, acc[3][0]);
            acc[3][1] = fmaf(xv.w, wv.y, acc[3][1]);
            acc[3][2] = fmaf(xv.w, wv.z, acc[3][2]);
            acc[3][3] = fmaf(xv.w, wv.w, acc[3][3]);
        }
        __syncthreads();
    }

    float bv[4];
#pragma unroll
    for (int j = 0; j < 4; ++j) bv[j] = BIAS ? bias[n0 + tx * 4 + j] : 0.f;

#pragma unroll
    for (int i = 0; i < 4; ++i) {
        int gr = row0 + ty * 4 + i;
        if (gr < M) {
            if (!OBF16) {
                float4 o = { acc[i][0] + bv[0], acc[i][1] + bv[1],
                             acc[i][2] + bv[2], acc[i][3] + bv[3] };
                *(float4*)&((float*)Yv)[(size_t)gr * N + n0 + tx * 4] = o;
            } else {
                ushort4 o = { f2b(acc[i][0] + bv[0]), f2b(acc[i][1] + bv[1]),
                              f2b(acc[i][2] + bv[2]), f2b(acc[i][3] + bv[3]) };
                *(ushort4*)&((ushort*)Yv)[(size_t)gr * N + n0 + tx * 4] = o;
            }
        }
    }

    if (LOGITS) {
        const int h = blockIdx.y;
        float asv[4], adv[4];
#pragma unroll
        for (int j = 0; j < 4; ++j) {
            asv[j] = as_[h * 64 + tx * 4 + j];
            adv[j] = ad_[h * 64 + tx * 4 + j];
        }
#pragma unroll
        for (int i = 0; i < 4; ++i) {
            float ls = acc[i][0] * asv[0] + acc[i][1] * asv[1] +
                       acc[i][2] * asv[2] + acc[i][3] * asv[3];
            float ld = acc[i][0] * adv[0] + acc[i][1] * adv[1] +
                       acc[i][2] * adv[2] + acc[i][3] * adv[3];
            for (int off = 8; off; off >>= 1) {
                ls += __shfl_xor(ls, off);
                ld += __shfl_xor(ld, off);
            }
            int gr = row0 + ty * 4 + i;
            if (tx == 0 && gr < M) {
                als[gr * HEADS + h] = ls;
                ald[gr * HEADS + h] = ld;
            }
        }
    }
}

// ---------------- CSR build ----------------
__device__ inline void edge_sd(const int* __restrict__ ei, int E, int idx, int& s, int& d) {
    if (idx < E) { s = ei[idx]; d = ei[E + idx]; }
    else         { s = idx - E; d = idx - E; }
}

__global__ __launch_bounds__(256) void csr_count(const int* __restrict__ ei, int E, int Etot,
                                                 int* __restrict__ deg) {
    int idx = blockIdx.x * 256 + threadIdx.x;
    if (idx >= Etot) return;
    int s, d; edge_sd(ei, E, idx, s, d);
    atomicAdd(&deg[d], 1);
}

__global__ __launch_bounds__(256) void scan1(const int* __restrict__ deg, int* __restrict__ out,
                                             int* __restrict__ csum, int N) {
    __shared__ int s[256];
    int t = threadIdx.x;
    int idx0 = blockIdx.x * 1024 + t * 4;
    int v[4];
#pragma unroll
    for (int i = 0; i < 4; ++i) { int id = idx0 + i; v[i] = (id < N) ? deg[id] : 0; }
    int sum = v[0] + v[1] + v[2] + v[3];
    s[t] = sum; __syncthreads();
    for (int off = 1; off < 256; off <<= 1) {
        int x = (t >= off) ? s[t - off] : 0;
        __syncthreads();
        s[t] += x;
        __syncthreads();
    }
    int run = (t == 0) ? 0 : s[t - 1];
#pragma unroll
    for (int i = 0; i < 4; ++i) {
        run += v[i];
        int id = idx0 + i;
        if (id < N) out[id] = run;
    }
    if (t == 255) csum[blockIdx.x] = s[255];
}

__global__ __launch_bounds__(256) void scan2(int* __restrict__ csum, int M) {
    __shared__ int s[256];
    int t = threadIdx.x;
    s[t] = (t < M) ? csum[t] : 0;
    __syncthreads();
    for (int off = 1; off < 256; off <<= 1) {
        int x = (t >= off) ? s[t - off] : 0;
        __syncthreads();
        s[t] += x;
        __syncthreads();
    }
    if (t < M) csum[t] = s[t];
}

__global__ __launch_bounds__(256) void scan3(const int* __restrict__ deg, int* __restrict__ rend,
                                             const int* __restrict__ csum, int* __restrict__ wcur, int N) {
    int id = blockIdx.x * 256 + threadIdx.x;
    if (id >= N) return;
    int chunk = id >> 10;
    int off = (chunk == 0) ? 0 : csum[chunk - 1];
    int e = rend[id] + off;
    rend[id] = e;
    wcur[id] = e - deg[id];
}

__global__ __launch_bounds__(256) void csr_fill(const int* __restrict__ ei, int E, int Etot,
                                                int* __restrict__ wcur, int* __restrict__ csr_src) {
    int idx = blockIdx.x * 256 + threadIdx.x;
    if (idx >= Etot) return;
    int s, d; edge_sd(ei, E, idx, s, d);
    int pos = atomicAdd(&wcur[d], 1);
    csr_src[pos] = s;
}

// ---------------- per-node softmax (H=4), wave per node ----------------
__global__ __launch_bounds__(256) void node_softmax4(const int* __restrict__ csr_src,
                                                     const int* __restrict__ rend,
                                                     const int* __restrict__ deg,
                                                     const float* __restrict__ als,
                                                     const float* __restrict__ ald,
                                                     float* __restrict__ exb,
                                                     float* __restrict__ invden, int N) {
    int n = blockIdx.x * 4 + (threadIdx.x >> 6);
    int l = threadIdx.x & 63;
    if (n >= N) return;
    int end = rend[n], dg = deg[n], start = end - dg;
    const float4 ad4 = reinterpret_cast<const float4*>(ald)[n];
    float m0 = -3.4e38f, m1 = -3.4e38f, m2 = -3.4e38f, m3 = -3.4e38f;
    for (int i = l; i < dg; i += 64) {
        int s = csr_src[start + i];
        float4 a = reinterpret_cast<const float4*>(als)[s];
        float e0 = a.x + ad4.x; e0 = e0 > 0.f ? e0 : SLOPE * e0;
        float e1 = a.y + ad4.y; e1 = e1 > 0.f ? e1 : SLOPE * e1;
        float e2 = a.z + ad4.z; e2 = e2 > 0.f ? e2 : SLOPE * e2;
        float e3 = a.w + ad4.w; e3 = e3 > 0.f ? e3 : SLOPE * e3;
        m0 = fmaxf(m0, e0); m1 = fmaxf(m1, e1); m2 = fmaxf(m2, e2); m3 = fmaxf(m3, e3);
    }
    for (int off = 32; off; off >>= 1) {
        m0 = fmaxf(m0, __shfl_xor(m0, off));
        m1 = fmaxf(m1, __shfl_xor(m1, off));
        m2 = fmaxf(m2, __shfl_xor(m2, off));
        m3 = fmaxf(m3, __shfl_xor(m3, off));
    }
    float s0 = 0.f, s1 = 0.f, s2 = 0.f, s3 = 0.f;
    for (int i = l; i < dg; i += 64) {
        int s = csr_src[start + i];
        float4 a = reinterpret_cast<const float4*>(als)[s];
        float e0 = a.x + ad4.x; e0 = e0 > 0.f ? e0 : SLOPE * e0;
        float e1 = a.y + ad4.y; e1 = e1 > 0.f ? e1 : SLOPE * e1;
        float e2 = a.z + ad4.z; e2 = e2 > 0.f ? e2 : SLOPE * e2;
        float e3 = a.w + ad4.w; e3 = e3 > 0.f ? e3 : SLOPE * e3;
        float4 ex = { expf(e0 - m0), expf(e1 - m1), expf(e2 - m2), expf(e3 - m3) };
        reinterpret_cast<float4*>(exb)[start + i] = ex;
        s0 += ex.x; s1 += ex.y; s2 += ex.z; s3 += ex.w;
    }
    for (int off = 32; off; off >>= 1) {
        s0 += __shfl_xor(s0, off);
        s1 += __shfl_xor(s1, off);
        s2 += __shfl_xor(s2, off);
        s3 += __shfl_xor(s3, off);
    }
    if (l == 0) {
        float4 iv = { 1.f / (s0 + 1e-16f), 1.f / (s1 + 1e-16f),
                      1.f / (s2 + 1e-16f), 1.f / (s3 + 1e-16f) };
        reinterpret_cast<float4*>(invden)[n] = iv;
    }
}

// ---------------- per-node softmax (H=1) ----------------
__global__ __launch_bounds__(256) void node_softmax1(const int* __restrict__ csr_src,
                                                     const int* __restrict__ rend,
                                                     const int* __restrict__ deg,
                                                     const float* __restrict__ als,
                                                     const float* __restrict__ ald,
                                                     float* __restrict__ exb,
                                                     float* __restrict__ invden, int N) {
    int n = blockIdx.x * 4 + (threadIdx.x >> 6);
    int l = threadIdx.x & 63;
    if (n >= N) return;
    int end = rend[n], dg = deg[n], start = end - dg;
    float ad = ald[n];
    float m = -3.4e38f;
    for (int i = l; i < dg; i += 64) {
        int s = csr_src[start + i];
        float e = als[s] + ad; e = e > 0.f ? e : SLOPE * e;
        m = fmaxf(m, e);
    }
    for (int off = 32; off; off >>= 1) m = fmaxf(m, __shfl_xor(m, off));
    float sum = 0.f;
    for (int i = l; i < dg; i += 64) {
        int s = csr_src[start + i];
        float e = als[s] + ad; e = e > 0.f ? e : SLOPE * e;
        float ex = expf(e - m);
        exb[start + i] = ex;
        sum += ex;
    }
    for (int off = 32; off; off >>= 1) sum += __shfl_xor(sum, off);
    if (l == 0) invden[n] = 1.f / (sum + 1e-16f);
}

// -------- aggregate (block per node, bf16 gather) + bias + LN (+res) + ELU --------
// FEAT2: compute f2 = act @ W2 (256->2) + layer-2 logits instead of storing act.
template<bool RES, bool FEAT2>
__global__ __launch_bounds__(256) void aggregate_ln(const int* __restrict__ csr_src,
                                                    const int* __restrict__ rend,
                                                    const int* __restrict__ deg,
                                                    const ushort* __restrict__ feat,
                                                    const float* __restrict__ exb,
                                                    const float* __restrict__ invden,
                                                    const float* __restrict__ bias,
                                                    const float* __restrict__ g,
                                                    const float* __restrict__ bln,
                                                    const float* __restrict__ res,
                                                    float* __restrict__ out,
                                                    const float* __restrict__ W2,
                                                    const float* __restrict__ as2,
                                                    const float* __restrict__ ad2,
                                                    float* __restrict__ f2,
                                                    float* __restrict__ als2,
                                                    float* __restrict__ ald2,
                                                    int N) {
    int n = blockIdx.x;
    int t = threadIdx.x;
    int h = t >> 6, l = t & 63;
    int end = rend[n], dg = deg[n], start = end - dg;
    float iv = invden[n * HEADS + h];
    float acc = 0.f;
    for (int c0 = start; c0 < end; c0 += 64) {
        int cnt = min(64, end - c0);
        int sp = 0; float ap = 0.f;
        if (l < cnt) {
            sp = csr_src[c0 + l];
            ap = exb[(size_t)(c0 + l) * HEADS + h] * iv;
        }
        int i = 0;
        for (; i + 8 <= cnt; i += 8) {
            int ss[8]; float aa[8]; float ff[8];
#pragma unroll
            for (int j = 0; j < 8; ++j) {
                ss[j] = __shfl(sp, i + j);
                aa[j] = __shfl(ap, i + j);
            }
#pragma unroll
            for (int j = 0; j < 8; ++j) ff[j] = bload(feat, (size_t)ss[j] * F1 + t);
#pragma unroll
            for (int j = 0; j < 8; ++j) acc = fmaf(ff[j], aa[j], acc);
        }
        for (; i < cnt; ++i) {
            int   s = __shfl(sp, i);
            float a = __shfl(ap, i);
            acc = fmaf(bload(feat, (size_t)s * F1 + t), a, acc);
        }
    }
    __shared__ float sred[4];
    __shared__ float s20[4], s21[4];
    float v = acc + bias[t];
    float sm = v;
    for (int off = 32; off; off >>= 1) sm += __shfl_down(sm, off);
    if (l == 0) sred[h] = sm;
    __syncthreads();
    float mu = (sred[0] + sred[1] + sred[2] + sred[3]) * (1.f / F1);
    __syncthreads();
    float dv = (v - mu) * (v - mu);
    for (int off = 32; off; off >>= 1) dv += __shfl_down(dv, off);
    if (l == 0) sred[h] = dv;
    __syncthreads();
    float var = (sred[0] + sred[1] + sred[2] + sred[3]) * (1.f / F1);
    float y = (v - mu) * rsqrtf(var + LN_EPS) * g[t] + bln[t];
    if (RES) y += res[(size_t)n * F1 + t];
    y = y > 0.f ? y : expm1f(y);
    if (!FEAT2) {
        out[(size_t)n * F1 + t] = y;
    } else {
        float c0 = y * W2[t * 2 + 0];
        float c1 = y * W2[t * 2 + 1];
        for (int off = 32; off; off >>= 1) {
            c0 += __shfl_down(c0, off);
            c1 += __shfl_down(c1, off);
        }
        if (l == 0) { s20[h] = c0; s21[h] = c1; }
        __syncthreads();
        if (t == 0) {
            float f0 = s20[0] + s20[1] + s20[2] + s20[3];
            float f1 = s21[0] + s21[1] + s21[2] + s21[3];
            f2[(size_t)n * 2 + 0] = f0;
            f2[(size_t)n * 2 + 1] = f1;
            als2[n] = f0 * as2[0] + f1 * as2[1];
            ald2[n] = f0 * ad2[0] + f1 * ad2[1];
        }
    }
}

// ---------------- layer2 aggregation: wave per node, 2 features ----------------
__global__ __launch_bounds__(256) void aggregate2(const int* __restrict__ csr_src,
                                                  const int* __restrict__ rend,
                                                  const int* __restrict__ deg,
                                                  const float* __restrict__ f2,
                                                  const float* __restrict__ exb,
                                                  const float* __restrict__ invden,
                                                  const float* __restrict__ b2,
                                                  float* __restrict__ out, int N) {
    int n = blockIdx.x * 4 + (threadIdx.x >> 6);
    int l = threadIdx.x & 63;
    if (n >= N) return;
    int end = rend[n], dg = deg[n], start = end - dg;
    float iv = invden[n];
    float a0 = 0.f, a1 = 0.f;
    for (int i = l; i < dg; i += 64) {
        int s = csr_src[start + i];
        float a = exb[start + i] * iv;
        float2 f = reinterpret_cast<const float2*>(f2)[s];
        a0 = fmaf(f.x, a, a0);
        a1 = fmaf(f.y, a, a1);
    }
    for (int off = 32; off; off >>= 1) {
        a0 += __shfl_xor(a0, off);
        a1 += __shfl_xor(a1, off);
    }
    if (l == 0) {
        out[(size_t)n * 2 + 0] = a0 + b2[0];
        out[(size_t)n * 2 + 1] = a1 + b2[1];
    }
}

extern "C" void kernel_launch(void* const* d_in, const int* in_sizes, int n_in,
                              void* d_out, int out_size, void* d_ws, size_t ws_size,
                              hipStream_t stream) {
    const float* x    = (const float*)d_in[0];
    const int*   ei   = (const int*)d_in[1];
    const float* Wp   = (const float*)d_in[2];
    const float* bp   = (const float*)d_in[3];
    const float* W0   = (const float*)d_in[4];
    const float* as0  = (const float*)d_in[5];
    const float* ad0  = (const float*)d_in[6];
    const float* b0   = (const float*)d_in[7];
    const float* W1   = (const float*)d_in[8];
    const float* as1  = (const float*)d_in[9];
    const float* ad1  = (const float*)d_in[10];
    const float* b1   = (const float*)d_in[11];
    const float* W2   = (const float*)d_in[12];
    const float* as2  = (const float*)d_in[13];
    const float* ad2  = (const float*)d_in[14];
    const float* b2   = (const float*)d_in[15];
    const float* ln_g = (const float*)d_in[16];
    const float* ln_b = (const float*)d_in[17];
    float* out = (float*)d_out;

    const int N    = in_sizes[0] / IN_DIM;   // 50000
    const int E    = in_sizes[1] / 2;        // 800000
    const int Etot = E + N;

    char* wptr = (char*)d_ws;
    auto alloc = [&](size_t bytes) -> void* {
        void* p = wptr;
        wptr += (bytes + 255) & ~(size_t)255;
        return p;
    };
    float*  P      = (float*)alloc(sizeof(float) * (size_t)N * HID);
    ushort* F      = (ushort*)alloc(sizeof(ushort) * (size_t)N * F1);
    float*  A      = (float*)alloc(sizeof(float) * (size_t)N * F1);   // layer0 activation
    float*  als    = (float*)alloc(sizeof(float) * (size_t)N * HEADS);
    float*  ald    = (float*)alloc(sizeof(float) * (size_t)N * HEADS);
    float*  invden = (float*)alloc(sizeof(float) * (size_t)N * HEADS);
    float*  exb    = (float*)alloc(sizeof(float) * (size_t)Etot * HEADS);
    float*  f2     = (float*)alloc(sizeof(float) * (size_t)N * 2);
    int*    deg    = (int*)alloc(sizeof(int) * (size_t)N);
    int*    rend   = (int*)alloc(sizeof(int) * (size_t)N);
    int*    wcur   = (int*)alloc(sizeof(int) * (size_t)N);
    int*    csum   = (int*)alloc(sizeof(int) * 256);
    int*    csrs   = (int*)alloc(sizeof(int) * (size_t)Etot);

    const int eb  = (Etot + 255) / 256;
    const int nb  = (N + 255) / 256;
    const int nb4 = (N + 3) / 4;
    const int nchunks = (N + 1023) / 1024;
    const int mb  = (N + 63) / 64;

    // -------- CSR build --------
    hipMemsetAsync(deg, 0, sizeof(int) * (size_t)N, stream);
    csr_count<<<eb, 256, 0, stream>>>(ei, E, Etot, deg);
    scan1<<<nchunks, 256, 0, stream>>>(deg, rend, csum, N);
    scan2<<<1, 256, 0, stream>>>(csum, nchunks);
    scan3<<<nb, 256, 0, stream>>>(deg, rend, csum, wcur, N);
    csr_fill<<<eb, 256, 0, stream>>>(ei, E, Etot, wcur, csrs);

    // -------- input projection: P = x @ Wp + bp (f32 out) --------
    gemm_tile<true, false, false><<<dim3(mb, 1), 256, 0, stream>>>(
        x, Wp, bp, nullptr, nullptr, P, nullptr, nullptr, N, HID, IN_DIM);

    // ================= layer 0 =================
    gemm_tile<false, true, true><<<dim3(mb, 4), 256, 0, stream>>>(
        P, W0, nullptr, as0, ad0, F, als, ald, N, F1, HID);
    node_softmax4<<<nb4, 256, 0, stream>>>(csrs, rend, deg, als, ald, exb, invden, N);
    aggregate_ln<false, false><<<N, 256, 0, stream>>>(csrs, rend, deg, F, exb, invden,
        b0, ln_g, ln_b, nullptr, A, nullptr, nullptr, nullptr, nullptr, nullptr, nullptr, N);

    // ================= layer 1 =================
    gemm_tile<false, true, true><<<dim3(mb, 4), 256, 0, stream>>>(
        A, W1, nullptr, as1, ad1, F, als, ald, N, F1, F1);
    node_softmax4<<<nb4, 256, 0, stream>>>(csrs, rend, deg, als, ald, exb, invden, N);
    aggregate_ln<true, true><<<N, 256, 0, stream>>>(csrs, rend, deg, F, exb, invden,
        b1, ln_g, ln_b, A, nullptr, W2, as2, ad2, f2, als, ald, N);

    // ================= layer 2 (heads=1, C=2) =================
    node_softmax1<<<nb4, 256, 0, stream>>>(csrs, rend, deg, als, ald, exb, invden, N);
    aggregate2<<<nb4, 256, 0, stream>>>(csrs, rend, deg, f2, exb, invden, b2, out, N);
}

// Round 6
// 599.612 us; speedup vs baseline: 4.8961x; 1.1036x over previous
//
#include <hip/hip_runtime.h>
#include <hip/hip_bf16.h>
#include <cmath>

constexpr int IN_DIM = 184;
constexpr int HID    = 64;
constexpr int HEADS  = 4;
constexpr int F1     = HEADS * HID;   // 256
constexpr float SLOPE = 0.2f;
constexpr float LN_EPS = 1e-5f;

__device__ inline float b2f(ushort u) {
    return __uint_as_float(((unsigned)u) << 16);        // bf16 -> f32 (exact)
}
__device__ inline ushort f2b(float f) {
    __hip_bfloat16 b = __float2bfloat16(f);             // RNE
    return *reinterpret_cast<ushort*>(&b);
}

// ================= tiled f32 GEMM =================
// Y[M,N] = X[M,K] @ W[K,N] (+bias). BM=64, BN=64, BK=32; 256 thr, 4x4/thread.
// OBF16: store output as bf16 (ushort). LOGITS: blockIdx.y==head h; epilogue
// computes als/ald row-dots from the exact f32 accumulators (no atomics).
template<bool BIAS, bool LOGITS, bool OBF16>
__global__ __launch_bounds__(256) void gemm_tile(const float* __restrict__ X,
                                                 const float* __restrict__ W,
                                                 const float* __restrict__ bias,
                                                 const float* __restrict__ as_,
                                                 const float* __restrict__ ad_,
                                                 void* __restrict__ Yv,
                                                 float* __restrict__ als,
                                                 float* __restrict__ ald,
                                                 int M, int N, int K) {
    __shared__ __align__(16) float xs[32][68];   // k-major, padded
    __shared__ __align__(16) float ws[32][68];
    const int row0 = blockIdx.x * 64;
    const int n0   = blockIdx.y * 64;
    const int tid  = threadIdx.x;
    const int tx   = tid & 15, ty = tid >> 4;

    float acc[4][4] = {};

    for (int k0 = 0; k0 < K; k0 += 32) {
        for (int i = tid; i < 64 * 32; i += 256) {
            int r = i >> 5, kk = i & 31;
            int gr = row0 + r, gk = k0 + kk;
            xs[kk][r] = (gr < M && gk < K) ? X[(size_t)gr * K + gk] : 0.f;
        }
        for (int i = tid; i < 32 * 64; i += 256) {
            int kk = i >> 6, c = i & 63;
            int gk = k0 + kk;
            ws[kk][c] = (gk < K) ? W[(size_t)gk * N + n0 + c] : 0.f;
        }
        __syncthreads();
#pragma unroll 4
        for (int kk = 0; kk < 32; ++kk) {
            float4 xv = *(const float4*)&xs[kk][ty * 4];
            float4 wv = *(const float4*)&ws[kk][tx * 4];
            acc[0][0] = fmaf(xv.x, wv.x, acc[0][0]);
            acc[0][1] = fmaf(xv.x, wv.y, acc[0][1]);
            acc[0][2] = fmaf(xv.x, wv.z, acc[0][2]);
            acc[0][3] = fmaf(xv.x, wv.w, acc[0][3]);
            acc[1][0] = fmaf(xv.y, wv.x, acc[1][0]);
            acc[1][1] = fmaf(xv.y, wv.y, acc[1][1]);
            acc[1][2] = fmaf(xv.y, wv.z, acc[1][2]);
            acc[1][3] = fmaf(xv.y, wv.w, acc[1][3]);
            acc[2][0] = fmaf(xv.z, wv.x, acc[2][0]);
            acc[2][1] = fmaf(xv.z, wv.y, acc[2][1]);
            acc[2][2] = fmaf(xv.z, wv.z, acc[2][2]);
            acc[2][3] = fmaf(xv.z, wv.w, acc[2][3]);
            acc[3][0] = fmaf(xv.w, wv.x, acc[3][0]);
            acc[3][1] = fmaf(xv.w, wv.y, acc[3][1]);
            acc[3][2] = fmaf(xv.w, wv.z, acc[3][2]);
            acc[3][3] = fmaf(xv.w, wv.w, acc[3][3]);
        }
        __syncthreads();
    }

    float bv[4];
#pragma unroll
    for (int j = 0; j < 4; ++j) bv[j] = BIAS ? bias[n0 + tx * 4 + j] : 0.f;

#pragma unroll
    for (int i = 0; i < 4; ++i) {
        int gr = row0 + ty * 4 + i;
        if (gr < M) {
            if (!OBF16) {
                float4 o = { acc[i][0] + bv[0], acc[i][1] + bv[1],
                             acc[i][2] + bv[2], acc[i][3] + bv[3] };
                *(float4*)&((float*)Yv)[(size_t)gr * N + n0 + tx * 4] = o;
            } else {
                ushort4 o = { f2b(acc[i][0] + bv[0]), f2b(acc[i][1] + bv[1]),
                              f2b(acc[i][2] + bv[2]), f2b(acc[i][3] + bv[3]) };
                *(ushort4*)&((ushort*)Yv)[(size_t)gr * N + n0 + tx * 4] = o;
            }
        }
    }

    if (LOGITS) {
        const int h = blockIdx.y;
        float asv[4], adv[4];
#pragma unroll
        for (int j = 0; j < 4; ++j) {
            asv[j] = as_[h * 64 + tx * 4 + j];
            adv[j] = ad_[h * 64 + tx * 4 + j];
        }
#pragma unroll
        for (int i = 0; i < 4; ++i) {
            float ls = acc[i][0] * asv[0] + acc[i][1] * asv[1] +
                       acc[i][2] * asv[2] + acc[i][3] * asv[3];
            float ld = acc[i][0] * adv[0] + acc[i][1] * adv[1] +
                       acc[i][2] * adv[2] + acc[i][3] * adv[3];
            for (int off = 8; off; off >>= 1) {
                ls += __shfl_xor(ls, off);
                ld += __shfl_xor(ld, off);
            }
            int gr = row0 + ty * 4 + i;
            if (tx == 0 && gr < M) {
                als[gr * HEADS + h] = ls;
                ald[gr * HEADS + h] = ld;
            }
        }
    }
}

// ---------------- CSR build ----------------
__device__ inline void edge_sd(const int* __restrict__ ei, int E, int idx, int& s, int& d) {
    if (idx < E) { s = ei[idx]; d = ei[E + idx]; }
    else         { s = idx - E; d = idx - E; }
}

__global__ __launch_bounds__(256) void csr_count(const int* __restrict__ ei, int E, int Etot,
                                                 int* __restrict__ deg) {
    int idx = blockIdx.x * 256 + threadIdx.x;
    if (idx >= Etot) return;
    int s, d; edge_sd(ei, E, idx, s, d);
    atomicAdd(&deg[d], 1);
}

__global__ __launch_bounds__(256) void scan1(const int* __restrict__ deg, int* __restrict__ out,
                                             int* __restrict__ csum, int N) {
    __shared__ int s[256];
    int t = threadIdx.x;
    int idx0 = blockIdx.x * 1024 + t * 4;
    int v[4];
#pragma unroll
    for (int i = 0; i < 4; ++i) { int id = idx0 + i; v[i] = (id < N) ? deg[id] : 0; }
    int sum = v[0] + v[1] + v[2] + v[3];
    s[t] = sum; __syncthreads();
    for (int off = 1; off < 256; off <<= 1) {
        int x = (t >= off) ? s[t - off] : 0;
        __syncthreads();
        s[t] += x;
        __syncthreads();
    }
    int run = (t == 0) ? 0 : s[t - 1];
#pragma unroll
    for (int i = 0; i < 4; ++i) {
        run += v[i];
        int id = idx0 + i;
        if (id < N) out[id] = run;
    }
    if (t == 255) csum[blockIdx.x] = s[255];
}

__global__ __launch_bounds__(256) void scan2(int* __restrict__ csum, int M) {
    __shared__ int s[256];
    int t = threadIdx.x;
    s[t] = (t < M) ? csum[t] : 0;
    __syncthreads();
    for (int off = 1; off < 256; off <<= 1) {
        int x = (t >= off) ? s[t - off] : 0;
        __syncthreads();
        s[t] += x;
        __syncthreads();
    }
    if (t < M) csum[t] = s[t];
}

__global__ __launch_bounds__(256) void scan3(const int* __restrict__ deg, int* __restrict__ rend,
                                             const int* __restrict__ csum, int* __restrict__ wcur, int N) {
    int id = blockIdx.x * 256 + threadIdx.x;
    if (id >= N) return;
    int chunk = id >> 10;
    int off = (chunk == 0) ? 0 : csum[chunk - 1];
    int e = rend[id] + off;
    rend[id] = e;
    wcur[id] = e - deg[id];
}

__global__ __launch_bounds__(256) void csr_fill(const int* __restrict__ ei, int E, int Etot,
                                                int* __restrict__ wcur, int* __restrict__ csr_src) {
    int idx = blockIdx.x * 256 + threadIdx.x;
    if (idx >= Etot) return;
    int s, d; edge_sd(ei, E, idx, s, d);
    int pos = atomicAdd(&wcur[d], 1);
    csr_src[pos] = s;
}

// ---------------- per-node softmax (H=4), wave per node ----------------
__global__ __launch_bounds__(256) void node_softmax4(const int* __restrict__ csr_src,
                                                     const int* __restrict__ rend,
                                                     const int* __restrict__ deg,
                                                     const float* __restrict__ als,
                                                     const float* __restrict__ ald,
                                                     float* __restrict__ exb,
                                                     float* __restrict__ invden, int N) {
    int n = blockIdx.x * 4 + (threadIdx.x >> 6);
    int l = threadIdx.x & 63;
    if (n >= N) return;
    int end = rend[n], dg = deg[n], start = end - dg;
    const float4 ad4 = reinterpret_cast<const float4*>(ald)[n];
    float m0 = -3.4e38f, m1 = -3.4e38f, m2 = -3.4e38f, m3 = -3.4e38f;
    for (int i = l; i < dg; i += 64) {
        int s = csr_src[start + i];
        float4 a = reinterpret_cast<const float4*>(als)[s];
        float e0 = a.x + ad4.x; e0 = e0 > 0.f ? e0 : SLOPE * e0;
        float e1 = a.y + ad4.y; e1 = e1 > 0.f ? e1 : SLOPE * e1;
        float e2 = a.z + ad4.z; e2 = e2 > 0.f ? e2 : SLOPE * e2;
        float e3 = a.w + ad4.w; e3 = e3 > 0.f ? e3 : SLOPE * e3;
        m0 = fmaxf(m0, e0); m1 = fmaxf(m1, e1); m2 = fmaxf(m2, e2); m3 = fmaxf(m3, e3);
    }
    for (int off = 32; off; off >>= 1) {
        m0 = fmaxf(m0, __shfl_xor(m0, off));
        m1 = fmaxf(m1, __shfl_xor(m1, off));
        m2 = fmaxf(m2, __shfl_xor(m2, off));
        m3 = fmaxf(m3, __shfl_xor(m3, off));
    }
    float s0 = 0.f, s1 = 0.f, s2 = 0.f, s3 = 0.f;
    for (int i = l; i < dg; i += 64) {
        int s = csr_src[start + i];
        float4 a = reinterpret_cast<const float4*>(als)[s];
        float e0 = a.x + ad4.x; e0 = e0 > 0.f ? e0 : SLOPE * e0;
        float e1 = a.y + ad4.y; e1 = e1 > 0.f ? e1 : SLOPE * e1;
        float e2 = a.z + ad4.z; e2 = e2 > 0.f ? e2 : SLOPE * e2;
        float e3 = a.w + ad4.w; e3 = e3 > 0.f ? e3 : SLOPE * e3;
        float4 ex = { expf(e0 - m0), expf(e1 - m1), expf(e2 - m2), expf(e3 - m3) };
        reinterpret_cast<float4*>(exb)[start + i] = ex;
        s0 += ex.x; s1 += ex.y; s2 += ex.z; s3 += ex.w;
    }
    for (int off = 32; off; off >>= 1) {
        s0 += __shfl_xor(s0, off);
        s1 += __shfl_xor(s1, off);
        s2 += __shfl_xor(s2, off);
        s3 += __shfl_xor(s3, off);
    }
    if (l == 0) {
        float4 iv = { 1.f / (s0 + 1e-16f), 1.f / (s1 + 1e-16f),
                      1.f / (s2 + 1e-16f), 1.f / (s3 + 1e-16f) };
        reinterpret_cast<float4*>(invden)[n] = iv;
    }
}

// ---------------- per-node softmax (H=1) ----------------
__global__ __launch_bounds__(256) void node_softmax1(const int* __restrict__ csr_src,
                                                     const int* __restrict__ rend,
                                                     const int* __restrict__ deg,
                                                     const float* __restrict__ als,
                                                     const float* __restrict__ ald,
                                                     float* __restrict__ exb,
                                                     float* __restrict__ invden, int N) {
    int n = blockIdx.x * 4 + (threadIdx.x >> 6);
    int l = threadIdx.x & 63;
    if (n >= N) return;
    int end = rend[n], dg = deg[n], start = end - dg;
    float ad = ald[n];
    float m = -3.4e38f;
    for (int i = l; i < dg; i += 64) {
        int s = csr_src[start + i];
        float e = als[s] + ad; e = e > 0.f ? e : SLOPE * e;
        m = fmaxf(m, e);
    }
    for (int off = 32; off; off >>= 1) m = fmaxf(m, __shfl_xor(m, off));
    float sum = 0.f;
    for (int i = l; i < dg; i += 64) {
        int s = csr_src[start + i];
        float e = als[s] + ad; e = e > 0.f ? e : SLOPE * e;
        float ex = expf(e - m);
        exb[start + i] = ex;
        sum += ex;
    }
    for (int off = 32; off; off >>= 1) sum += __shfl_xor(sum, off);
    if (l == 0) invden[n] = 1.f / (sum + 1e-16f);
}

// -------- aggregate: block per node, WAVE per edge-row (lane owns 4 features) --------
// Each wave w processes edges start+w, start+w+4, ... loading ushort4 (8B/lane,
// 512B/wave = full row in one instruction). Partials merged via LDS; invden
// applied once per node. Then bias + LN (+res) + ELU epilogue; FEAT2 optional.
template<bool RES, bool FEAT2>
__global__ __launch_bounds__(256) void aggregate_ln(const int* __restrict__ csr_src,
                                                    const int* __restrict__ rend,
                                                    const int* __restrict__ deg,
                                                    const ushort* __restrict__ feat,
                                                    const float* __restrict__ exb,
                                                    const float* __restrict__ invden,
                                                    const float* __restrict__ bias,
                                                    const float* __restrict__ g,
                                                    const float* __restrict__ bln,
                                                    const float* __restrict__ res,
                                                    float* __restrict__ out,
                                                    const float* __restrict__ W2,
                                                    const float* __restrict__ as2,
                                                    const float* __restrict__ ad2,
                                                    float* __restrict__ f2,
                                                    float* __restrict__ als2,
                                                    float* __restrict__ ald2,
                                                    int N) {
    const int n = blockIdx.x;
    const int t = threadIdx.x;
    const int w = t >> 6, l = t & 63;
    const int hh = l >> 4;                     // head of this lane's 4 features
    const int end = rend[n], dg = deg[n], start = end - dg;

    float a0 = 0.f, a1 = 0.f, a2 = 0.f, a3 = 0.f;
    int i = start + w;
    for (; i + 4 < end; i += 8) {              // unroll x2 across this wave's edges
        int   s0 = csr_src[i];
        int   s1 = csr_src[i + 4];
        float e0 = exb[(size_t)i * HEADS + hh];
        float e1 = exb[(size_t)(i + 4) * HEADS + hh];
        ushort4 f0 = *(const ushort4*)&feat[(size_t)s0 * F1 + l * 4];
        ushort4 f1 = *(const ushort4*)&feat[(size_t)s1 * F1 + l * 4];
        a0 = fmaf(b2f(f0.x), e0, a0);
        a1 = fmaf(b2f(f0.y), e0, a1);
        a2 = fmaf(b2f(f0.z), e0, a2);
        a3 = fmaf(b2f(f0.w), e0, a3);
        a0 = fmaf(b2f(f1.x), e1, a0);
        a1 = fmaf(b2f(f1.y), e1, a1);
        a2 = fmaf(b2f(f1.z), e1, a2);
        a3 = fmaf(b2f(f1.w), e1, a3);
    }
    if (i < end) {
        int   s0 = csr_src[i];
        float e0 = exb[(size_t)i * HEADS + hh];
        ushort4 f0 = *(const ushort4*)&feat[(size_t)s0 * F1 + l * 4];
        a0 = fmaf(b2f(f0.x), e0, a0);
        a1 = fmaf(b2f(f0.y), e0, a1);
        a2 = fmaf(b2f(f0.z), e0, a2);
        a3 = fmaf(b2f(f0.w), e0, a3);
    }

    __shared__ __align__(16) float sm[4][256];
    *(float4*)&sm[w][l * 4] = float4{ a0, a1, a2, a3 };
    __syncthreads();

    float acc = sm[0][t] + sm[1][t] + sm[2][t] + sm[3][t];
    float v = acc * invden[n * HEADS + (t >> 6)] + bias[t];

    const int h = t >> 6, lt = t & 63;
    __shared__ float sred[4];
    __shared__ float s20[4], s21[4];
    float smv = v;
    for (int off = 32; off; off >>= 1) smv += __shfl_down(smv, off);
    if (lt == 0) sred[h] = smv;
    __syncthreads();
    float mu = (sred[0] + sred[1] + sred[2] + sred[3]) * (1.f / F1);
    __syncthreads();
    float dv = (v - mu) * (v - mu);
    for (int off = 32; off; off >>= 1) dv += __shfl_down(dv, off);
    if (lt == 0) sred[h] = dv;
    __syncthreads();
    float var = (sred[0] + sred[1] + sred[2] + sred[3]) * (1.f / F1);
    float y = (v - mu) * rsqrtf(var + LN_EPS) * g[t] + bln[t];
    if (RES) y += res[(size_t)n * F1 + t];
    y = y > 0.f ? y : expm1f(y);
    if (!FEAT2) {
        out[(size_t)n * F1 + t] = y;
    } else {
        float c0 = y * W2[t * 2 + 0];
        float c1 = y * W2[t * 2 + 1];
        for (int off = 32; off; off >>= 1) {
            c0 += __shfl_down(c0, off);
            c1 += __shfl_down(c1, off);
        }
        if (lt == 0) { s20[h] = c0; s21[h] = c1; }
        __syncthreads();
        if (t == 0) {
            float f0 = s20[0] + s20[1] + s20[2] + s20[3];
            float f1 = s21[0] + s21[1] + s21[2] + s21[3];
            f2[(size_t)n * 2 + 0] = f0;
            f2[(size_t)n * 2 + 1] = f1;
            als2[n] = f0 * as2[0] + f1 * as2[1];
            ald2[n] = f0 * ad2[0] + f1 * ad2[1];
        }
    }
}

// ---------------- layer2 aggregation: wave per node, 2 features ----------------
__global__ __launch_bounds__(256) void aggregate2(const int* __restrict__ csr_src,
                                                  const int* __restrict__ rend,
                                                  const int* __restrict__ deg,
                                                  const float* __restrict__ f2,
                                                  const float* __restrict__ exb,
                                                  const float* __restrict__ invden,
                                                  const float* __restrict__ b2,
                                                  float* __restrict__ out, int N) {
    int n = blockIdx.x * 4 + (threadIdx.x >> 6);
    int l = threadIdx.x & 63;
    if (n >= N) return;
    int end = rend[n], dg = deg[n], start = end - dg;
    float iv = invden[n];
    float a0 = 0.f, a1 = 0.f;
    for (int i = l; i < dg; i += 64) {
        int s = csr_src[start + i];
        float a = exb[start + i] * iv;
        float2 f = reinterpret_cast<const float2*>(f2)[s];
        a0 = fmaf(f.x, a, a0);
        a1 = fmaf(f.y, a, a1);
    }
    for (int off = 32; off; off >>= 1) {
        a0 += __shfl_xor(a0, off);
        a1 += __shfl_xor(a1, off);
    }
    if (l == 0) {
        out[(size_t)n * 2 + 0] = a0 + b2[0];
        out[(size_t)n * 2 + 1] = a1 + b2[1];
    }
}

extern "C" void kernel_launch(void* const* d_in, const int* in_sizes, int n_in,
                              void* d_out, int out_size, void* d_ws, size_t ws_size,
                              hipStream_t stream) {
    const float* x    = (const float*)d_in[0];
    const int*   ei   = (const int*)d_in[1];
    const float* Wp   = (const float*)d_in[2];
    const float* bp   = (const float*)d_in[3];
    const float* W0   = (const float*)d_in[4];
    const float* as0  = (const float*)d_in[5];
    const float* ad0  = (const float*)d_in[6];
    const float* b0   = (const float*)d_in[7];
    const float* W1   = (const float*)d_in[8];
    const float* as1  = (const float*)d_in[9];
    const float* ad1  = (const float*)d_in[10];
    const float* b1   = (const float*)d_in[11];
    const float* W2   = (const float*)d_in[12];
    const float* as2  = (const float*)d_in[13];
    const float* ad2  = (const float*)d_in[14];
    const float* b2   = (const float*)d_in[15];
    const float* ln_g = (const float*)d_in[16];
    const float* ln_b = (const float*)d_in[17];
    float* out = (float*)d_out;

    const int N    = in_sizes[0] / IN_DIM;   // 50000
    const int E    = in_sizes[1] / 2;        // 800000
    const int Etot = E + N;

    char* wptr = (char*)d_ws;
    auto alloc = [&](size_t bytes) -> void* {
        void* p = wptr;
        wptr += (bytes + 255) & ~(size_t)255;
        return p;
    };
    float*  P      = (float*)alloc(sizeof(float) * (size_t)N * HID);
    ushort* F      = (ushort*)alloc(sizeof(ushort) * (size_t)N * F1);
    float*  A      = (float*)alloc(sizeof(float) * (size_t)N * F1);   // layer0 activation
    float*  als    = (float*)alloc(sizeof(float) * (size_t)N * HEADS);
    float*  ald    = (float*)alloc(sizeof(float) * (size_t)N * HEADS);
    float*  invden = (float*)alloc(sizeof(float) * (size_t)N * HEADS);
    float*  exb    = (float*)alloc(sizeof(float) * (size_t)Etot * HEADS);
    float*  f2     = (float*)alloc(sizeof(float) * (size_t)N * 2);
    int*    deg    = (int*)alloc(sizeof(int) * (size_t)N);
    int*    rend   = (int*)alloc(sizeof(int) * (size_t)N);
    int*    wcur   = (int*)alloc(sizeof(int) * (size_t)N);
    int*    csum   = (int*)alloc(sizeof(int) * 256);
    int*    csrs   = (int*)alloc(sizeof(int) * (size_t)Etot);

    const int eb  = (Etot + 255) / 256;
    const int nb  = (N + 255) / 256;
    const int nb4 = (N + 3) / 4;
    const int nchunks = (N + 1023) / 1024;
    const int mb  = (N + 63) / 64;

    // -------- CSR build --------
    hipMemsetAsync(deg, 0, sizeof(int) * (size_t)N, stream);
    csr_count<<<eb, 256, 0, stream>>>(ei, E, Etot, deg);
    scan1<<<nchunks, 256, 0, stream>>>(deg, rend, csum, N);
    scan2<<<1, 256, 0, stream>>>(csum, nchunks);
    scan3<<<nb, 256, 0, stream>>>(deg, rend, csum, wcur, N);
    csr_fill<<<eb, 256, 0, stream>>>(ei, E, Etot, wcur, csrs);

    // -------- input projection: P = x @ Wp + bp (f32 out) --------
    gemm_tile<true, false, false><<<dim3(mb, 1), 256, 0, stream>>>(
        x, Wp, bp, nullptr, nullptr, P, nullptr, nullptr, N, HID, IN_DIM);

    // ================= layer 0 =================
    gemm_tile<false, true, true><<<dim3(mb, 4), 256, 0, stream>>>(
        P, W0, nullptr, as0, ad0, F, als, ald, N, F1, HID);
    node_softmax4<<<nb4, 256, 0, stream>>>(csrs, rend, deg, als, ald, exb, invden, N);
    aggregate_ln<false, false><<<N, 256, 0, stream>>>(csrs, rend, deg, F, exb, invden,
        b0, ln_g, ln_b, nullptr, A, nullptr, nullptr, nullptr, nullptr, nullptr, nullptr, N);

    // ================= layer 1 =================
    gemm_tile<false, true, true><<<dim3(mb, 4), 256, 0, stream>>>(
        A, W1, nullptr, as1, ad1, F, als, ald, N, F1, F1);
    node_softmax4<<<nb4, 256, 0, stream>>>(csrs, rend, deg, als, ald, exb, invden, N);
    aggregate_ln<true, true><<<N, 256, 0, stream>>>(csrs, rend, deg, F, exb, invden,
        b1, ln_g, ln_b, A, nullptr, W2, as2, ad2, f2, als, ald, N);

    // ================= layer 2 (heads=1, C=2) =================
    node_softmax1<<<nb4, 256, 0, stream>>>(csrs, rend, deg, als, ald, exb, invden, N);
    aggregate2<<<nb4, 256, 0, stream>>>(csrs, rend, deg, f2, exb, invden, b2, out, N);
}

// Round 7
// 559.058 us; speedup vs baseline: 5.2513x; 1.0725x over previous
//
#include <hip/hip_runtime.h>
#include <hip/hip_bf16.h>
#include <cmath>

constexpr int IN_DIM = 184;
constexpr int HID    = 64;
constexpr int HEADS  = 4;
constexpr int F1     = HEADS * HID;   // 256
constexpr float SLOPE = 0.2f;
constexpr float LN_EPS = 1e-5f;

using short8 = __attribute__((ext_vector_type(8))) short;
using f32x4  = __attribute__((ext_vector_type(4))) float;

__device__ inline float b2f(ushort u) {
    return __uint_as_float(((unsigned)u) << 16);        // bf16 -> f32 (exact)
}
__device__ inline ushort f2b(float f) {
    __hip_bfloat16 b = __float2bfloat16(f);             // RNE
    return *reinterpret_cast<ushort*>(&b);
}
__device__ inline short8 mk8(ushort4 lo, ushort4 hi) {
    short8 v;
    v[0] = (short)lo.x; v[1] = (short)lo.y; v[2] = (short)lo.z; v[3] = (short)lo.w;
    v[4] = (short)hi.x; v[5] = (short)hi.y; v[6] = (short)hi.z; v[7] = (short)hi.w;
    return v;
}

// ---------------- W -> Wt bf16 transpose: Wt[c][k] = bf16(W[k][c]) ----------------
__global__ __launch_bounds__(256) void cvt_transpose(const float* __restrict__ W,
                                                     ushort* __restrict__ Wt,
                                                     int K, int NC) {
    int idx = blockIdx.x * 256 + threadIdx.x;
    if (idx >= K * NC) return;
    int k = idx / NC, c = idx - k * NC;
    Wt[(size_t)c * K + k] = f2b(W[idx]);
}

// ================= MFMA bf16 GEMM: Y[M,256] = X[M,K] @ W[K,256] =================
// X bf16 row-major [M][K]; Wt bf16 TRANSPOSED [256][K]. 32 rows/block, 4 waves;
// wave w owns cols w*64..w*64+63 (== head w). No LDS; A/B frags straight from
// global (L2/L3 resident). Epilogue: Y bf16 store + per-head attention logits.
// mfma_f32_16x16x32_bf16 layouts: A lane l reg j -> A[l&15][4*(l>>4)+(j&3)+16*(j>>2)];
// B lane l reg j -> B[k same][l&15]; D lane l reg r -> D[(l>>4)*4+r][l&15].
template<int K, bool LOGITS>
__global__ __launch_bounds__(256) void mfma_gemm(const ushort* __restrict__ X,
                                                 const ushort* __restrict__ Wt,
                                                 const float* __restrict__ as_,
                                                 const float* __restrict__ ad_,
                                                 ushort* __restrict__ Y,
                                                 float* __restrict__ als,
                                                 float* __restrict__ ald,
                                                 int M) {
    const int tid = threadIdx.x;
    const int w = tid >> 6, l = tid & 63;
    const int lr = l & 15, q = l >> 4;
    const int row0 = blockIdx.x * 32;

    f32x4 acc00 = {0,0,0,0}, acc01 = {0,0,0,0}, acc02 = {0,0,0,0}, acc03 = {0,0,0,0};
    f32x4 acc10 = {0,0,0,0}, acc11 = {0,0,0,0}, acc12 = {0,0,0,0}, acc13 = {0,0,0,0};

    const int rA0 = min(row0 + lr, M - 1);
    const int rA1 = min(row0 + 16 + lr, M - 1);
    const int colb = w * 64 + lr;

#pragma unroll
    for (int k0 = 0; k0 < K; k0 += 32) {
        const ushort* p0 = &X[(size_t)rA0 * K + k0 + 4 * q];
        const ushort* p1 = &X[(size_t)rA1 * K + k0 + 4 * q];
        short8 a0 = mk8(*(const ushort4*)p0, *(const ushort4*)(p0 + 16));
        short8 a1 = mk8(*(const ushort4*)p1, *(const ushort4*)(p1 + 16));

        const ushort* pb0 = &Wt[(size_t)(colb +  0) * K + k0 + 4 * q];
        const ushort* pb1 = &Wt[(size_t)(colb + 16) * K + k0 + 4 * q];
        const ushort* pb2 = &Wt[(size_t)(colb + 32) * K + k0 + 4 * q];
        const ushort* pb3 = &Wt[(size_t)(colb + 48) * K + k0 + 4 * q];
        short8 b0 = mk8(*(const ushort4*)pb0, *(const ushort4*)(pb0 + 16));
        short8 b1 = mk8(*(const ushort4*)pb1, *(const ushort4*)(pb1 + 16));
        short8 b2 = mk8(*(const ushort4*)pb2, *(const ushort4*)(pb2 + 16));
        short8 b3 = mk8(*(const ushort4*)pb3, *(const ushort4*)(pb3 + 16));

        acc00 = __builtin_amdgcn_mfma_f32_16x16x32_bf16(a0, b0, acc00, 0, 0, 0);
        acc01 = __builtin_amdgcn_mfma_f32_16x16x32_bf16(a0, b1, acc01, 0, 0, 0);
        acc02 = __builtin_amdgcn_mfma_f32_16x16x32_bf16(a0, b2, acc02, 0, 0, 0);
        acc03 = __builtin_amdgcn_mfma_f32_16x16x32_bf16(a0, b3, acc03, 0, 0, 0);
        acc10 = __builtin_amdgcn_mfma_f32_16x16x32_bf16(a1, b0, acc10, 0, 0, 0);
        acc11 = __builtin_amdgcn_mfma_f32_16x16x32_bf16(a1, b1, acc11, 0, 0, 0);
        acc12 = __builtin_amdgcn_mfma_f32_16x16x32_bf16(a1, b2, acc12, 0, 0, 0);
        acc13 = __builtin_amdgcn_mfma_f32_16x16x32_bf16(a1, b3, acc13, 0, 0, 0);
    }

    f32x4 accs[2][4] = { { acc00, acc01, acc02, acc03 },
                         { acc10, acc11, acc12, acc13 } };

#pragma unroll
    for (int rt = 0; rt < 2; ++rt) {
#pragma unroll
        for (int r = 0; r < 4; ++r) {
            int row = row0 + rt * 16 + q * 4 + r;
            if (row < M) {
#pragma unroll
                for (int ct = 0; ct < 4; ++ct)
                    Y[(size_t)row * 256 + w * 64 + ct * 16 + lr] = f2b(accs[rt][ct][r]);
            }
        }
    }

    if (LOGITS) {
        float asv[4], adv[4];
#pragma unroll
        for (int ct = 0; ct < 4; ++ct) {
            asv[ct] = as_[w * 64 + ct * 16 + lr];
            adv[ct] = ad_[w * 64 + ct * 16 + lr];
        }
#pragma unroll
        for (int rt = 0; rt < 2; ++rt) {
#pragma unroll
            for (int r = 0; r < 4; ++r) {
                float ls = 0.f, ld_ = 0.f;
#pragma unroll
                for (int ct = 0; ct < 4; ++ct) {
                    ls  = fmaf(accs[rt][ct][r], asv[ct], ls);
                    ld_ = fmaf(accs[rt][ct][r], adv[ct], ld_);
                }
                for (int off = 8; off; off >>= 1) {
                    ls  += __shfl_xor(ls, off);
                    ld_ += __shfl_xor(ld_, off);
                }
                int row = row0 + rt * 16 + q * 4 + r;
                if (lr == 0 && row < M) {
                    als[row * HEADS + w] = ls;
                    ald[row * HEADS + w] = ld_;
                }
            }
        }
    }
}

// ================= tiled f32 GEMM (input projection only) =================
template<bool BIAS, bool OBF16>
__global__ __launch_bounds__(256) void gemm_tile(const float* __restrict__ X,
                                                 const float* __restrict__ W,
                                                 const float* __restrict__ bias,
                                                 void* __restrict__ Yv,
                                                 int M, int N, int K) {
    __shared__ __align__(16) float xs[32][68];
    __shared__ __align__(16) float ws[32][68];
    const int row0 = blockIdx.x * 64;
    const int n0   = blockIdx.y * 64;
    const int tid  = threadIdx.x;
    const int tx   = tid & 15, ty = tid >> 4;

    float acc[4][4] = {};

    for (int k0 = 0; k0 < K; k0 += 32) {
        for (int i = tid; i < 64 * 32; i += 256) {
            int r = i >> 5, kk = i & 31;
            int gr = row0 + r, gk = k0 + kk;
            xs[kk][r] = (gr < M && gk < K) ? X[(size_t)gr * K + gk] : 0.f;
        }
        for (int i = tid; i < 32 * 64; i += 256) {
            int kk = i >> 6, c = i & 63;
            int gk = k0 + kk;
            ws[kk][c] = (gk < K) ? W[(size_t)gk * N + n0 + c] : 0.f;
        }
        __syncthreads();
#pragma unroll 4
        for (int kk = 0; kk < 32; ++kk) {
            float4 xv = *(const float4*)&xs[kk][ty * 4];
            float4 wv = *(const float4*)&ws[kk][tx * 4];
            acc[0][0] = fmaf(xv.x, wv.x, acc[0][0]);
            acc[0][1] = fmaf(xv.x, wv.y, acc[0][1]);
            acc[0][2] = fmaf(xv.x, wv.z, acc[0][2]);
            acc[0][3] = fmaf(xv.x, wv.w, acc[0][3]);
            acc[1][0] = fmaf(xv.y, wv.x, acc[1][0]);
            acc[1][1] = fmaf(xv.y, wv.y, acc[1][1]);
            acc[1][2] = fmaf(xv.y, wv.z, acc[1][2]);
            acc[1][3] = fmaf(xv.y, wv.w, acc[1][3]);
            acc[2][0] = fmaf(xv.z, wv.x, acc[2][0]);
            acc[2][1] = fmaf(xv.z, wv.y, acc[2][1]);
            acc[2][2] = fmaf(xv.z, wv.z, acc[2][2]);
            acc[2][3] = fmaf(xv.z, wv.w, acc[2][3]);
            acc[3][0] = fmaf(xv.w, wv.x, acc[3][0]);
            acc[3][1] = fmaf(xv.w, wv.y, acc[3][1]);
            acc[3][2] = fmaf(xv.w, wv.z, acc[3][2]);
            acc[3][3] = fmaf(xv.w, wv.w, acc[3][3]);
        }
        __syncthreads();
    }

    float bv[4];
#pragma unroll
    for (int j = 0; j < 4; ++j) bv[j] = BIAS ? bias[n0 + tx * 4 + j] : 0.f;

#pragma unroll
    for (int i = 0; i < 4; ++i) {
        int gr = row0 + ty * 4 + i;
        if (gr < M) {
            if (!OBF16) {
                float4 o = { acc[i][0] + bv[0], acc[i][1] + bv[1],
                             acc[i][2] + bv[2], acc[i][3] + bv[3] };
                *(float4*)&((float*)Yv)[(size_t)gr * N + n0 + tx * 4] = o;
            } else {
                ushort4 o = { f2b(acc[i][0] + bv[0]), f2b(acc[i][1] + bv[1]),
                              f2b(acc[i][2] + bv[2]), f2b(acc[i][3] + bv[3]) };
                *(ushort4*)&((ushort*)Yv)[(size_t)gr * N + n0 + tx * 4] = o;
            }
        }
    }
}

// ---------------- CSR build ----------------
__device__ inline void edge_sd(const int* __restrict__ ei, int E, int idx, int& s, int& d) {
    if (idx < E) { s = ei[idx]; d = ei[E + idx]; }
    else         { s = idx - E; d = idx - E; }
}

__global__ __launch_bounds__(256) void csr_count(const int* __restrict__ ei, int E, int Etot,
                                                 int* __restrict__ deg) {
    int idx = blockIdx.x * 256 + threadIdx.x;
    if (idx >= Etot) return;
    int s, d; edge_sd(ei, E, idx, s, d);
    atomicAdd(&deg[d], 1);
}

__global__ __launch_bounds__(256) void scan1(const int* __restrict__ deg, int* __restrict__ out,
                                             int* __restrict__ csum, int N) {
    __shared__ int s[256];
    int t = threadIdx.x;
    int idx0 = blockIdx.x * 1024 + t * 4;
    int v[4];
#pragma unroll
    for (int i = 0; i < 4; ++i) { int id = idx0 + i; v[i] = (id < N) ? deg[id] : 0; }
    int sum = v[0] + v[1] + v[2] + v[3];
    s[t] = sum; __syncthreads();
    for (int off = 1; off < 256; off <<= 1) {
        int x = (t >= off) ? s[t - off] : 0;
        __syncthreads();
        s[t] += x;
        __syncthreads();
    }
    int run = (t == 0) ? 0 : s[t - 1];
#pragma unroll
    for (int i = 0; i < 4; ++i) {
        run += v[i];
        int id = idx0 + i;
        if (id < N) out[id] = run;
    }
    if (t == 255) csum[blockIdx.x] = s[255];
}

__global__ __launch_bounds__(256) void scan2(int* __restrict__ csum, int M) {
    __shared__ int s[256];
    int t = threadIdx.x;
    s[t] = (t < M) ? csum[t] : 0;
    __syncthreads();
    for (int off = 1; off < 256; off <<= 1) {
        int x = (t >= off) ? s[t - off] : 0;
        __syncthreads();
        s[t] += x;
        __syncthreads();
    }
    if (t < M) csum[t] = s[t];
}

__global__ __launch_bounds__(256) void scan3(const int* __restrict__ deg, int* __restrict__ rend,
                                             const int* __restrict__ csum, int* __restrict__ wcur, int N) {
    int id = blockIdx.x * 256 + threadIdx.x;
    if (id >= N) return;
    int chunk = id >> 10;
    int off = (chunk == 0) ? 0 : csum[chunk - 1];
    int e = rend[id] + off;
    rend[id] = e;
    wcur[id] = e - deg[id];
}

__global__ __launch_bounds__(256) void csr_fill(const int* __restrict__ ei, int E, int Etot,
                                                int* __restrict__ wcur, int* __restrict__ csr_src) {
    int idx = blockIdx.x * 256 + threadIdx.x;
    if (idx >= Etot) return;
    int s, d; edge_sd(ei, E, idx, s, d);
    int pos = atomicAdd(&wcur[d], 1);
    csr_src[pos] = s;
}

// ---------------- per-node softmax (H=4), wave per node ----------------
__global__ __launch_bounds__(256) void node_softmax4(const int* __restrict__ csr_src,
                                                     const int* __restrict__ rend,
                                                     const int* __restrict__ deg,
                                                     const float* __restrict__ als,
                                                     const float* __restrict__ ald,
                                                     float* __restrict__ exb,
                                                     float* __restrict__ invden, int N) {
    int n = blockIdx.x * 4 + (threadIdx.x >> 6);
    int l = threadIdx.x & 63;
    if (n >= N) return;
    int end = rend[n], dg = deg[n], start = end - dg;
    const float4 ad4 = reinterpret_cast<const float4*>(ald)[n];
    float m0 = -3.4e38f, m1 = -3.4e38f, m2 = -3.4e38f, m3 = -3.4e38f;
    for (int i = l; i < dg; i += 64) {
        int s = csr_src[start + i];
        float4 a = reinterpret_cast<const float4*>(als)[s];
        float e0 = a.x + ad4.x; e0 = e0 > 0.f ? e0 : SLOPE * e0;
        float e1 = a.y + ad4.y; e1 = e1 > 0.f ? e1 : SLOPE * e1;
        float e2 = a.z + ad4.z; e2 = e2 > 0.f ? e2 : SLOPE * e2;
        float e3 = a.w + ad4.w; e3 = e3 > 0.f ? e3 : SLOPE * e3;
        m0 = fmaxf(m0, e0); m1 = fmaxf(m1, e1); m2 = fmaxf(m2, e2); m3 = fmaxf(m3, e3);
    }
    for (int off = 32; off; off >>= 1) {
        m0 = fmaxf(m0, __shfl_xor(m0, off));
        m1 = fmaxf(m1, __shfl_xor(m1, off));
        m2 = fmaxf(m2, __shfl_xor(m2, off));
        m3 = fmaxf(m3, __shfl_xor(m3, off));
    }
    float s0 = 0.f, s1 = 0.f, s2 = 0.f, s3 = 0.f;
    for (int i = l; i < dg; i += 64) {
        int s = csr_src[start + i];
        float4 a = reinterpret_cast<const float4*>(als)[s];
        float e0 = a.x + ad4.x; e0 = e0 > 0.f ? e0 : SLOPE * e0;
        float e1 = a.y + ad4.y; e1 = e1 > 0.f ? e1 : SLOPE * e1;
        float e2 = a.z + ad4.z; e2 = e2 > 0.f ? e2 : SLOPE * e2;
        float e3 = a.w + ad4.w; e3 = e3 > 0.f ? e3 : SLOPE * e3;
        float4 ex = { expf(e0 - m0), expf(e1 - m1), expf(e2 - m2), expf(e3 - m3) };
        reinterpret_cast<float4*>(exb)[start + i] = ex;
        s0 += ex.x; s1 += ex.y; s2 += ex.z; s3 += ex.w;
    }
    for (int off = 32; off; off >>= 1) {
        s0 += __shfl_xor(s0, off);
        s1 += __shfl_xor(s1, off);
        s2 += __shfl_xor(s2, off);
        s3 += __shfl_xor(s3, off);
    }
    if (l == 0) {
        float4 iv = { 1.f / (s0 + 1e-16f), 1.f / (s1 + 1e-16f),
                      1.f / (s2 + 1e-16f), 1.f / (s3 + 1e-16f) };
        reinterpret_cast<float4*>(invden)[n] = iv;
    }
}

// ---------------- per-node softmax (H=1) ----------------
__global__ __launch_bounds__(256) void node_softmax1(const int* __restrict__ csr_src,
                                                     const int* __restrict__ rend,
                                                     const int* __restrict__ deg,
                                                     const float* __restrict__ als,
                                                     const float* __restrict__ ald,
                                                     float* __restrict__ exb,
                                                     float* __restrict__ invden, int N) {
    int n = blockIdx.x * 4 + (threadIdx.x >> 6);
    int l = threadIdx.x & 63;
    if (n >= N) return;
    int end = rend[n], dg = deg[n], start = end - dg;
    float ad = ald[n];
    float m = -3.4e38f;
    for (int i = l; i < dg; i += 64) {
        int s = csr_src[start + i];
        float e = als[s] + ad; e = e > 0.f ? e : SLOPE * e;
        m = fmaxf(m, e);
    }
    for (int off = 32; off; off >>= 1) m = fmaxf(m, __shfl_xor(m, off));
    float sum = 0.f;
    for (int i = l; i < dg; i += 64) {
        int s = csr_src[start + i];
        float e = als[s] + ad; e = e > 0.f ? e : SLOPE * e;
        float ex = expf(e - m);
        exb[start + i] = ex;
        sum += ex;
    }
    for (int off = 32; off; off >>= 1) sum += __shfl_xor(sum, off);
    if (l == 0) invden[n] = 1.f / (sum + 1e-16f);
}

// -------- aggregate: block per node, WAVE per edge-row (lane owns 4 features) --------
// WBF: also write bf16 copy of the activation (next layer's GEMM input).
template<bool RES, bool FEAT2, bool WBF>
__global__ __launch_bounds__(256) void aggregate_ln(const int* __restrict__ csr_src,
                                                    const int* __restrict__ rend,
                                                    const int* __restrict__ deg,
                                                    const ushort* __restrict__ feat,
                                                    const float* __restrict__ exb,
                                                    const float* __restrict__ invden,
                                                    const float* __restrict__ bias,
                                                    const float* __restrict__ g,
                                                    const float* __restrict__ bln,
                                                    const float* __restrict__ res,
                                                    float* __restrict__ out,
                                                    ushort* __restrict__ out_bf,
                                                    const float* __restrict__ W2,
                                                    const float* __restrict__ as2,
                                                    const float* __restrict__ ad2,
                                                    float* __restrict__ f2,
                                                    float* __restrict__ als2,
                                                    float* __restrict__ ald2,
                                                    int N) {
    const int n = blockIdx.x;
    const int t = threadIdx.x;
    const int w = t >> 6, l = t & 63;
    const int hh = l >> 4;
    const int end = rend[n], dg = deg[n], start = end - dg;

    float a0 = 0.f, a1 = 0.f, a2 = 0.f, a3 = 0.f;
    int i = start + w;
    for (; i + 4 < end; i += 8) {
        int   s0 = csr_src[i];
        int   s1 = csr_src[i + 4];
        float e0 = exb[(size_t)i * HEADS + hh];
        float e1 = exb[(size_t)(i + 4) * HEADS + hh];
        ushort4 f0 = *(const ushort4*)&feat[(size_t)s0 * F1 + l * 4];
        ushort4 f1 = *(const ushort4*)&feat[(size_t)s1 * F1 + l * 4];
        a0 = fmaf(b2f(f0.x), e0, a0);
        a1 = fmaf(b2f(f0.y), e0, a1);
        a2 = fmaf(b2f(f0.z), e0, a2);
        a3 = fmaf(b2f(f0.w), e0, a3);
        a0 = fmaf(b2f(f1.x), e1, a0);
        a1 = fmaf(b2f(f1.y), e1, a1);
        a2 = fmaf(b2f(f1.z), e1, a2);
        a3 = fmaf(b2f(f1.w), e1, a3);
    }
    if (i < end) {
        int   s0 = csr_src[i];
        float e0 = exb[(size_t)i * HEADS + hh];
        ushort4 f0 = *(const ushort4*)&feat[(size_t)s0 * F1 + l * 4];
        a0 = fmaf(b2f(f0.x), e0, a0);
        a1 = fmaf(b2f(f0.y), e0, a1);
        a2 = fmaf(b2f(f0.z), e0, a2);
        a3 = fmaf(b2f(f0.w), e0, a3);
    }

    __shared__ __align__(16) float sm[4][256];
    *(float4*)&sm[w][l * 4] = float4{ a0, a1, a2, a3 };
    __syncthreads();

    float acc = sm[0][t] + sm[1][t] + sm[2][t] + sm[3][t];
    float v = acc * invden[n * HEADS + (t >> 6)] + bias[t];

    const int h = t >> 6, lt = t & 63;
    __shared__ float sred[4];
    __shared__ float s20[4], s21[4];
    float smv = v;
    for (int off = 32; off; off >>= 1) smv += __shfl_down(smv, off);
    if (lt == 0) sred[h] = smv;
    __syncthreads();
    float mu = (sred[0] + sred[1] + sred[2] + sred[3]) * (1.f / F1);
    __syncthreads();
    float dv = (v - mu) * (v - mu);
    for (int off = 32; off; off >>= 1) dv += __shfl_down(dv, off);
    if (lt == 0) sred[h] = dv;
    __syncthreads();
    float var = (sred[0] + sred[1] + sred[2] + sred[3]) * (1.f / F1);
    float y = (v - mu) * rsqrtf(var + LN_EPS) * g[t] + bln[t];
    if (RES) y += res[(size_t)n * F1 + t];
    y = y > 0.f ? y : expm1f(y);
    if (!FEAT2) {
        out[(size_t)n * F1 + t] = y;
        if (WBF) out_bf[(size_t)n * F1 + t] = f2b(y);
    } else {
        float c0 = y * W2[t * 2 + 0];
        float c1 = y * W2[t * 2 + 1];
        for (int off = 32; off; off >>= 1) {
            c0 += __shfl_down(c0, off);
            c1 += __shfl_down(c1, off);
        }
        if (lt == 0) { s20[h] = c0; s21[h] = c1; }
        __syncthreads();
        if (t == 0) {
            float f0 = s20[0] + s20[1] + s20[2] + s20[3];
            float f1 = s21[0] + s21[1] + s21[2] + s21[3];
            f2[(size_t)n * 2 + 0] = f0;
            f2[(size_t)n * 2 + 1] = f1;
            als2[n] = f0 * as2[0] + f1 * as2[1];
            ald2[n] = f0 * ad2[0] + f1 * ad2[1];
        }
    }
}

// ---------------- layer2 aggregation: wave per node, 2 features ----------------
__global__ __launch_bounds__(256) void aggregate2(const int* __restrict__ csr_src,
                                                  const int* __restrict__ rend,
                                                  const int* __restrict__ deg,
                                                  const float* __restrict__ f2,
                                                  const float* __restrict__ exb,
                                                  const float* __restrict__ invden,
                                                  const float* __restrict__ b2,
                                                  float* __restrict__ out, int N) {
    int n = blockIdx.x * 4 + (threadIdx.x >> 6);
    int l = threadIdx.x & 63;
    if (n >= N) return;
    int end = rend[n], dg = deg[n], start = end - dg;
    float iv = invden[n];
    float a0 = 0.f, a1 = 0.f;
    for (int i = l; i < dg; i += 64) {
        int s = csr_src[start + i];
        float a = exb[start + i] * iv;
        float2 f = reinterpret_cast<const float2*>(f2)[s];
        a0 = fmaf(f.x, a, a0);
        a1 = fmaf(f.y, a, a1);
    }
    for (int off = 32; off; off >>= 1) {
        a0 += __shfl_xor(a0, off);
        a1 += __shfl_xor(a1, off);
    }
    if (l == 0) {
        out[(size_t)n * 2 + 0] = a0 + b2[0];
        out[(size_t)n * 2 + 1] = a1 + b2[1];
    }
}

extern "C" void kernel_launch(void* const* d_in, const int* in_sizes, int n_in,
                              void* d_out, int out_size, void* d_ws, size_t ws_size,
                              hipStream_t stream) {
    const float* x    = (const float*)d_in[0];
    const int*   ei   = (const int*)d_in[1];
    const float* Wp   = (const float*)d_in[2];
    const float* bp   = (const float*)d_in[3];
    const float* W0   = (const float*)d_in[4];
    const float* as0  = (const float*)d_in[5];
    const float* ad0  = (const float*)d_in[6];
    const float* b0   = (const float*)d_in[7];
    const float* W1   = (const float*)d_in[8];
    const float* as1  = (const float*)d_in[9];
    const float* ad1  = (const float*)d_in[10];
    const float* b1   = (const float*)d_in[11];
    const float* W2   = (const float*)d_in[12];
    const float* as2  = (const float*)d_in[13];
    const float* ad2  = (const float*)d_in[14];
    const float* b2   = (const float*)d_in[15];
    const float* ln_g = (const float*)d_in[16];
    const float* ln_b = (const float*)d_in[17];
    float* out = (float*)d_out;

    const int N    = in_sizes[0] / IN_DIM;   // 50000
    const int E    = in_sizes[1] / 2;        // 800000
    const int Etot = E + N;

    char* wptr = (char*)d_ws;
    auto alloc = [&](size_t bytes) -> void* {
        void* p = wptr;
        wptr += (bytes + 255) & ~(size_t)255;
        return p;
    };
    ushort* P      = (ushort*)alloc(sizeof(ushort) * (size_t)N * HID);
    ushort* F      = (ushort*)alloc(sizeof(ushort) * (size_t)N * F1);
    float*  A      = (float*)alloc(sizeof(float) * (size_t)N * F1);    // layer0 act (f32, residual)
    ushort* Ab     = (ushort*)alloc(sizeof(ushort) * (size_t)N * F1);  // layer0 act (bf16, GEMM in)
    float*  als    = (float*)alloc(sizeof(float) * (size_t)N * HEADS);
    float*  ald    = (float*)alloc(sizeof(float) * (size_t)N * HEADS);
    float*  invden = (float*)alloc(sizeof(float) * (size_t)N * HEADS);
    float*  exb    = (float*)alloc(sizeof(float) * (size_t)Etot * HEADS);
    float*  f2     = (float*)alloc(sizeof(float) * (size_t)N * 2);
    ushort* Wt0    = (ushort*)alloc(sizeof(ushort) * (size_t)F1 * HID);   // [256][64]
    ushort* Wt1    = (ushort*)alloc(sizeof(ushort) * (size_t)F1 * F1);    // [256][256]
    int*    deg    = (int*)alloc(sizeof(int) * (size_t)N);
    int*    rend   = (int*)alloc(sizeof(int) * (size_t)N);
    int*    wcur   = (int*)alloc(sizeof(int) * (size_t)N);
    int*    csum   = (int*)alloc(sizeof(int) * 256);
    int*    csrs   = (int*)alloc(sizeof(int) * (size_t)Etot);

    const int eb   = (Etot + 255) / 256;
    const int nb   = (N + 255) / 256;
    const int nb4  = (N + 3) / 4;
    const int nchunks = (N + 1023) / 1024;
    const int mb64 = (N + 63) / 64;
    const int mb32 = (N + 31) / 32;

    // -------- CSR build --------
    hipMemsetAsync(deg, 0, sizeof(int) * (size_t)N, stream);
    csr_count<<<eb, 256, 0, stream>>>(ei, E, Etot, deg);
    scan1<<<nchunks, 256, 0, stream>>>(deg, rend, csum, N);
    scan2<<<1, 256, 0, stream>>>(csum, nchunks);
    scan3<<<nb, 256, 0, stream>>>(deg, rend, csum, wcur, N);
    csr_fill<<<eb, 256, 0, stream>>>(ei, E, Etot, wcur, csrs);

    // -------- weight transposes (bf16) --------
    cvt_transpose<<<(HID * F1 + 255) / 256, 256, 0, stream>>>(W0, Wt0, HID, F1);
    cvt_transpose<<<(F1 * F1 + 255) / 256, 256, 0, stream>>>(W1, Wt1, F1, F1);

    // -------- input projection: P = bf16(x @ Wp + bp) --------
    gemm_tile<true, true><<<dim3(mb64, 1), 256, 0, stream>>>(
        x, Wp, bp, P, N, HID, IN_DIM);

    // ================= layer 0 =================
    mfma_gemm<HID, true><<<mb32, 256, 0, stream>>>(P, Wt0, as0, ad0, F, als, ald, N);
    node_softmax4<<<nb4, 256, 0, stream>>>(csrs, rend, deg, als, ald, exb, invden, N);
    aggregate_ln<false, false, true><<<N, 256, 0, stream>>>(csrs, rend, deg, F, exb, invden,
        b0, ln_g, ln_b, nullptr, A, Ab, nullptr, nullptr, nullptr, nullptr, nullptr, nullptr, N);

    // ================= layer 1 =================
    mfma_gemm<F1, true><<<mb32, 256, 0, stream>>>(Ab, Wt1, as1, ad1, F, als, ald, N);
    node_softmax4<<<nb4, 256, 0, stream>>>(csrs, rend, deg, als, ald, exb, invden, N);
    aggregate_ln<true, true, false><<<N, 256, 0, stream>>>(csrs, rend, deg, F, exb, invden,
        b1, ln_g, ln_b, A, nullptr, nullptr, W2, as2, ad2, f2, als, ald, N);

    // ================= layer 2 (heads=1, C=2) =================
    node_softmax1<<<nb4, 256, 0, stream>>>(csrs, rend, deg, als, ald, exb, invden, N);
    aggregate2<<<nb4, 256, 0, stream>>>(csrs, rend, deg, f2, exb, invden, b2, out, N);
}

// Round 8
// 436.500 us; speedup vs baseline: 6.7257x; 1.2808x over previous
//
#include <hip/hip_runtime.h>
#include <hip/hip_bf16.h>
#include <cmath>
#include <cfloat>

constexpr int IN_DIM = 184;
constexpr int HID    = 64;
constexpr int HEADS  = 4;
constexpr int F1     = HEADS * HID;   // 256
constexpr float SLOPE = 0.2f;
constexpr float LN_EPS = 1e-5f;

using short8 = __attribute__((ext_vector_type(8))) short;
using f32x4  = __attribute__((ext_vector_type(4))) float;

__device__ inline float b2f(ushort u) {
    return __uint_as_float(((unsigned)u) << 16);
}
__device__ inline ushort f2b(float f) {
    __hip_bfloat16 b = __float2bfloat16(f);
    return *reinterpret_cast<ushort*>(&b);
}
__device__ inline short8 mk8(ushort4 lo, ushort4 hi) {
    short8 v;
    v[0] = (short)lo.x; v[1] = (short)lo.y; v[2] = (short)lo.z; v[3] = (short)lo.w;
    v[4] = (short)hi.x; v[5] = (short)hi.y; v[6] = (short)hi.z; v[7] = (short)hi.w;
    return v;
}
__device__ inline float lrelu(float e) { return e > 0.f ? e : SLOPE * e; }

// ---------------- W -> Wt bf16 transpose ----------------
__global__ __launch_bounds__(256) void cvt_transpose(const float* __restrict__ W,
                                                     ushort* __restrict__ Wt,
                                                     int K, int NC) {
    int idx = blockIdx.x * 256 + threadIdx.x;
    if (idx >= K * NC) return;
    int k = idx / NC, c = idx - k * NC;
    Wt[(size_t)c * K + k] = f2b(W[idx]);
}

// ================= MFMA bf16 GEMM: Y[M,256] = X[M,K] @ W[K,256] =================
template<int K, bool LOGITS>
__global__ __launch_bounds__(256) void mfma_gemm(const ushort* __restrict__ X,
                                                 const ushort* __restrict__ Wt,
                                                 const float* __restrict__ as_,
                                                 const float* __restrict__ ad_,
                                                 ushort* __restrict__ Y,
                                                 float* __restrict__ als,
                                                 float* __restrict__ ald,
                                                 int M) {
    const int tid = threadIdx.x;
    const int w = tid >> 6, l = tid & 63;
    const int lr = l & 15, q = l >> 4;
    const int row0 = blockIdx.x * 32;

    f32x4 acc00 = {0,0,0,0}, acc01 = {0,0,0,0}, acc02 = {0,0,0,0}, acc03 = {0,0,0,0};
    f32x4 acc10 = {0,0,0,0}, acc11 = {0,0,0,0}, acc12 = {0,0,0,0}, acc13 = {0,0,0,0};

    const int rA0 = min(row0 + lr, M - 1);
    const int rA1 = min(row0 + 16 + lr, M - 1);
    const int colb = w * 64 + lr;

#pragma unroll
    for (int k0 = 0; k0 < K; k0 += 32) {
        const ushort* p0 = &X[(size_t)rA0 * K + k0 + 4 * q];
        const ushort* p1 = &X[(size_t)rA1 * K + k0 + 4 * q];
        short8 a0 = mk8(*(const ushort4*)p0, *(const ushort4*)(p0 + 16));
        short8 a1 = mk8(*(const ushort4*)p1, *(const ushort4*)(p1 + 16));

        const ushort* pb0 = &Wt[(size_t)(colb +  0) * K + k0 + 4 * q];
        const ushort* pb1 = &Wt[(size_t)(colb + 16) * K + k0 + 4 * q];
        const ushort* pb2 = &Wt[(size_t)(colb + 32) * K + k0 + 4 * q];
        const ushort* pb3 = &Wt[(size_t)(colb + 48) * K + k0 + 4 * q];
        short8 b0 = mk8(*(const ushort4*)pb0, *(const ushort4*)(pb0 + 16));
        short8 b1 = mk8(*(const ushort4*)pb1, *(const ushort4*)(pb1 + 16));
        short8 b2 = mk8(*(const ushort4*)pb2, *(const ushort4*)(pb2 + 16));
        short8 b3 = mk8(*(const ushort4*)pb3, *(const ushort4*)(pb3 + 16));

        acc00 = __builtin_amdgcn_mfma_f32_16x16x32_bf16(a0, b0, acc00, 0, 0, 0);
        acc01 = __builtin_amdgcn_mfma_f32_16x16x32_bf16(a0, b1, acc01, 0, 0, 0);
        acc02 = __builtin_amdgcn_mfma_f32_16x16x32_bf16(a0, b2, acc02, 0, 0, 0);
        acc03 = __builtin_amdgcn_mfma_f32_16x16x32_bf16(a0, b3, acc03, 0, 0, 0);
        acc10 = __builtin_amdgcn_mfma_f32_16x16x32_bf16(a1, b0, acc10, 0, 0, 0);
        acc11 = __builtin_amdgcn_mfma_f32_16x16x32_bf16(a1, b1, acc11, 0, 0, 0);
        acc12 = __builtin_amdgcn_mfma_f32_16x16x32_bf16(a1, b2, acc12, 0, 0, 0);
        acc13 = __builtin_amdgcn_mfma_f32_16x16x32_bf16(a1, b3, acc13, 0, 0, 0);
    }

    f32x4 accs[2][4] = { { acc00, acc01, acc02, acc03 },
                         { acc10, acc11, acc12, acc13 } };

#pragma unroll
    for (int rt = 0; rt < 2; ++rt) {
#pragma unroll
        for (int r = 0; r < 4; ++r) {
            int row = row0 + rt * 16 + q * 4 + r;
            if (row < M) {
#pragma unroll
                for (int ct = 0; ct < 4; ++ct)
                    Y[(size_t)row * 256 + w * 64 + ct * 16 + lr] = f2b(accs[rt][ct][r]);
            }
        }
    }

    if (LOGITS) {
        float asv[4], adv[4];
#pragma unroll
        for (int ct = 0; ct < 4; ++ct) {
            asv[ct] = as_[w * 64 + ct * 16 + lr];
            adv[ct] = ad_[w * 64 + ct * 16 + lr];
        }
#pragma unroll
        for (int rt = 0; rt < 2; ++rt) {
#pragma unroll
            for (int r = 0; r < 4; ++r) {
                float ls = 0.f, ld_ = 0.f;
#pragma unroll
                for (int ct = 0; ct < 4; ++ct) {
                    ls  = fmaf(accs[rt][ct][r], asv[ct], ls);
                    ld_ = fmaf(accs[rt][ct][r], adv[ct], ld_);
                }
                for (int off = 8; off; off >>= 1) {
                    ls  += __shfl_xor(ls, off);
                    ld_ += __shfl_xor(ld_, off);
                }
                int row = row0 + rt * 16 + q * 4 + r;
                if (lr == 0 && row < M) {
                    als[row * HEADS + w] = ls;
                    ald[row * HEADS + w] = ld_;
                }
            }
        }
    }
}

// ================= tiled f32 GEMM (input projection only) =================
template<bool BIAS, bool OBF16>
__global__ __launch_bounds__(256) void gemm_tile(const float* __restrict__ X,
                                                 const float* __restrict__ W,
                                                 const float* __restrict__ bias,
                                                 void* __restrict__ Yv,
                                                 int M, int N, int K) {
    __shared__ __align__(16) float xs[32][68];
    __shared__ __align__(16) float ws[32][68];
    const int row0 = blockIdx.x * 64;
    const int n0   = blockIdx.y * 64;
    const int tid  = threadIdx.x;
    const int tx   = tid & 15, ty = tid >> 4;

    float acc[4][4] = {};

    for (int k0 = 0; k0 < K; k0 += 32) {
        for (int i = tid; i < 64 * 32; i += 256) {
            int r = i >> 5, kk = i & 31;
            int gr = row0 + r, gk = k0 + kk;
            xs[kk][r] = (gr < M && gk < K) ? X[(size_t)gr * K + gk] : 0.f;
        }
        for (int i = tid; i < 32 * 64; i += 256) {
            int kk = i >> 6, c = i & 63;
            int gk = k0 + kk;
            ws[kk][c] = (gk < K) ? W[(size_t)gk * N + n0 + c] : 0.f;
        }
        __syncthreads();
#pragma unroll 4
        for (int kk = 0; kk < 32; ++kk) {
            float4 xv = *(const float4*)&xs[kk][ty * 4];
            float4 wv = *(const float4*)&ws[kk][tx * 4];
            acc[0][0] = fmaf(xv.x, wv.x, acc[0][0]);
            acc[0][1] = fmaf(xv.x, wv.y, acc[0][1]);
            acc[0][2] = fmaf(xv.x, wv.z, acc[0][2]);
            acc[0][3] = fmaf(xv.x, wv.w, acc[0][3]);
            acc[1][0] = fmaf(xv.y, wv.x, acc[1][0]);
            acc[1][1] = fmaf(xv.y, wv.y, acc[1][1]);
            acc[1][2] = fmaf(xv.y, wv.z, acc[1][2]);
            acc[1][3] = fmaf(xv.y, wv.w, acc[1][3]);
            acc[2][0] = fmaf(xv.z, wv.x, acc[2][0]);
            acc[2][1] = fmaf(xv.z, wv.y, acc[2][1]);
            acc[2][2] = fmaf(xv.z, wv.z, acc[2][2]);
            acc[2][3] = fmaf(xv.z, wv.w, acc[2][3]);
            acc[3][0] = fmaf(xv.w, wv.x, acc[3][0]);
            acc[3][1] = fmaf(xv.w, wv.y, acc[3][1]);
            acc[3][2] = fmaf(xv.w, wv.z, acc[3][2]);
            acc[3][3] = fmaf(xv.w, wv.w, acc[3][3]);
        }
        __syncthreads();
    }

    float bv[4];
#pragma unroll
    for (int j = 0; j < 4; ++j) bv[j] = BIAS ? bias[n0 + tx * 4 + j] : 0.f;

#pragma unroll
    for (int i = 0; i < 4; ++i) {
        int gr = row0 + ty * 4 + i;
        if (gr < M) {
            if (!OBF16) {
                float4 o = { acc[i][0] + bv[0], acc[i][1] + bv[1],
                             acc[i][2] + bv[2], acc[i][3] + bv[3] };
                *(float4*)&((float*)Yv)[(size_t)gr * N + n0 + tx * 4] = o;
            } else {
                ushort4 o = { f2b(acc[i][0] + bv[0]), f2b(acc[i][1] + bv[1]),
                              f2b(acc[i][2] + bv[2]), f2b(acc[i][3] + bv[3]) };
                *(ushort4*)&((ushort*)Yv)[(size_t)gr * N + n0 + tx * 4] = o;
            }
        }
    }
}

// ---------------- CSR build ----------------
__device__ inline void edge_sd(const int* __restrict__ ei, int E, int idx, int& s, int& d) {
    if (idx < E) { s = ei[idx]; d = ei[E + idx]; }
    else         { s = idx - E; d = idx - E; }
}

__global__ __launch_bounds__(256) void csr_count(const int* __restrict__ ei, int E, int Etot,
                                                 int* __restrict__ deg) {
    int idx = blockIdx.x * 256 + threadIdx.x;
    if (idx >= Etot) return;
    int s, d; edge_sd(ei, E, idx, s, d);
    atomicAdd(&deg[d], 1);
}

__global__ __launch_bounds__(256) void scan1(const int* __restrict__ deg, int* __restrict__ out,
                                             int* __restrict__ csum, int N) {
    __shared__ int s[256];
    int t = threadIdx.x;
    int idx0 = blockIdx.x * 1024 + t * 4;
    int v[4];
#pragma unroll
    for (int i = 0; i < 4; ++i) { int id = idx0 + i; v[i] = (id < N) ? deg[id] : 0; }
    int sum = v[0] + v[1] + v[2] + v[3];
    s[t] = sum; __syncthreads();
    for (int off = 1; off < 256; off <<= 1) {
        int x = (t >= off) ? s[t - off] : 0;
        __syncthreads();
        s[t] += x;
        __syncthreads();
    }
    int run = (t == 0) ? 0 : s[t - 1];
#pragma unroll
    for (int i = 0; i < 4; ++i) {
        run += v[i];
        int id = idx0 + i;
        if (id < N) out[id] = run;
    }
    if (t == 255) csum[blockIdx.x] = s[255];
}

__global__ __launch_bounds__(256) void scan2(int* __restrict__ csum, int M) {
    __shared__ int s[256];
    int t = threadIdx.x;
    s[t] = (t < M) ? csum[t] : 0;
    __syncthreads();
    for (int off = 1; off < 256; off <<= 1) {
        int x = (t >= off) ? s[t - off] : 0;
        __syncthreads();
        s[t] += x;
        __syncthreads();
    }
    if (t < M) csum[t] = s[t];
}

__global__ __launch_bounds__(256) void scan3(const int* __restrict__ deg, int* __restrict__ rend,
                                             const int* __restrict__ csum, int* __restrict__ wcur, int N) {
    int id = blockIdx.x * 256 + threadIdx.x;
    if (id >= N) return;
    int chunk = id >> 10;
    int off = (chunk == 0) ? 0 : csum[chunk - 1];
    int e = rend[id] + off;
    rend[id] = e;
    wcur[id] = e - deg[id];
}

__global__ __launch_bounds__(256) void csr_fill(const int* __restrict__ ei, int E, int Etot,
                                                int* __restrict__ wcur, int* __restrict__ csr_src) {
    int idx = blockIdx.x * 256 + threadIdx.x;
    if (idx >= Etot) return;
    int s, d; edge_sd(ei, E, idx, s, d);
    int pos = atomicAdd(&wcur[d], 1);
    csr_src[pos] = s;
}

// ======== fused softmax + gather + LN(+res)+ELU, WAVE per node ========
// lane l owns features 4l..4l+3 (head l>>4). No __syncthreads; per-wave LDS slice.
// FEAT2: write nf2[n] = {f0, f1, als2, ald2} instead of the 256-wide act.
template<bool RES, bool FEAT2, bool WBF>
__global__ __launch_bounds__(256) void aggregate_fused(const int* __restrict__ csr_src,
                                                       const int* __restrict__ rend,
                                                       const int* __restrict__ deg_,
                                                       const ushort* __restrict__ feat,
                                                       const float* __restrict__ als,
                                                       const float* __restrict__ ald,
                                                       const float* __restrict__ bias,
                                                       const float* __restrict__ g,
                                                       const float* __restrict__ bln,
                                                       const float* __restrict__ res,
                                                       float* __restrict__ out,
                                                       ushort* __restrict__ out_bf,
                                                       const float* __restrict__ W2,
                                                       const float* __restrict__ as2,
                                                       const float* __restrict__ ad2,
                                                       float4* __restrict__ nf2,
                                                       int N) {
    __shared__ __align__(16) float alds[4][64][4];
    __shared__ int srcs[4][64];
    const int w = threadIdx.x >> 6, l = threadIdx.x & 63;
    const int n = blockIdx.x * 4 + w;
    if (n >= N) return;
    const int dg = deg_[n], end = rend[n], start = end - dg;
    const int hh = l >> 4;
    const float4 ad4 = ((const float4*)ald)[n];

    float acc0 = 0.f, acc1 = 0.f, acc2 = 0.f, acc3 = 0.f;

    auto gather_chunk = [&](int cnt) {
        int j = 0;
        for (; j + 4 <= cnt; j += 4) {
            int s0 = srcs[w][j],     s1 = srcs[w][j + 1];
            int s2 = srcs[w][j + 2], s3 = srcs[w][j + 3];
            float a0 = alds[w][j][hh],     a1 = alds[w][j + 1][hh];
            float a2 = alds[w][j + 2][hh], a3 = alds[w][j + 3][hh];
            ushort4 f0 = *(const ushort4*)&feat[(size_t)s0 * F1 + l * 4];
            ushort4 f1 = *(const ushort4*)&feat[(size_t)s1 * F1 + l * 4];
            ushort4 f2v = *(const ushort4*)&feat[(size_t)s2 * F1 + l * 4];
            ushort4 f3 = *(const ushort4*)&feat[(size_t)s3 * F1 + l * 4];
            acc0 = fmaf(b2f(f0.x), a0, acc0); acc1 = fmaf(b2f(f0.y), a0, acc1);
            acc2 = fmaf(b2f(f0.z), a0, acc2); acc3 = fmaf(b2f(f0.w), a0, acc3);
            acc0 = fmaf(b2f(f1.x), a1, acc0); acc1 = fmaf(b2f(f1.y), a1, acc1);
            acc2 = fmaf(b2f(f1.z), a1, acc2); acc3 = fmaf(b2f(f1.w), a1, acc3);
            acc0 = fmaf(b2f(f2v.x), a2, acc0); acc1 = fmaf(b2f(f2v.y), a2, acc1);
            acc2 = fmaf(b2f(f2v.z), a2, acc2); acc3 = fmaf(b2f(f2v.w), a2, acc3);
            acc0 = fmaf(b2f(f3.x), a3, acc0); acc1 = fmaf(b2f(f3.y), a3, acc1);
            acc2 = fmaf(b2f(f3.z), a3, acc2); acc3 = fmaf(b2f(f3.w), a3, acc3);
        }
        for (; j < cnt; ++j) {
            int s0 = srcs[w][j];
            float a0 = alds[w][j][hh];
            ushort4 f0 = *(const ushort4*)&feat[(size_t)s0 * F1 + l * 4];
            acc0 = fmaf(b2f(f0.x), a0, acc0); acc1 = fmaf(b2f(f0.y), a0, acc1);
            acc2 = fmaf(b2f(f0.z), a0, acc2); acc3 = fmaf(b2f(f0.w), a0, acc3);
        }
    };

    if (dg <= 64) {
        int s = 0;
        float4 e = { -FLT_MAX, -FLT_MAX, -FLT_MAX, -FLT_MAX };
        if (l < dg) {
            s = csr_src[start + l];
            float4 a = ((const float4*)als)[s];
            e.x = lrelu(a.x + ad4.x); e.y = lrelu(a.y + ad4.y);
            e.z = lrelu(a.z + ad4.z); e.w = lrelu(a.w + ad4.w);
        }
        float4 m = e;
        for (int off = 32; off; off >>= 1) {
            m.x = fmaxf(m.x, __shfl_xor(m.x, off));
            m.y = fmaxf(m.y, __shfl_xor(m.y, off));
            m.z = fmaxf(m.z, __shfl_xor(m.z, off));
            m.w = fmaxf(m.w, __shfl_xor(m.w, off));
        }
        float4 ex = { 0.f, 0.f, 0.f, 0.f };
        if (l < dg) {
            ex.x = expf(e.x - m.x); ex.y = expf(e.y - m.y);
            ex.z = expf(e.z - m.z); ex.w = expf(e.w - m.w);
        }
        float4 sum = ex;
        for (int off = 32; off; off >>= 1) {
            sum.x += __shfl_xor(sum.x, off);
            sum.y += __shfl_xor(sum.y, off);
            sum.z += __shfl_xor(sum.z, off);
            sum.w += __shfl_xor(sum.w, off);
        }
        float4 al = { ex.x / (sum.x + 1e-16f), ex.y / (sum.y + 1e-16f),
                      ex.z / (sum.z + 1e-16f), ex.w / (sum.w + 1e-16f) };
        *(float4*)&alds[w][l][0] = al;
        srcs[w][l] = s;
        __builtin_amdgcn_s_waitcnt(0);   // lgkm drain before same-wave LDS read
        gather_chunk(dg);
    } else {
        // pass 1: global max
        float4 m = { -FLT_MAX, -FLT_MAX, -FLT_MAX, -FLT_MAX };
        for (int i = l; i < dg; i += 64) {
            int s = csr_src[start + i];
            float4 a = ((const float4*)als)[s];
            m.x = fmaxf(m.x, lrelu(a.x + ad4.x));
            m.y = fmaxf(m.y, lrelu(a.y + ad4.y));
            m.z = fmaxf(m.z, lrelu(a.z + ad4.z));
            m.w = fmaxf(m.w, lrelu(a.w + ad4.w));
        }
        for (int off = 32; off; off >>= 1) {
            m.x = fmaxf(m.x, __shfl_xor(m.x, off));
            m.y = fmaxf(m.y, __shfl_xor(m.y, off));
            m.z = fmaxf(m.z, __shfl_xor(m.z, off));
            m.w = fmaxf(m.w, __shfl_xor(m.w, off));
        }
        // pass 2: global sum
        float4 sum = { 0.f, 0.f, 0.f, 0.f };
        for (int i = l; i < dg; i += 64) {
            int s = csr_src[start + i];
            float4 a = ((const float4*)als)[s];
            sum.x += expf(lrelu(a.x + ad4.x) - m.x);
            sum.y += expf(lrelu(a.y + ad4.y) - m.y);
            sum.z += expf(lrelu(a.z + ad4.z) - m.z);
            sum.w += expf(lrelu(a.w + ad4.w) - m.w);
        }
        for (int off = 32; off; off >>= 1) {
            sum.x += __shfl_xor(sum.x, off);
            sum.y += __shfl_xor(sum.y, off);
            sum.z += __shfl_xor(sum.z, off);
            sum.w += __shfl_xor(sum.w, off);
        }
        float4 inv = { 1.f / (sum.x + 1e-16f), 1.f / (sum.y + 1e-16f),
                       1.f / (sum.z + 1e-16f), 1.f / (sum.w + 1e-16f) };
        // per chunk: alpha -> LDS, then gather
        for (int c0 = start; c0 < end; c0 += 64) {
            int cnt = min(64, end - c0);
            if (l < cnt) {
                int s = csr_src[c0 + l];
                float4 a = ((const float4*)als)[s];
                float4 al = { expf(lrelu(a.x + ad4.x) - m.x) * inv.x,
                              expf(lrelu(a.y + ad4.y) - m.y) * inv.y,
                              expf(lrelu(a.z + ad4.z) - m.z) * inv.z,
                              expf(lrelu(a.w + ad4.w) - m.w) * inv.w };
                *(float4*)&alds[w][l][0] = al;
                srcs[w][l] = s;
            }
            __builtin_amdgcn_s_waitcnt(0);
            gather_chunk(cnt);
        }
    }

    // ---- epilogue: bias + LN (+res) + ELU, wave-local ----
    float4 bb = ((const float4*)bias)[l];
    float4 v = { acc0 + bb.x, acc1 + bb.y, acc2 + bb.z, acc3 + bb.w };
    float sm = v.x + v.y + v.z + v.w;
    for (int off = 32; off; off >>= 1) sm += __shfl_xor(sm, off);
    float mu = sm * (1.f / F1);
    float dx = v.x - mu, dy = v.y - mu, dz = v.z - mu, dw = v.w - mu;
    float dv = dx * dx + dy * dy + dz * dz + dw * dw;
    for (int off = 32; off; off >>= 1) dv += __shfl_xor(dv, off);
    float rstd = rsqrtf(dv * (1.f / F1) + LN_EPS);
    float4 gg = ((const float4*)g)[l];
    float4 lb = ((const float4*)bln)[l];
    float4 y = { dx * rstd * gg.x + lb.x, dy * rstd * gg.y + lb.y,
                 dz * rstd * gg.z + lb.z, dw * rstd * gg.w + lb.w };
    if (RES) {
        float4 r = ((const float4*)res)[(size_t)n * 64 + l];
        y.x += r.x; y.y += r.y; y.z += r.z; y.w += r.w;
    }
    y.x = y.x > 0.f ? y.x : expm1f(y.x);
    y.y = y.y > 0.f ? y.y : expm1f(y.y);
    y.z = y.z > 0.f ? y.z : expm1f(y.z);
    y.w = y.w > 0.f ? y.w : expm1f(y.w);

    if (!FEAT2) {
        ((float4*)out)[(size_t)n * 64 + l] = y;
        if (WBF) {
            ushort4 o = { f2b(y.x), f2b(y.y), f2b(y.z), f2b(y.w) };
            ((ushort4*)out_bf)[(size_t)n * 64 + l] = o;
        }
    } else {
        const float4* W24 = (const float4*)W2;
        float4 wa = W24[l * 2], wb = W24[l * 2 + 1];
        float c0 = y.x * wa.x + y.y * wa.z + y.z * wb.x + y.w * wb.z;
        float c1 = y.x * wa.y + y.y * wa.w + y.z * wb.y + y.w * wb.w;
        for (int off = 32; off; off >>= 1) {
            c0 += __shfl_xor(c0, off);
            c1 += __shfl_xor(c1, off);
        }
        if (l == 0) {
            float4 o = { c0, c1,
                         c0 * as2[0] + c1 * as2[1],
                         c0 * ad2[0] + c1 * ad2[1] };
            nf2[n] = o;
        }
    }
}

// ---- layer 2 fully fused: softmax(H=1) + 2-feature gather, wave per node ----
__global__ __launch_bounds__(256) void layer2_fused(const int* __restrict__ csr_src,
                                                    const int* __restrict__ rend,
                                                    const int* __restrict__ deg_,
                                                    const float4* __restrict__ nf2,
                                                    const float* __restrict__ b2,
                                                    float* __restrict__ out, int N) {
    const int w = threadIdx.x >> 6, l = threadIdx.x & 63;
    const int n = blockIdx.x * 4 + w;
    if (n >= N) return;
    const int dg = deg_[n], end = rend[n], start = end - dg;
    const float ad = nf2[n].w;

    float a0 = 0.f, a1 = 0.f;
    if (dg <= 64) {
        float e = -FLT_MAX;
        float f0 = 0.f, f1 = 0.f;
        if (l < dg) {
            int s = csr_src[start + l];
            float4 v = nf2[s];
            e = lrelu(v.z + ad);
            f0 = v.x; f1 = v.y;
        }
        float m = e;
        for (int off = 32; off; off >>= 1) m = fmaxf(m, __shfl_xor(m, off));
        float ex = (l < dg) ? expf(e - m) : 0.f;
        float sum = ex;
        for (int off = 32; off; off >>= 1) sum += __shfl_xor(sum, off);
        float al = ex / (sum + 1e-16f);
        a0 = f0 * al; a1 = f1 * al;
    } else {
        float m = -FLT_MAX;
        for (int i = l; i < dg; i += 64) {
            int s = csr_src[start + i];
            m = fmaxf(m, lrelu(nf2[s].z + ad));
        }
        for (int off = 32; off; off >>= 1) m = fmaxf(m, __shfl_xor(m, off));
        float sum = 0.f;
        for (int i = l; i < dg; i += 64) {
            int s = csr_src[start + i];
            sum += expf(lrelu(nf2[s].z + ad) - m);
        }
        for (int off = 32; off; off >>= 1) sum += __shfl_xor(sum, off);
        float inv = 1.f / (sum + 1e-16f);
        for (int i = l; i < dg; i += 64) {
            int s = csr_src[start + i];
            float4 v = nf2[s];
            float al = expf(lrelu(v.z + ad) - m) * inv;
            a0 = fmaf(v.x, al, a0);
            a1 = fmaf(v.y, al, a1);
        }
    }
    for (int off = 32; off; off >>= 1) {
        a0 += __shfl_xor(a0, off);
        a1 += __shfl_xor(a1, off);
    }
    if (l == 0) {
        out[(size_t)n * 2 + 0] = a0 + b2[0];
        out[(size_t)n * 2 + 1] = a1 + b2[1];
    }
}

extern "C" void kernel_launch(void* const* d_in, const int* in_sizes, int n_in,
                              void* d_out, int out_size, void* d_ws, size_t ws_size,
                              hipStream_t stream) {
    const float* x    = (const float*)d_in[0];
    const int*   ei   = (const int*)d_in[1];
    const float* Wp   = (const float*)d_in[2];
    const float* bp   = (const float*)d_in[3];
    const float* W0   = (const float*)d_in[4];
    const float* as0  = (const float*)d_in[5];
    const float* ad0  = (const float*)d_in[6];
    const float* b0   = (const float*)d_in[7];
    const float* W1   = (const float*)d_in[8];
    const float* as1  = (const float*)d_in[9];
    const float* ad1  = (const float*)d_in[10];
    const float* b1   = (const float*)d_in[11];
    const float* W2   = (const float*)d_in[12];
    const float* as2  = (const float*)d_in[13];
    const float* ad2  = (const float*)d_in[14];
    const float* b2   = (const float*)d_in[15];
    const float* ln_g = (const float*)d_in[16];
    const float* ln_b = (const float*)d_in[17];
    float* out = (float*)d_out;

    const int N    = in_sizes[0] / IN_DIM;   // 50000
    const int E    = in_sizes[1] / 2;        // 800000
    const int Etot = E + N;

    char* wptr = (char*)d_ws;
    auto alloc = [&](size_t bytes) -> void* {
        void* p = wptr;
        wptr += (bytes + 255) & ~(size_t)255;
        return p;
    };
    ushort* P      = (ushort*)alloc(sizeof(ushort) * (size_t)N * HID);
    ushort* F      = (ushort*)alloc(sizeof(ushort) * (size_t)N * F1);
    float*  A      = (float*)alloc(sizeof(float) * (size_t)N * F1);    // layer0 act (f32, residual)
    ushort* Ab     = (ushort*)alloc(sizeof(ushort) * (size_t)N * F1);  // layer0 act (bf16)
    float*  als    = (float*)alloc(sizeof(float) * (size_t)N * HEADS);
    float*  ald    = (float*)alloc(sizeof(float) * (size_t)N * HEADS);
    float4* nf2    = (float4*)alloc(sizeof(float4) * (size_t)N);       // {f0,f1,als2,ald2}
    ushort* Wt0    = (ushort*)alloc(sizeof(ushort) * (size_t)F1 * HID);
    ushort* Wt1    = (ushort*)alloc(sizeof(ushort) * (size_t)F1 * F1);
    int*    deg    = (int*)alloc(sizeof(int) * (size_t)N);
    int*    rend   = (int*)alloc(sizeof(int) * (size_t)N);
    int*    wcur   = (int*)alloc(sizeof(int) * (size_t)N);
    int*    csum   = (int*)alloc(sizeof(int) * 256);
    int*    csrs   = (int*)alloc(sizeof(int) * (size_t)Etot);

    const int eb   = (Etot + 255) / 256;
    const int nb   = (N + 255) / 256;
    const int nb4  = (N + 3) / 4;
    const int nchunks = (N + 1023) / 1024;
    const int mb64 = (N + 63) / 64;
    const int mb32 = (N + 31) / 32;

    // -------- CSR build --------
    hipMemsetAsync(deg, 0, sizeof(int) * (size_t)N, stream);
    csr_count<<<eb, 256, 0, stream>>>(ei, E, Etot, deg);
    scan1<<<nchunks, 256, 0, stream>>>(deg, rend, csum, N);
    scan2<<<1, 256, 0, stream>>>(csum, nchunks);
    scan3<<<nb, 256, 0, stream>>>(deg, rend, csum, wcur, N);
    csr_fill<<<eb, 256, 0, stream>>>(ei, E, Etot, wcur, csrs);

    // -------- weight transposes (bf16) --------
    cvt_transpose<<<(HID * F1 + 255) / 256, 256, 0, stream>>>(W0, Wt0, HID, F1);
    cvt_transpose<<<(F1 * F1 + 255) / 256, 256, 0, stream>>>(W1, Wt1, F1, F1);

    // -------- input projection: P = bf16(x @ Wp + bp) --------
    gemm_tile<true, true><<<dim3(mb64, 1), 256, 0, stream>>>(
        x, Wp, bp, P, N, HID, IN_DIM);

    // ================= layer 0 =================
    mfma_gemm<HID, true><<<mb32, 256, 0, stream>>>(P, Wt0, as0, ad0, F, als, ald, N);
    aggregate_fused<false, false, true><<<nb4, 256, 0, stream>>>(csrs, rend, deg, F,
        als, ald, b0, ln_g, ln_b, nullptr, A, Ab, nullptr, nullptr, nullptr, nullptr, N);

    // ================= layer 1 =================
    mfma_gemm<F1, true><<<mb32, 256, 0, stream>>>(Ab, Wt1, as1, ad1, F, als, ald, N);
    aggregate_fused<true, true, false><<<nb4, 256, 0, stream>>>(csrs, rend, deg, F,
        als, ald, b1, ln_g, ln_b, A, nullptr, nullptr, W2, as2, ad2, nf2, N);

    // ================= layer 2 =================
    layer2_fused<<<nb4, 256, 0, stream>>>(csrs, rend, deg, nf2, b2, out, N);
}

// Round 9
// 412.663 us; speedup vs baseline: 7.1142x; 1.0578x over previous
//
#include <hip/hip_runtime.h>
#include <hip/hip_bf16.h>
#include <cmath>
#include <cfloat>

constexpr int IN_DIM = 184;
constexpr int KP     = 192;          // padded K for fused layer-0 GEMM
constexpr int HID    = 64;
constexpr int HEADS  = 4;
constexpr int F1     = HEADS * HID;  // 256
constexpr float SLOPE = 0.2f;
constexpr float LN_EPS = 1e-5f;

using short8 = __attribute__((ext_vector_type(8))) short;
using f32x4  = __attribute__((ext_vector_type(4))) float;

__device__ inline float b2f(ushort u) {
    return __uint_as_float(((unsigned)u) << 16);
}
__device__ inline ushort f2b(float f) {
    __hip_bfloat16 b = __float2bfloat16(f);
    return *reinterpret_cast<ushort*>(&b);
}
__device__ inline short8 mk8(ushort4 lo, ushort4 hi) {
    short8 v;
    v[0] = (short)lo.x; v[1] = (short)lo.y; v[2] = (short)lo.z; v[3] = (short)lo.w;
    v[4] = (short)hi.x; v[5] = (short)hi.y; v[6] = (short)hi.z; v[7] = (short)hi.w;
    return v;
}
__device__ inline short8 mk8f(float4 lo, float4 hi) {
    short8 v;
    v[0] = (short)f2b(lo.x); v[1] = (short)f2b(lo.y);
    v[2] = (short)f2b(lo.z); v[3] = (short)f2b(lo.w);
    v[4] = (short)f2b(hi.x); v[5] = (short)f2b(hi.y);
    v[6] = (short)f2b(hi.z); v[7] = (short)f2b(hi.w);
    return v;
}
__device__ inline float lrelu(float e) { return e > 0.f ? e : SLOPE * e; }

// ---- combined weight: Wct[c][k] = bf16(sum_j Wp[k][j]*W0[j][c]) (k<184, else 0);
// ---- bc[c] = sum_j bp[j]*W0[j][c]
__global__ __launch_bounds__(256) void combine_w(const float* __restrict__ Wp,
                                                 const float* __restrict__ W0,
                                                 const float* __restrict__ bp,
                                                 ushort* __restrict__ Wct,
                                                 float* __restrict__ bc) {
    int k = blockIdx.x, c = threadIdx.x;
    float s = 0.f;
    if (k < IN_DIM) {
        for (int j = 0; j < HID; ++j) s = fmaf(Wp[k * HID + j], W0[j * F1 + c], s);
    }
    Wct[(size_t)c * KP + k] = f2b(s);
    if (k == 0) {
        float b = 0.f;
        for (int j = 0; j < HID; ++j) b = fmaf(bp[j], W0[j * F1 + c], b);
        bc[c] = b;
    }
}

// ---- W1 -> bf16 transpose ----
__global__ __launch_bounds__(256) void cvt_transpose(const float* __restrict__ W,
                                                     ushort* __restrict__ Wt,
                                                     int K, int NC) {
    int idx = blockIdx.x * 256 + threadIdx.x;
    if (idx >= K * NC) return;
    int k = idx / NC, c = idx - k * NC;
    Wt[(size_t)c * K + k] = f2b(W[idx]);
}

// ======= layer-0 fused GEMM: F = bf16( x_f32 @ Wc + bc ), + attention logits =======
// 32 rows/block, wave w owns cols w*64..+63 (head w). A frags cvt'd inline from f32 x.
__global__ __launch_bounds__(256) void mfma_l0(const float* __restrict__ X,
                                               const ushort* __restrict__ Wct,
                                               const float* __restrict__ bc,
                                               const float* __restrict__ as_,
                                               const float* __restrict__ ad_,
                                               ushort* __restrict__ Y,
                                               float* __restrict__ als,
                                               float* __restrict__ ald,
                                               int M) {
    const int tid = threadIdx.x;
    const int w = tid >> 6, l = tid & 63;
    const int lr = l & 15, q = l >> 4;
    const int row0 = blockIdx.x * 32;

    f32x4 acc00 = {0,0,0,0}, acc01 = {0,0,0,0}, acc02 = {0,0,0,0}, acc03 = {0,0,0,0};
    f32x4 acc10 = {0,0,0,0}, acc11 = {0,0,0,0}, acc12 = {0,0,0,0}, acc13 = {0,0,0,0};

    const int rA0 = min(row0 + lr, M - 1);
    const int rA1 = min(row0 + 16 + lr, M - 1);
    const int colb = w * 64 + lr;

#pragma unroll
    for (int k0 = 0; k0 < KP; k0 += 32) {
        const float* px0 = &X[(size_t)rA0 * IN_DIM + k0 + 4 * q];
        const float* px1 = &X[(size_t)rA1 * IN_DIM + k0 + 4 * q];
        const bool hiv = (k0 + 16 + 4 * q) < IN_DIM;       // lo half always < 184
        float4 z = {0.f, 0.f, 0.f, 0.f};
        float4 lo0 = *(const float4*)px0;
        float4 hi0 = hiv ? *(const float4*)(px0 + 16) : z;
        float4 lo1 = *(const float4*)px1;
        float4 hi1 = hiv ? *(const float4*)(px1 + 16) : z;
        short8 a0 = mk8f(lo0, hi0);
        short8 a1 = mk8f(lo1, hi1);

        const ushort* pb0 = &Wct[(size_t)(colb +  0) * KP + k0 + 4 * q];
        const ushort* pb1 = &Wct[(size_t)(colb + 16) * KP + k0 + 4 * q];
        const ushort* pb2 = &Wct[(size_t)(colb + 32) * KP + k0 + 4 * q];
        const ushort* pb3 = &Wct[(size_t)(colb + 48) * KP + k0 + 4 * q];
        short8 b0 = mk8(*(const ushort4*)pb0, *(const ushort4*)(pb0 + 16));
        short8 b1 = mk8(*(const ushort4*)pb1, *(const ushort4*)(pb1 + 16));
        short8 b2 = mk8(*(const ushort4*)pb2, *(const ushort4*)(pb2 + 16));
        short8 b3 = mk8(*(const ushort4*)pb3, *(const ushort4*)(pb3 + 16));

        acc00 = __builtin_amdgcn_mfma_f32_16x16x32_bf16(a0, b0, acc00, 0, 0, 0);
        acc01 = __builtin_amdgcn_mfma_f32_16x16x32_bf16(a0, b1, acc01, 0, 0, 0);
        acc02 = __builtin_amdgcn_mfma_f32_16x16x32_bf16(a0, b2, acc02, 0, 0, 0);
        acc03 = __builtin_amdgcn_mfma_f32_16x16x32_bf16(a0, b3, acc03, 0, 0, 0);
        acc10 = __builtin_amdgcn_mfma_f32_16x16x32_bf16(a1, b0, acc10, 0, 0, 0);
        acc11 = __builtin_amdgcn_mfma_f32_16x16x32_bf16(a1, b1, acc11, 0, 0, 0);
        acc12 = __builtin_amdgcn_mfma_f32_16x16x32_bf16(a1, b2, acc12, 0, 0, 0);
        acc13 = __builtin_amdgcn_mfma_f32_16x16x32_bf16(a1, b3, acc13, 0, 0, 0);
    }

    f32x4 accs[2][4] = { { acc00, acc01, acc02, acc03 },
                         { acc10, acc11, acc12, acc13 } };

    float bcv[4];
#pragma unroll
    for (int ct = 0; ct < 4; ++ct) bcv[ct] = bc[w * 64 + ct * 16 + lr];
#pragma unroll
    for (int rt = 0; rt < 2; ++rt)
#pragma unroll
        for (int ct = 0; ct < 4; ++ct)
#pragma unroll
            for (int r = 0; r < 4; ++r) accs[rt][ct][r] += bcv[ct];

#pragma unroll
    for (int rt = 0; rt < 2; ++rt) {
#pragma unroll
        for (int r = 0; r < 4; ++r) {
            int row = row0 + rt * 16 + q * 4 + r;
            if (row < M) {
#pragma unroll
                for (int ct = 0; ct < 4; ++ct)
                    Y[(size_t)row * F1 + w * 64 + ct * 16 + lr] = f2b(accs[rt][ct][r]);
            }
        }
    }

    float asv[4], adv[4];
#pragma unroll
    for (int ct = 0; ct < 4; ++ct) {
        asv[ct] = as_[w * 64 + ct * 16 + lr];
        adv[ct] = ad_[w * 64 + ct * 16 + lr];
    }
#pragma unroll
    for (int rt = 0; rt < 2; ++rt) {
#pragma unroll
        for (int r = 0; r < 4; ++r) {
            float ls = 0.f, ld_ = 0.f;
#pragma unroll
            for (int ct = 0; ct < 4; ++ct) {
                ls  = fmaf(accs[rt][ct][r], asv[ct], ls);
                ld_ = fmaf(accs[rt][ct][r], adv[ct], ld_);
            }
            for (int off = 8; off; off >>= 1) {
                ls  += __shfl_xor(ls, off);
                ld_ += __shfl_xor(ld_, off);
            }
            int row = row0 + rt * 16 + q * 4 + r;
            if (lr == 0 && row < M) {
                als[row * HEADS + w] = ls;
                ald[row * HEADS + w] = ld_;
            }
        }
    }
}

// ================= MFMA bf16 GEMM (layer 1): Y = X @ W1, + logits =================
template<int K>
__global__ __launch_bounds__(256) void mfma_gemm(const ushort* __restrict__ X,
                                                 const ushort* __restrict__ Wt,
                                                 const float* __restrict__ as_,
                                                 const float* __restrict__ ad_,
                                                 ushort* __restrict__ Y,
                                                 float* __restrict__ als,
                                                 float* __restrict__ ald,
                                                 int M) {
    const int tid = threadIdx.x;
    const int w = tid >> 6, l = tid & 63;
    const int lr = l & 15, q = l >> 4;
    const int row0 = blockIdx.x * 32;

    f32x4 acc00 = {0,0,0,0}, acc01 = {0,0,0,0}, acc02 = {0,0,0,0}, acc03 = {0,0,0,0};
    f32x4 acc10 = {0,0,0,0}, acc11 = {0,0,0,0}, acc12 = {0,0,0,0}, acc13 = {0,0,0,0};

    const int rA0 = min(row0 + lr, M - 1);
    const int rA1 = min(row0 + 16 + lr, M - 1);
    const int colb = w * 64 + lr;

#pragma unroll
    for (int k0 = 0; k0 < K; k0 += 32) {
        const ushort* p0 = &X[(size_t)rA0 * K + k0 + 4 * q];
        const ushort* p1 = &X[(size_t)rA1 * K + k0 + 4 * q];
        short8 a0 = mk8(*(const ushort4*)p0, *(const ushort4*)(p0 + 16));
        short8 a1 = mk8(*(const ushort4*)p1, *(const ushort4*)(p1 + 16));

        const ushort* pb0 = &Wt[(size_t)(colb +  0) * K + k0 + 4 * q];
        const ushort* pb1 = &Wt[(size_t)(colb + 16) * K + k0 + 4 * q];
        const ushort* pb2 = &Wt[(size_t)(colb + 32) * K + k0 + 4 * q];
        const ushort* pb3 = &Wt[(size_t)(colb + 48) * K + k0 + 4 * q];
        short8 b0 = mk8(*(const ushort4*)pb0, *(const ushort4*)(pb0 + 16));
        short8 b1 = mk8(*(const ushort4*)pb1, *(const ushort4*)(pb1 + 16));
        short8 b2 = mk8(*(const ushort4*)pb2, *(const ushort4*)(pb2 + 16));
        short8 b3 = mk8(*(const ushort4*)pb3, *(const ushort4*)(pb3 + 16));

        acc00 = __builtin_amdgcn_mfma_f32_16x16x32_bf16(a0, b0, acc00, 0, 0, 0);
        acc01 = __builtin_amdgcn_mfma_f32_16x16x32_bf16(a0, b1, acc01, 0, 0, 0);
        acc02 = __builtin_amdgcn_mfma_f32_16x16x32_bf16(a0, b2, acc02, 0, 0, 0);
        acc03 = __builtin_amdgcn_mfma_f32_16x16x32_bf16(a0, b3, acc03, 0, 0, 0);
        acc10 = __builtin_amdgcn_mfma_f32_16x16x32_bf16(a1, b0, acc10, 0, 0, 0);
        acc11 = __builtin_amdgcn_mfma_f32_16x16x32_bf16(a1, b1, acc11, 0, 0, 0);
        acc12 = __builtin_amdgcn_mfma_f32_16x16x32_bf16(a1, b2, acc12, 0, 0, 0);
        acc13 = __builtin_amdgcn_mfma_f32_16x16x32_bf16(a1, b3, acc13, 0, 0, 0);
    }

    f32x4 accs[2][4] = { { acc00, acc01, acc02, acc03 },
                         { acc10, acc11, acc12, acc13 } };

#pragma unroll
    for (int rt = 0; rt < 2; ++rt) {
#pragma unroll
        for (int r = 0; r < 4; ++r) {
            int row = row0 + rt * 16 + q * 4 + r;
            if (row < M) {
#pragma unroll
                for (int ct = 0; ct < 4; ++ct)
                    Y[(size_t)row * F1 + w * 64 + ct * 16 + lr] = f2b(accs[rt][ct][r]);
            }
        }
    }

    float asv[4], adv[4];
#pragma unroll
    for (int ct = 0; ct < 4; ++ct) {
        asv[ct] = as_[w * 64 + ct * 16 + lr];
        adv[ct] = ad_[w * 64 + ct * 16 + lr];
    }
#pragma unroll
    for (int rt = 0; rt < 2; ++rt) {
#pragma unroll
        for (int r = 0; r < 4; ++r) {
            float ls = 0.f, ld_ = 0.f;
#pragma unroll
            for (int ct = 0; ct < 4; ++ct) {
                ls  = fmaf(accs[rt][ct][r], asv[ct], ls);
                ld_ = fmaf(accs[rt][ct][r], adv[ct], ld_);
            }
            for (int off = 8; off; off >>= 1) {
                ls  += __shfl_xor(ls, off);
                ld_ += __shfl_xor(ld_, off);
            }
            int row = row0 + rt * 16 + q * 4 + r;
            if (lr == 0 && row < M) {
                als[row * HEADS + w] = ls;
                ald[row * HEADS + w] = ld_;
            }
        }
    }
}

// ---------------- CSR build ----------------
__device__ inline void edge_sd(const int* __restrict__ ei, int E, int idx, int& s, int& d) {
    if (idx < E) { s = ei[idx]; d = ei[E + idx]; }
    else         { s = idx - E; d = idx - E; }
}

__global__ __launch_bounds__(256) void csr_count(const int* __restrict__ ei, int E, int Etot,
                                                 int* __restrict__ deg) {
    int idx = blockIdx.x * 256 + threadIdx.x;
    if (idx >= Etot) return;
    int s, d; edge_sd(ei, E, idx, s, d);
    atomicAdd(&deg[d], 1);
}

__global__ __launch_bounds__(256) void scan1(const int* __restrict__ deg, int* __restrict__ out,
                                             int* __restrict__ csum, int N) {
    __shared__ int s[256];
    int t = threadIdx.x;
    int idx0 = blockIdx.x * 1024 + t * 4;
    int v[4];
#pragma unroll
    for (int i = 0; i < 4; ++i) { int id = idx0 + i; v[i] = (id < N) ? deg[id] : 0; }
    int sum = v[0] + v[1] + v[2] + v[3];
    s[t] = sum; __syncthreads();
    for (int off = 1; off < 256; off <<= 1) {
        int x = (t >= off) ? s[t - off] : 0;
        __syncthreads();
        s[t] += x;
        __syncthreads();
    }
    int run = (t == 0) ? 0 : s[t - 1];
#pragma unroll
    for (int i = 0; i < 4; ++i) {
        run += v[i];
        int id = idx0 + i;
        if (id < N) out[id] = run;
    }
    if (t == 255) csum[blockIdx.x] = s[255];
}

__global__ __launch_bounds__(256) void scan2(int* __restrict__ csum, int M) {
    __shared__ int s[256];
    int t = threadIdx.x;
    s[t] = (t < M) ? csum[t] : 0;
    __syncthreads();
    for (int off = 1; off < 256; off <<= 1) {
        int x = (t >= off) ? s[t - off] : 0;
        __syncthreads();
        s[t] += x;
        __syncthreads();
    }
    if (t < M) csum[t] = s[t];
}

__global__ __launch_bounds__(256) void scan3(const int* __restrict__ deg, int* __restrict__ rend,
                                             const int* __restrict__ csum, int* __restrict__ wcur, int N) {
    int id = blockIdx.x * 256 + threadIdx.x;
    if (id >= N) return;
    int chunk = id >> 10;
    int off = (chunk == 0) ? 0 : csum[chunk - 1];
    int e = rend[id] + off;
    rend[id] = e;
    wcur[id] = e - deg[id];
}

__global__ __launch_bounds__(256) void csr_fill(const int* __restrict__ ei, int E, int Etot,
                                                int* __restrict__ wcur, int* __restrict__ csr_src) {
    int idx = blockIdx.x * 256 + threadIdx.x;
    if (idx >= Etot) return;
    int s, d; edge_sd(ei, E, idx, s, d);
    int pos = atomicAdd(&wcur[d], 1);
    csr_src[pos] = s;
}

// ======== fused softmax + gather + LN(+res)+ELU, WAVE per node ========
// Gather: lane owns 8 features (uint4=16B); lanes<32 do even edges, >=32 odd;
// halves merged via shfl_xor(32). Epilogue reductions divide by 2 (dup halves).
template<bool RES, bool FEAT2>
__global__ __launch_bounds__(256) void aggregate_fused(const int* __restrict__ csr_src,
                                                       const int* __restrict__ rend,
                                                       const int* __restrict__ deg_,
                                                       const ushort* __restrict__ feat,
                                                       const float* __restrict__ als,
                                                       const float* __restrict__ ald,
                                                       const float* __restrict__ bias,
                                                       const float* __restrict__ g,
                                                       const float* __restrict__ bln,
                                                       const ushort* __restrict__ res,
                                                       ushort* __restrict__ out_bf,
                                                       const float* __restrict__ W2,
                                                       const float* __restrict__ as2,
                                                       const float* __restrict__ ad2,
                                                       float4* __restrict__ nf2,
                                                       int N) {
    __shared__ __align__(16) float alds[4][64][4];
    __shared__ int srcs[4][64];
    const int w = threadIdx.x >> 6, l = threadIdx.x & 63;
    const int n = blockIdx.x * 4 + w;
    if (n >= N) return;
    const int dg = deg_[n], end = rend[n], start = end - dg;
    const int hf = l >> 5;          // half: even/odd edges
    const int lh = l & 31;          // lane-in-half: owns features 8lh..8lh+7
    const int hh = lh >> 3;         // head of those features
    const float4 ad4 = ((const float4*)ald)[n];

    float acc[8] = {0.f, 0.f, 0.f, 0.f, 0.f, 0.f, 0.f, 0.f};

    auto fma8 = [&](uint4 u, float a) {
        acc[0] = fmaf(__uint_as_float(u.x << 16), a, acc[0]);
        acc[1] = fmaf(__uint_as_float(u.x & 0xffff0000u), a, acc[1]);
        acc[2] = fmaf(__uint_as_float(u.y << 16), a, acc[2]);
        acc[3] = fmaf(__uint_as_float(u.y & 0xffff0000u), a, acc[3]);
        acc[4] = fmaf(__uint_as_float(u.z << 16), a, acc[4]);
        acc[5] = fmaf(__uint_as_float(u.z & 0xffff0000u), a, acc[5]);
        acc[6] = fmaf(__uint_as_float(u.w << 16), a, acc[6]);
        acc[7] = fmaf(__uint_as_float(u.w & 0xffff0000u), a, acc[7]);
    };

    auto gather_chunk = [&](int cnt) {
        int j = hf;
        for (; j + 2 < cnt; j += 4) {           // 2 edges of this half in flight
            int s0 = srcs[w][j], s1 = srcs[w][j + 2];
            float a0 = alds[w][j][hh], a1 = alds[w][j + 2][hh];
            uint4 u0 = *(const uint4*)&feat[(size_t)s0 * F1 + lh * 8];
            uint4 u1 = *(const uint4*)&feat[(size_t)s1 * F1 + lh * 8];
            fma8(u0, a0);
            fma8(u1, a1);
        }
        for (; j < cnt; j += 2) {
            int s0 = srcs[w][j];
            float a0 = alds[w][j][hh];
            uint4 u0 = *(const uint4*)&feat[(size_t)s0 * F1 + lh * 8];
            fma8(u0, a0);
        }
    };

    if (dg <= 64) {
        int s = 0;
        float4 e = { -FLT_MAX, -FLT_MAX, -FLT_MAX, -FLT_MAX };
        if (l < dg) {
            s = csr_src[start + l];
            float4 a = ((const float4*)als)[s];
            e.x = lrelu(a.x + ad4.x); e.y = lrelu(a.y + ad4.y);
            e.z = lrelu(a.z + ad4.z); e.w = lrelu(a.w + ad4.w);
        }
        float4 m = e;
        for (int off = 32; off; off >>= 1) {
            m.x = fmaxf(m.x, __shfl_xor(m.x, off));
            m.y = fmaxf(m.y, __shfl_xor(m.y, off));
            m.z = fmaxf(m.z, __shfl_xor(m.z, off));
            m.w = fmaxf(m.w, __shfl_xor(m.w, off));
        }
        float4 ex = { 0.f, 0.f, 0.f, 0.f };
        if (l < dg) {
            ex.x = expf(e.x - m.x); ex.y = expf(e.y - m.y);
            ex.z = expf(e.z - m.z); ex.w = expf(e.w - m.w);
        }
        float4 sum = ex;
        for (int off = 32; off; off >>= 1) {
            sum.x += __shfl_xor(sum.x, off);
            sum.y += __shfl_xor(sum.y, off);
            sum.z += __shfl_xor(sum.z, off);
            sum.w += __shfl_xor(sum.w, off);
        }
        float4 al = { ex.x / (sum.x + 1e-16f), ex.y / (sum.y + 1e-16f),
                      ex.z / (sum.z + 1e-16f), ex.w / (sum.w + 1e-16f) };
        *(float4*)&alds[w][l][0] = al;
        srcs[w][l] = s;
        __builtin_amdgcn_s_waitcnt(0);
        gather_chunk(dg);
    } else {
        float4 m = { -FLT_MAX, -FLT_MAX, -FLT_MAX, -FLT_MAX };
        for (int i = l; i < dg; i += 64) {
            int s = csr_src[start + i];
            float4 a = ((const float4*)als)[s];
            m.x = fmaxf(m.x, lrelu(a.x + ad4.x));
            m.y = fmaxf(m.y, lrelu(a.y + ad4.y));
            m.z = fmaxf(m.z, lrelu(a.z + ad4.z));
            m.w = fmaxf(m.w, lrelu(a.w + ad4.w));
        }
        for (int off = 32; off; off >>= 1) {
            m.x = fmaxf(m.x, __shfl_xor(m.x, off));
            m.y = fmaxf(m.y, __shfl_xor(m.y, off));
            m.z = fmaxf(m.z, __shfl_xor(m.z, off));
            m.w = fmaxf(m.w, __shfl_xor(m.w, off));
        }
        float4 sum = { 0.f, 0.f, 0.f, 0.f };
        for (int i = l; i < dg; i += 64) {
            int s = csr_src[start + i];
            float4 a = ((const float4*)als)[s];
            sum.x += expf(lrelu(a.x + ad4.x) - m.x);
            sum.y += expf(lrelu(a.y + ad4.y) - m.y);
            sum.z += expf(lrelu(a.z + ad4.z) - m.z);
            sum.w += expf(lrelu(a.w + ad4.w) - m.w);
        }
        for (int off = 32; off; off >>= 1) {
            sum.x += __shfl_xor(sum.x, off);
            sum.y += __shfl_xor(sum.y, off);
            sum.z += __shfl_xor(sum.z, off);
            sum.w += __shfl_xor(sum.w, off);
        }
        float4 inv = { 1.f / (sum.x + 1e-16f), 1.f / (sum.y + 1e-16f),
                       1.f / (sum.z + 1e-16f), 1.f / (sum.w + 1e-16f) };
        for (int c0 = start; c0 < end; c0 += 64) {
            int cnt = min(64, end - c0);
            if (l < cnt) {
                int s = csr_src[c0 + l];
                float4 a = ((const float4*)als)[s];
                float4 al = { expf(lrelu(a.x + ad4.x) - m.x) * inv.x,
                              expf(lrelu(a.y + ad4.y) - m.y) * inv.y,
                              expf(lrelu(a.z + ad4.z) - m.z) * inv.z,
                              expf(lrelu(a.w + ad4.w) - m.w) * inv.w };
                *(float4*)&alds[w][l][0] = al;
                srcs[w][l] = s;
            }
            __builtin_amdgcn_s_waitcnt(0);
            gather_chunk(cnt);
        }
    }

    // merge halves: lanes lh and lh+32 own the same 8 features
#pragma unroll
    for (int r = 0; r < 8; ++r) acc[r] += __shfl_xor(acc[r], 32);

    // ---- epilogue: bias + LN (+res) + ELU (all lanes hold dup copies; /2 in reduces)
    float4 bv0 = ((const float4*)bias)[lh * 2];
    float4 bv1 = ((const float4*)bias)[lh * 2 + 1];
    float v[8] = { acc[0] + bv0.x, acc[1] + bv0.y, acc[2] + bv0.z, acc[3] + bv0.w,
                   acc[4] + bv1.x, acc[5] + bv1.y, acc[6] + bv1.z, acc[7] + bv1.w };
    float sm = v[0] + v[1] + v[2] + v[3] + v[4] + v[5] + v[6] + v[7];
    for (int off = 32; off; off >>= 1) sm += __shfl_xor(sm, off);
    float mu = sm * (1.f / (2 * F1));
    float dv = 0.f;
#pragma unroll
    for (int r = 0; r < 8; ++r) { float d = v[r] - mu; dv += d * d; }
    for (int off = 32; off; off >>= 1) dv += __shfl_xor(dv, off);
    float rstd = rsqrtf(dv * (1.f / (2 * F1)) + LN_EPS);
    float4 gv0 = ((const float4*)g)[lh * 2],   gv1 = ((const float4*)g)[lh * 2 + 1];
    float4 lb0 = ((const float4*)bln)[lh * 2], lb1 = ((const float4*)bln)[lh * 2 + 1];
    float y[8];
    y[0] = (v[0] - mu) * rstd * gv0.x + lb0.x;
    y[1] = (v[1] - mu) * rstd * gv0.y + lb0.y;
    y[2] = (v[2] - mu) * rstd * gv0.z + lb0.z;
    y[3] = (v[3] - mu) * rstd * gv0.w + lb0.w;
    y[4] = (v[4] - mu) * rstd * gv1.x + lb1.x;
    y[5] = (v[5] - mu) * rstd * gv1.y + lb1.y;
    y[6] = (v[6] - mu) * rstd * gv1.z + lb1.z;
    y[7] = (v[7] - mu) * rstd * gv1.w + lb1.w;
    if (RES) {
        uint4 rr = ((const uint4*)res)[(size_t)n * 32 + lh];
        y[0] += __uint_as_float(rr.x << 16);
        y[1] += __uint_as_float(rr.x & 0xffff0000u);
        y[2] += __uint_as_float(rr.y << 16);
        y[3] += __uint_as_float(rr.y & 0xffff0000u);
        y[4] += __uint_as_float(rr.z << 16);
        y[5] += __uint_as_float(rr.z & 0xffff0000u);
        y[6] += __uint_as_float(rr.w << 16);
        y[7] += __uint_as_float(rr.w & 0xffff0000u);
    }
#pragma unroll
    for (int r = 0; r < 8; ++r) y[r] = y[r] > 0.f ? y[r] : expm1f(y[r]);

    if (!FEAT2) {
        if (l < 32) {
            uint4 o;
            o.x = (uint)f2b(y[0]) | ((uint)f2b(y[1]) << 16);
            o.y = (uint)f2b(y[2]) | ((uint)f2b(y[3]) << 16);
            o.z = (uint)f2b(y[4]) | ((uint)f2b(y[5]) << 16);
            o.w = (uint)f2b(y[6]) | ((uint)f2b(y[7]) << 16);
            ((uint4*)out_bf)[(size_t)n * 32 + lh] = o;
        }
    } else {
        const float4* W24 = (const float4*)W2;
        float c0 = 0.f, c1 = 0.f;
#pragma unroll
        for (int j = 0; j < 4; ++j) {
            float4 wv = W24[lh * 4 + j];      // features 8lh+2j, 8lh+2j+1
            c0 += y[2 * j] * wv.x + y[2 * j + 1] * wv.z;
            c1 += y[2 * j] * wv.y + y[2 * j + 1] * wv.w;
        }
        for (int off = 32; off; off >>= 1) {
            c0 += __shfl_xor(c0, off);
            c1 += __shfl_xor(c1, off);
        }
        c0 *= 0.5f; c1 *= 0.5f;               // dup halves
        if (l == 0) {
            float4 o = { c0, c1,
                         c0 * as2[0] + c1 * as2[1],
                         c0 * ad2[0] + c1 * ad2[1] };
            nf2[n] = o;
        }
    }
}

// ---- layer 2 fully fused: softmax(H=1) + 2-feature gather, wave per node ----
__global__ __launch_bounds__(256) void layer2_fused(const int* __restrict__ csr_src,
                                                    const int* __restrict__ rend,
                                                    const int* __restrict__ deg_,
                                                    const float4* __restrict__ nf2,
                                                    const float* __restrict__ b2,
                                                    float* __restrict__ out, int N) {
    const int w = threadIdx.x >> 6, l = threadIdx.x & 63;
    const int n = blockIdx.x * 4 + w;
    if (n >= N) return;
    const int dg = deg_[n], end = rend[n], start = end - dg;
    const float ad = nf2[n].w;

    float a0 = 0.f, a1 = 0.f;
    if (dg <= 64) {
        float e = -FLT_MAX;
        float f0 = 0.f, f1 = 0.f;
        if (l < dg) {
            int s = csr_src[start + l];
            float4 v = nf2[s];
            e = lrelu(v.z + ad);
            f0 = v.x; f1 = v.y;
        }
        float m = e;
        for (int off = 32; off; off >>= 1) m = fmaxf(m, __shfl_xor(m, off));
        float ex = (l < dg) ? expf(e - m) : 0.f;
        float sum = ex;
        for (int off = 32; off; off >>= 1) sum += __shfl_xor(sum, off);
        float al = ex / (sum + 1e-16f);
        a0 = f0 * al; a1 = f1 * al;
    } else {
        float m = -FLT_MAX;
        for (int i = l; i < dg; i += 64) {
            int s = csr_src[start + i];
            m = fmaxf(m, lrelu(nf2[s].z + ad));
        }
        for (int off = 32; off; off >>= 1) m = fmaxf(m, __shfl_xor(m, off));
        float sum = 0.f;
        for (int i = l; i < dg; i += 64) {
            int s = csr_src[start + i];
            sum += expf(lrelu(nf2[s].z + ad) - m);
        }
        for (int off = 32; off; off >>= 1) sum += __shfl_xor(sum, off);
        float inv = 1.f / (sum + 1e-16f);
        for (int i = l; i < dg; i += 64) {
            int s = csr_src[start + i];
            float4 v = nf2[s];
            float al = expf(lrelu(v.z + ad) - m) * inv;
            a0 = fmaf(v.x, al, a0);
            a1 = fmaf(v.y, al, a1);
        }
    }
    for (int off = 32; off; off >>= 1) {
        a0 += __shfl_xor(a0, off);
        a1 += __shfl_xor(a1, off);
    }
    if (l == 0) {
        out[(size_t)n * 2 + 0] = a0 + b2[0];
        out[(size_t)n * 2 + 1] = a1 + b2[1];
    }
}

extern "C" void kernel_launch(void* const* d_in, const int* in_sizes, int n_in,
                              void* d_out, int out_size, void* d_ws, size_t ws_size,
                              hipStream_t stream) {
    const float* x    = (const float*)d_in[0];
    const int*   ei   = (const int*)d_in[1];
    const float* Wp   = (const float*)d_in[2];
    const float* bp   = (const float*)d_in[3];
    const float* W0   = (const float*)d_in[4];
    const float* as0  = (const float*)d_in[5];
    const float* ad0  = (const float*)d_in[6];
    const float* b0   = (const float*)d_in[7];
    const float* W1   = (const float*)d_in[8];
    const float* as1  = (const float*)d_in[9];
    const float* ad1  = (const float*)d_in[10];
    const float* b1   = (const float*)d_in[11];
    const float* W2   = (const float*)d_in[12];
    const float* as2  = (const float*)d_in[13];
    const float* ad2  = (const float*)d_in[14];
    const float* b2   = (const float*)d_in[15];
    const float* ln_g = (const float*)d_in[16];
    const float* ln_b = (const float*)d_in[17];
    float* out = (float*)d_out;

    const int N    = in_sizes[0] / IN_DIM;   // 50000
    const int E    = in_sizes[1] / 2;        // 800000
    const int Etot = E + N;

    char* wptr = (char*)d_ws;
    auto alloc = [&](size_t bytes) -> void* {
        void* p = wptr;
        wptr += (bytes + 255) & ~(size_t)255;
        return p;
    };
    ushort* F      = (ushort*)alloc(sizeof(ushort) * (size_t)N * F1);
    ushort* Ab     = (ushort*)alloc(sizeof(ushort) * (size_t)N * F1);  // layer0 act (bf16)
    float*  als    = (float*)alloc(sizeof(float) * (size_t)N * HEADS);
    float*  ald    = (float*)alloc(sizeof(float) * (size_t)N * HEADS);
    float4* nf2    = (float4*)alloc(sizeof(float4) * (size_t)N);
    ushort* Wct    = (ushort*)alloc(sizeof(ushort) * (size_t)F1 * KP);  // combined [256][192]
    float*  bc     = (float*)alloc(sizeof(float) * F1);
    ushort* Wt1    = (ushort*)alloc(sizeof(ushort) * (size_t)F1 * F1);
    int*    deg    = (int*)alloc(sizeof(int) * (size_t)N);
    int*    rend   = (int*)alloc(sizeof(int) * (size_t)N);
    int*    wcur   = (int*)alloc(sizeof(int) * (size_t)N);
    int*    csum   = (int*)alloc(sizeof(int) * 256);
    int*    csrs   = (int*)alloc(sizeof(int) * (size_t)Etot);

    const int eb   = (Etot + 255) / 256;
    const int nb   = (N + 255) / 256;
    const int nb4  = (N + 3) / 4;
    const int nchunks = (N + 1023) / 1024;
    const int mb32 = (N + 31) / 32;

    // -------- CSR build --------
    hipMemsetAsync(deg, 0, sizeof(int) * (size_t)N, stream);
    csr_count<<<eb, 256, 0, stream>>>(ei, E, Etot, deg);
    scan1<<<nchunks, 256, 0, stream>>>(deg, rend, csum, N);
    scan2<<<1, 256, 0, stream>>>(csum, nchunks);
    scan3<<<nb, 256, 0, stream>>>(deg, rend, csum, wcur, N);
    csr_fill<<<eb, 256, 0, stream>>>(ei, E, Etot, wcur, csrs);

    // -------- weight prep --------
    combine_w<<<KP, 256, 0, stream>>>(Wp, W0, bp, Wct, bc);
    cvt_transpose<<<(F1 * F1 + 255) / 256, 256, 0, stream>>>(W1, Wt1, F1, F1);

    // ================= layer 0 (proj fused in) =================
    mfma_l0<<<mb32, 256, 0, stream>>>(x, Wct, bc, as0, ad0, F, als, ald, N);
    aggregate_fused<false, false><<<nb4, 256, 0, stream>>>(csrs, rend, deg, F,
        als, ald, b0, ln_g, ln_b, nullptr, Ab, nullptr, nullptr, nullptr, nullptr, N);

    // ================= layer 1 =================
    mfma_gemm<F1><<<mb32, 256, 0, stream>>>(Ab, Wt1, as1, ad1, F, als, ald, N);
    aggregate_fused<true, true><<<nb4, 256, 0, stream>>>(csrs, rend, deg, F,
        als, ald, b1, ln_g, ln_b, Ab, nullptr, W2, as2, ad2, nf2, N);

    // ================= layer 2 =================
    layer2_fused<<<nb4, 256, 0, stream>>>(csrs, rend, deg, nf2, b2, out, N);
}

// Round 10
// 327.290 us; speedup vs baseline: 8.9699x; 1.2608x over previous
//
#include <hip/hip_runtime.h>
#include <hip/hip_bf16.h>
#include <cmath>
#include <cfloat>

constexpr int IN_DIM = 184;
constexpr int KP     = 192;          // padded K for fused layer-0 GEMM
constexpr int HID    = 64;
constexpr int HEADS  = 4;
constexpr int F1     = HEADS * HID;  // 256
constexpr float SLOPE = 0.2f;
constexpr float LN_EPS = 1e-5f;

using short8 = __attribute__((ext_vector_type(8))) short;
using f32x4  = __attribute__((ext_vector_type(4))) float;

__device__ inline float b2f(ushort u) {
    return __uint_as_float(((unsigned)u) << 16);
}
__device__ inline ushort f2b(float f) {
    __hip_bfloat16 b = __float2bfloat16(f);
    return *reinterpret_cast<ushort*>(&b);
}
__device__ inline float lrelu(float e) { return e > 0.f ? e : SLOPE * e; }

// ======== weight prep: emit W in MFMA B-fragment order ========
// Wfrag[((kt*4 + w)*4 + ct)*64 + lane]*8 + j  holds  W[k][c] with
// k = 32*kt + 4*(lane>>4) + (j&3) + 16*(j>>2), c = w*64 + ct*16 + (lane&15).
__device__ inline size_t frag_idx(int k, int c) {
    int kt = k >> 5, kk = k & 31;
    int q = (kk & 15) >> 2, j = (kk & 3) | ((kk >> 4) << 2);
    int w = c >> 6, ct = (c >> 4) & 3, lr = c & 15;
    int lane = (q << 4) | lr;
    return ((((size_t)kt * 4 + w) * 4 + ct) * 64 + lane) * 8 + j;
}

// combined layer-0 weight: Wc[k][c] = sum_j Wp[k][j]*W0[j][c]; bc[c] = bp@W0
__global__ __launch_bounds__(256) void combine_w_frag(const float* __restrict__ Wp,
                                                      const float* __restrict__ W0,
                                                      const float* __restrict__ bp,
                                                      ushort* __restrict__ Wfrag,
                                                      float* __restrict__ bc) {
    int k = blockIdx.x;          // 0..KP-1
    int c = threadIdx.x;         // 0..255
    float s = 0.f;
    if (k < IN_DIM)
        for (int j = 0; j < HID; ++j) s = fmaf(Wp[k * HID + j], W0[j * F1 + c], s);
    Wfrag[frag_idx(k, c)] = f2b(s);
    if (k == 0) {
        float b = 0.f;
        for (int j = 0; j < HID; ++j) b = fmaf(bp[j], W0[j * F1 + c], b);
        bc[c] = b;
    }
}

__global__ __launch_bounds__(256) void cvt_frag(const float* __restrict__ W,
                                                ushort* __restrict__ Wfrag) {
    int k = blockIdx.x, c = threadIdx.x;    // [256][256]
    Wfrag[frag_idx(k, c)] = f2b(W[(size_t)k * F1 + c]);
}

// ======== staged MFMA GEMM: Y[M,256] = X[M,K] @ W (+bc), + attention logits ========
// 64 rows/block, 4 waves; wave w owns cols w*64..+63 (head w).
// B frags: 1 coalesced dwordx4/lane from Wfrag (prefetched 1 step ahead).
// A: global->LDS double-buffered [64][40] bf16, ds_read frags.
// L0: X is f32 [M][IN_DIM], converted inline; adds bc bias.
template<int KSTEPS, bool L0>
__global__ __launch_bounds__(256) void mfma_gemm2(const void* __restrict__ Xv,
                                                  const ushort* __restrict__ Wfrag,
                                                  const float* __restrict__ bc,
                                                  const float* __restrict__ as_,
                                                  const float* __restrict__ ad_,
                                                  ushort* __restrict__ Y,
                                                  float* __restrict__ als,
                                                  float* __restrict__ ald,
                                                  int M) {
    const int tid = threadIdx.x;
    const int w = tid >> 6, l = tid & 63;
    const int lr = l & 15, q = l >> 4;
    const int row0 = blockIdx.x * 64;

    __shared__ ushort a_lds[2][64][40];    // pad 40: 2-way bank alias (free), 16B aligned rows

    const int srow = tid >> 2, seg = tid & 3;
    int grow = row0 + srow; if (grow >= M) grow = M - 1;

    auto stage = [&](int buf, int kt) {
        if constexpr (!L0) {
            const ushort* p = (const ushort*)Xv + (size_t)grow * 256 + kt * 32 + seg * 8;
            *(uint4*)&a_lds[buf][srow][seg * 8] = *(const uint4*)p;
        } else {
            int kb = kt * 32 + seg * 8;
            uint4 o = {0u, 0u, 0u, 0u};
            if (kb < IN_DIM) {               // kb multiples of 8; 176 valid (176..183), 184 -> zeros
                const float* p = (const float*)Xv + (size_t)grow * IN_DIM + kb;
                float4 lo = *(const float4*)p;
                float4 hi = *(const float4*)(p + 4);
                o.x = (uint)f2b(lo.x) | ((uint)f2b(lo.y) << 16);
                o.y = (uint)f2b(lo.z) | ((uint)f2b(lo.w) << 16);
                o.z = (uint)f2b(hi.x) | ((uint)f2b(hi.y) << 16);
                o.w = (uint)f2b(hi.z) | ((uint)f2b(hi.w) << 16);
            }
            *(uint4*)&a_lds[buf][srow][seg * 8] = o;
        }
    };

    f32x4 acc[4][4] = {};

    stage(0, 0);
    short8 bcur[4];
#pragma unroll
    for (int ct = 0; ct < 4; ++ct) {
        const ushort* bp = Wfrag + ((((size_t)0 * 4 + w) * 4 + ct) * 64 + l) * 8;
        short8 b; *(uint4*)&b = *(const uint4*)bp; bcur[ct] = b;
    }
    __syncthreads();

    int buf = 0;
#pragma unroll
    for (int kt = 0; kt < KSTEPS; ++kt) {
        short8 bnext[4];
        if (kt + 1 < KSTEPS) {
#pragma unroll
            for (int ct = 0; ct < 4; ++ct) {
                const ushort* bp = Wfrag + ((((size_t)(kt + 1) * 4 + w) * 4 + ct) * 64 + l) * 8;
                short8 b; *(uint4*)&b = *(const uint4*)bp; bnext[ct] = b;
            }
            stage(buf ^ 1, kt + 1);          // writes other buffer; safe (prev barrier)
        }
        short8 afr[4];
#pragma unroll
        for (int rt = 0; rt < 4; ++rt) {
            short8 a;
            *(uint2*)&a       = *(const uint2*)&a_lds[buf][rt * 16 + lr][4 * q];
            *((uint2*)&a + 1) = *(const uint2*)&a_lds[buf][rt * 16 + lr][4 * q + 16];
            afr[rt] = a;
        }
#pragma unroll
        for (int rt = 0; rt < 4; ++rt)
#pragma unroll
            for (int ct = 0; ct < 4; ++ct)
                acc[rt][ct] = __builtin_amdgcn_mfma_f32_16x16x32_bf16(afr[rt], bcur[ct], acc[rt][ct], 0, 0, 0);
        __syncthreads();
        if (kt + 1 < KSTEPS) {
#pragma unroll
            for (int ct = 0; ct < 4; ++ct) bcur[ct] = bnext[ct];
        }
        buf ^= 1;
    }

    if constexpr (L0) {
        float bcv[4];
#pragma unroll
        for (int ct = 0; ct < 4; ++ct) bcv[ct] = bc[w * 64 + ct * 16 + lr];
#pragma unroll
        for (int rt = 0; rt < 4; ++rt)
#pragma unroll
            for (int ct = 0; ct < 4; ++ct)
#pragma unroll
                for (int r = 0; r < 4; ++r) acc[rt][ct][r] += bcv[ct];
    }

#pragma unroll
    for (int rt = 0; rt < 4; ++rt) {
#pragma unroll
        for (int r = 0; r < 4; ++r) {
            int row = row0 + rt * 16 + q * 4 + r;
            if (row < M) {
#pragma unroll
                for (int ct = 0; ct < 4; ++ct)
                    Y[(size_t)row * F1 + w * 64 + ct * 16 + lr] = f2b(acc[rt][ct][r]);
            }
        }
    }

    float asv[4], adv[4];
#pragma unroll
    for (int ct = 0; ct < 4; ++ct) {
        asv[ct] = as_[w * 64 + ct * 16 + lr];
        adv[ct] = ad_[w * 64 + ct * 16 + lr];
    }
#pragma unroll
    for (int rt = 0; rt < 4; ++rt) {
#pragma unroll
        for (int r = 0; r < 4; ++r) {
            float ls = 0.f, ld_ = 0.f;
#pragma unroll
            for (int ct = 0; ct < 4; ++ct) {
                ls  = fmaf(acc[rt][ct][r], asv[ct], ls);
                ld_ = fmaf(acc[rt][ct][r], adv[ct], ld_);
            }
            for (int off = 8; off; off >>= 1) {
                ls  += __shfl_xor(ls, off);
                ld_ += __shfl_xor(ld_, off);
            }
            int row = row0 + rt * 16 + q * 4 + r;
            if (lr == 0 && row < M) {
                als[row * HEADS + w] = ls;
                ald[row * HEADS + w] = ld_;
            }
        }
    }
}

// ---------------- CSR build ----------------
__device__ inline void edge_sd(const int* __restrict__ ei, int E, int idx, int& s, int& d) {
    if (idx < E) { s = ei[idx]; d = ei[E + idx]; }
    else         { s = idx - E; d = idx - E; }
}

__global__ __launch_bounds__(256) void csr_count(const int* __restrict__ ei, int E, int Etot,
                                                 int* __restrict__ deg) {
    int idx = blockIdx.x * 256 + threadIdx.x;
    if (idx >= Etot) return;
    int s, d; edge_sd(ei, E, idx, s, d);
    atomicAdd(&deg[d], 1);
}

__global__ __launch_bounds__(256) void scan1(const int* __restrict__ deg, int* __restrict__ out,
                                             int* __restrict__ csum, int N) {
    __shared__ int s[256];
    int t = threadIdx.x;
    int idx0 = blockIdx.x * 1024 + t * 4;
    int v[4];
#pragma unroll
    for (int i = 0; i < 4; ++i) { int id = idx0 + i; v[i] = (id < N) ? deg[id] : 0; }
    int sum = v[0] + v[1] + v[2] + v[3];
    s[t] = sum; __syncthreads();
    for (int off = 1; off < 256; off <<= 1) {
        int x = (t >= off) ? s[t - off] : 0;
        __syncthreads();
        s[t] += x;
        __syncthreads();
    }
    int run = (t == 0) ? 0 : s[t - 1];
#pragma unroll
    for (int i = 0; i < 4; ++i) {
        run += v[i];
        int id = idx0 + i;
        if (id < N) out[id] = run;
    }
    if (t == 255) csum[blockIdx.x] = s[255];
}

__global__ __launch_bounds__(256) void scan2(int* __restrict__ csum, int M) {
    __shared__ int s[256];
    int t = threadIdx.x;
    s[t] = (t < M) ? csum[t] : 0;
    __syncthreads();
    for (int off = 1; off < 256; off <<= 1) {
        int x = (t >= off) ? s[t - off] : 0;
        __syncthreads();
        s[t] += x;
        __syncthreads();
    }
    if (t < M) csum[t] = s[t];
}

__global__ __launch_bounds__(256) void scan3(const int* __restrict__ deg, int* __restrict__ rend,
                                             const int* __restrict__ csum, int* __restrict__ wcur, int N) {
    int id = blockIdx.x * 256 + threadIdx.x;
    if (id >= N) return;
    int chunk = id >> 10;
    int off = (chunk == 0) ? 0 : csum[chunk - 1];
    int e = rend[id] + off;
    rend[id] = e;
    wcur[id] = e - deg[id];
}

__global__ __launch_bounds__(256) void csr_fill(const int* __restrict__ ei, int E, int Etot,
                                                int* __restrict__ wcur, int* __restrict__ csr_src) {
    int idx = blockIdx.x * 256 + threadIdx.x;
    if (idx >= Etot) return;
    int s, d; edge_sd(ei, E, idx, s, d);
    int pos = atomicAdd(&wcur[d], 1);
    csr_src[pos] = s;
}

// ======== fused softmax + gather + LN(+res)+ELU, WAVE per node ========
template<bool RES, bool FEAT2>
__global__ __launch_bounds__(256) void aggregate_fused(const int* __restrict__ csr_src,
                                                       const int* __restrict__ rend,
                                                       const int* __restrict__ deg_,
                                                       const ushort* __restrict__ feat,
                                                       const float* __restrict__ als,
                                                       const float* __restrict__ ald,
                                                       const float* __restrict__ bias,
                                                       const float* __restrict__ g,
                                                       const float* __restrict__ bln,
                                                       const ushort* __restrict__ res,
                                                       ushort* __restrict__ out_bf,
                                                       const float* __restrict__ W2,
                                                       const float* __restrict__ as2,
                                                       const float* __restrict__ ad2,
                                                       float4* __restrict__ nf2,
                                                       int N) {
    __shared__ __align__(16) float alds[4][64][4];
    __shared__ int srcs[4][64];
    const int w = threadIdx.x >> 6, l = threadIdx.x & 63;
    const int n = blockIdx.x * 4 + w;
    if (n >= N) return;
    const int dg = deg_[n], end = rend[n], start = end - dg;
    const int hf = l >> 5;          // half: even/odd edges
    const int lh = l & 31;          // lane-in-half: owns features 8lh..8lh+7
    const int hh = lh >> 3;         // head of those features
    const float4 ad4 = ((const float4*)ald)[n];

    float acc[8] = {0.f, 0.f, 0.f, 0.f, 0.f, 0.f, 0.f, 0.f};

    auto fma8 = [&](uint4 u, float a) {
        acc[0] = fmaf(__uint_as_float(u.x << 16), a, acc[0]);
        acc[1] = fmaf(__uint_as_float(u.x & 0xffff0000u), a, acc[1]);
        acc[2] = fmaf(__uint_as_float(u.y << 16), a, acc[2]);
        acc[3] = fmaf(__uint_as_float(u.y & 0xffff0000u), a, acc[3]);
        acc[4] = fmaf(__uint_as_float(u.z << 16), a, acc[4]);
        acc[5] = fmaf(__uint_as_float(u.z & 0xffff0000u), a, acc[5]);
        acc[6] = fmaf(__uint_as_float(u.w << 16), a, acc[6]);
        acc[7] = fmaf(__uint_as_float(u.w & 0xffff0000u), a, acc[7]);
    };

    auto gather_chunk = [&](int cnt) {
        int j = hf;
        for (; j + 2 < cnt; j += 4) {
            int s0 = srcs[w][j], s1 = srcs[w][j + 2];
            float a0 = alds[w][j][hh], a1 = alds[w][j + 2][hh];
            uint4 u0 = *(const uint4*)&feat[(size_t)s0 * F1 + lh * 8];
            uint4 u1 = *(const uint4*)&feat[(size_t)s1 * F1 + lh * 8];
            fma8(u0, a0);
            fma8(u1, a1);
        }
        for (; j < cnt; j += 2) {
            int s0 = srcs[w][j];
            float a0 = alds[w][j][hh];
            uint4 u0 = *(const uint4*)&feat[(size_t)s0 * F1 + lh * 8];
            fma8(u0, a0);
        }
    };

    if (dg <= 64) {
        int s = 0;
        float4 e = { -FLT_MAX, -FLT_MAX, -FLT_MAX, -FLT_MAX };
        if (l < dg) {
            s = csr_src[start + l];
            float4 a = ((const float4*)als)[s];
            e.x = lrelu(a.x + ad4.x); e.y = lrelu(a.y + ad4.y);
            e.z = lrelu(a.z + ad4.z); e.w = lrelu(a.w + ad4.w);
        }
        float4 m = e;
        for (int off = 32; off; off >>= 1) {
            m.x = fmaxf(m.x, __shfl_xor(m.x, off));
            m.y = fmaxf(m.y, __shfl_xor(m.y, off));
            m.z = fmaxf(m.z, __shfl_xor(m.z, off));
            m.w = fmaxf(m.w, __shfl_xor(m.w, off));
        }
        float4 ex = { 0.f, 0.f, 0.f, 0.f };
        if (l < dg) {
            ex.x = expf(e.x - m.x); ex.y = expf(e.y - m.y);
            ex.z = expf(e.z - m.z); ex.w = expf(e.w - m.w);
        }
        float4 sum = ex;
        for (int off = 32; off; off >>= 1) {
            sum.x += __shfl_xor(sum.x, off);
            sum.y += __shfl_xor(sum.y, off);
            sum.z += __shfl_xor(sum.z, off);
            sum.w += __shfl_xor(sum.w, off);
        }
        float4 al = { ex.x / (sum.x + 1e-16f), ex.y / (sum.y + 1e-16f),
                      ex.z / (sum.z + 1e-16f), ex.w / (sum.w + 1e-16f) };
        *(float4*)&alds[w][l][0] = al;
        srcs[w][l] = s;
        __builtin_amdgcn_s_waitcnt(0);
        gather_chunk(dg);
    } else {
        float4 m = { -FLT_MAX, -FLT_MAX, -FLT_MAX, -FLT_MAX };
        for (int i = l; i < dg; i += 64) {
            int s = csr_src[start + i];
            float4 a = ((const float4*)als)[s];
            m.x = fmaxf(m.x, lrelu(a.x + ad4.x));
            m.y = fmaxf(m.y, lrelu(a.y + ad4.y));
            m.z = fmaxf(m.z, lrelu(a.z + ad4.z));
            m.w = fmaxf(m.w, lrelu(a.w + ad4.w));
        }
        for (int off = 32; off; off >>= 1) {
            m.x = fmaxf(m.x, __shfl_xor(m.x, off));
            m.y = fmaxf(m.y, __shfl_xor(m.y, off));
            m.z = fmaxf(m.z, __shfl_xor(m.z, off));
            m.w = fmaxf(m.w, __shfl_xor(m.w, off));
        }
        float4 sum = { 0.f, 0.f, 0.f, 0.f };
        for (int i = l; i < dg; i += 64) {
            int s = csr_src[start + i];
            float4 a = ((const float4*)als)[s];
            sum.x += expf(lrelu(a.x + ad4.x) - m.x);
            sum.y += expf(lrelu(a.y + ad4.y) - m.y);
            sum.z += expf(lrelu(a.z + ad4.z) - m.z);
            sum.w += expf(lrelu(a.w + ad4.w) - m.w);
        }
        for (int off = 32; off; off >>= 1) {
            sum.x += __shfl_xor(sum.x, off);
            sum.y += __shfl_xor(sum.y, off);
            sum.z += __shfl_xor(sum.z, off);
            sum.w += __shfl_xor(sum.w, off);
        }
        float4 inv = { 1.f / (sum.x + 1e-16f), 1.f / (sum.y + 1e-16f),
                       1.f / (sum.z + 1e-16f), 1.f / (sum.w + 1e-16f) };
        for (int c0 = start; c0 < end; c0 += 64) {
            int cnt = min(64, end - c0);
            if (l < cnt) {
                int s = csr_src[c0 + l];
                float4 a = ((const float4*)als)[s];
                float4 al = { expf(lrelu(a.x + ad4.x) - m.x) * inv.x,
                              expf(lrelu(a.y + ad4.y) - m.y) * inv.y,
                              expf(lrelu(a.z + ad4.z) - m.z) * inv.z,
                              expf(lrelu(a.w + ad4.w) - m.w) * inv.w };
                *(float4*)&alds[w][l][0] = al;
                srcs[w][l] = s;
            }
            __builtin_amdgcn_s_waitcnt(0);
            gather_chunk(cnt);
        }
    }

#pragma unroll
    for (int r = 0; r < 8; ++r) acc[r] += __shfl_xor(acc[r], 32);

    float4 bv0 = ((const float4*)bias)[lh * 2];
    float4 bv1 = ((const float4*)bias)[lh * 2 + 1];
    float v[8] = { acc[0] + bv0.x, acc[1] + bv0.y, acc[2] + bv0.z, acc[3] + bv0.w,
                   acc[4] + bv1.x, acc[5] + bv1.y, acc[6] + bv1.z, acc[7] + bv1.w };
    float sm = v[0] + v[1] + v[2] + v[3] + v[4] + v[5] + v[6] + v[7];
    for (int off = 32; off; off >>= 1) sm += __shfl_xor(sm, off);
    float mu = sm * (1.f / (2 * F1));
    float dv = 0.f;
#pragma unroll
    for (int r = 0; r < 8; ++r) { float d = v[r] - mu; dv += d * d; }
    for (int off = 32; off; off >>= 1) dv += __shfl_xor(dv, off);
    float rstd = rsqrtf(dv * (1.f / (2 * F1)) + LN_EPS);
    float4 gv0 = ((const float4*)g)[lh * 2],   gv1 = ((const float4*)g)[lh * 2 + 1];
    float4 lb0 = ((const float4*)bln)[lh * 2], lb1 = ((const float4*)bln)[lh * 2 + 1];
    float y[8];
    y[0] = (v[0] - mu) * rstd * gv0.x + lb0.x;
    y[1] = (v[1] - mu) * rstd * gv0.y + lb0.y;
    y[2] = (v[2] - mu) * rstd * gv0.z + lb0.z;
    y[3] = (v[3] - mu) * rstd * gv0.w + lb0.w;
    y[4] = (v[4] - mu) * rstd * gv1.x + lb1.x;
    y[5] = (v[5] - mu) * rstd * gv1.y + lb1.y;
    y[6] = (v[6] - mu) * rstd * gv1.z + lb1.z;
    y[7] = (v[7] - mu) * rstd * gv1.w + lb1.w;
    if (RES) {
        uint4 rr = ((const uint4*)res)[(size_t)n * 32 + lh];
        y[0] += __uint_as_float(rr.x << 16);
        y[1] += __uint_as_float(rr.x & 0xffff0000u);
        y[2] += __uint_as_float(rr.y << 16);
        y[3] += __uint_as_float(rr.y & 0xffff0000u);
        y[4] += __uint_as_float(rr.z << 16);
        y[5] += __uint_as_float(rr.z & 0xffff0000u);
        y[6] += __uint_as_float(rr.w << 16);
        y[7] += __uint_as_float(rr.w & 0xffff0000u);
    }
#pragma unroll
    for (int r = 0; r < 8; ++r) y[r] = y[r] > 0.f ? y[r] : expm1f(y[r]);

    if (!FEAT2) {
        if (l < 32) {
            uint4 o;
            o.x = (uint)f2b(y[0]) | ((uint)f2b(y[1]) << 16);
            o.y = (uint)f2b(y[2]) | ((uint)f2b(y[3]) << 16);
            o.z = (uint)f2b(y[4]) | ((uint)f2b(y[5]) << 16);
            o.w = (uint)f2b(y[6]) | ((uint)f2b(y[7]) << 16);
            ((uint4*)out_bf)[(size_t)n * 32 + lh] = o;
        }
    } else {
        const float4* W24 = (const float4*)W2;
        float c0 = 0.f, c1 = 0.f;
#pragma unroll
        for (int j = 0; j < 4; ++j) {
            float4 wv = W24[lh * 4 + j];
            c0 += y[2 * j] * wv.x + y[2 * j + 1] * wv.z;
            c1 += y[2 * j] * wv.y + y[2 * j + 1] * wv.w;
        }
        for (int off = 32; off; off >>= 1) {
            c0 += __shfl_xor(c0, off);
            c1 += __shfl_xor(c1, off);
        }
        c0 *= 0.5f; c1 *= 0.5f;
        if (l == 0) {
            float4 o = { c0, c1,
                         c0 * as2[0] + c1 * as2[1],
                         c0 * ad2[0] + c1 * ad2[1] };
            nf2[n] = o;
        }
    }
}

// ---- layer 2 fully fused ----
__global__ __launch_bounds__(256) void layer2_fused(const int* __restrict__ csr_src,
                                                    const int* __restrict__ rend,
                                                    const int* __restrict__ deg_,
                                                    const float4* __restrict__ nf2,
                                                    const float* __restrict__ b2,
                                                    float* __restrict__ out, int N) {
    const int w = threadIdx.x >> 6, l = threadIdx.x & 63;
    const int n = blockIdx.x * 4 + w;
    if (n >= N) return;
    const int dg = deg_[n], end = rend[n], start = end - dg;
    const float ad = nf2[n].w;

    float a0 = 0.f, a1 = 0.f;
    if (dg <= 64) {
        float e = -FLT_MAX;
        float f0 = 0.f, f1 = 0.f;
        if (l < dg) {
            int s = csr_src[start + l];
            float4 v = nf2[s];
            e = lrelu(v.z + ad);
            f0 = v.x; f1 = v.y;
        }
        float m = e;
        for (int off = 32; off; off >>= 1) m = fmaxf(m, __shfl_xor(m, off));
        float ex = (l < dg) ? expf(e - m) : 0.f;
        float sum = ex;
        for (int off = 32; off; off >>= 1) sum += __shfl_xor(sum, off);
        float al = ex / (sum + 1e-16f);
        a0 = f0 * al; a1 = f1 * al;
    } else {
        float m = -FLT_MAX;
        for (int i = l; i < dg; i += 64) {
            int s = csr_src[start + i];
            m = fmaxf(m, lrelu(nf2[s].z + ad));
        }
        for (int off = 32; off; off >>= 1) m = fmaxf(m, __shfl_xor(m, off));
        float sum = 0.f;
        for (int i = l; i < dg; i += 64) {
            int s = csr_src[start + i];
            sum += expf(lrelu(nf2[s].z + ad) - m);
        }
        for (int off = 32; off; off >>= 1) sum += __shfl_xor(sum, off);
        float inv = 1.f / (sum + 1e-16f);
        for (int i = l; i < dg; i += 64) {
            int s = csr_src[start + i];
            float4 v = nf2[s];
            float al = expf(lrelu(v.z + ad) - m) * inv;
            a0 = fmaf(v.x, al, a0);
            a1 = fmaf(v.y, al, a1);
        }
    }
    for (int off = 32; off; off >>= 1) {
        a0 += __shfl_xor(a0, off);
        a1 += __shfl_xor(a1, off);
    }
    if (l == 0) {
        out[(size_t)n * 2 + 0] = a0 + b2[0];
        out[(size_t)n * 2 + 1] = a1 + b2[1];
    }
}

extern "C" void kernel_launch(void* const* d_in, const int* in_sizes, int n_in,
                              void* d_out, int out_size, void* d_ws, size_t ws_size,
                              hipStream_t stream) {
    const float* x    = (const float*)d_in[0];
    const int*   ei   = (const int*)d_in[1];
    const float* Wp   = (const float*)d_in[2];
    const float* bp   = (const float*)d_in[3];
    const float* W0   = (const float*)d_in[4];
    const float* as0  = (const float*)d_in[5];
    const float* ad0  = (const float*)d_in[6];
    const float* b0   = (const float*)d_in[7];
    const float* W1   = (const float*)d_in[8];
    const float* as1  = (const float*)d_in[9];
    const float* ad1  = (const float*)d_in[10];
    const float* b1   = (const float*)d_in[11];
    const float* W2   = (const float*)d_in[12];
    const float* as2  = (const float*)d_in[13];
    const float* ad2  = (const float*)d_in[14];
    const float* b2   = (const float*)d_in[15];
    const float* ln_g = (const float*)d_in[16];
    const float* ln_b = (const float*)d_in[17];
    float* out = (float*)d_out;

    const int N    = in_sizes[0] / IN_DIM;   // 50000
    const int E    = in_sizes[1] / 2;        // 800000
    const int Etot = E + N;

    char* wptr = (char*)d_ws;
    auto alloc = [&](size_t bytes) -> void* {
        void* p = wptr;
        wptr += (bytes + 255) & ~(size_t)255;
        return p;
    };
    ushort* F      = (ushort*)alloc(sizeof(ushort) * (size_t)N * F1);
    ushort* Ab     = (ushort*)alloc(sizeof(ushort) * (size_t)N * F1);
    float*  als    = (float*)alloc(sizeof(float) * (size_t)N * HEADS);
    float*  ald    = (float*)alloc(sizeof(float) * (size_t)N * HEADS);
    float4* nf2    = (float4*)alloc(sizeof(float4) * (size_t)N);
    ushort* Wf0    = (ushort*)alloc(sizeof(ushort) * (size_t)F1 * KP);   // frag layout
    float*  bc     = (float*)alloc(sizeof(float) * F1);
    ushort* Wf1    = (ushort*)alloc(sizeof(ushort) * (size_t)F1 * F1);   // frag layout
    int*    deg    = (int*)alloc(sizeof(int) * (size_t)N);
    int*    rend   = (int*)alloc(sizeof(int) * (size_t)N);
    int*    wcur   = (int*)alloc(sizeof(int) * (size_t)N);
    int*    csum   = (int*)alloc(sizeof(int) * 256);
    int*    csrs   = (int*)alloc(sizeof(int) * (size_t)Etot);

    const int eb   = (Etot + 255) / 256;
    const int nb   = (N + 255) / 256;
    const int nb4  = (N + 3) / 4;
    const int nchunks = (N + 1023) / 1024;
    const int mb64 = (N + 63) / 64;

    // -------- CSR build --------
    hipMemsetAsync(deg, 0, sizeof(int) * (size_t)N, stream);
    csr_count<<<eb, 256, 0, stream>>>(ei, E, Etot, deg);
    scan1<<<nchunks, 256, 0, stream>>>(deg, rend, csum, N);
    scan2<<<1, 256, 0, stream>>>(csum, nchunks);
    scan3<<<nb, 256, 0, stream>>>(deg, rend, csum, wcur, N);
    csr_fill<<<eb, 256, 0, stream>>>(ei, E, Etot, wcur, csrs);

    // -------- weight prep (frag layout) --------
    combine_w_frag<<<KP, 256, 0, stream>>>(Wp, W0, bp, Wf0, bc);
    cvt_frag<<<F1, 256, 0, stream>>>(W1, Wf1);

    // ================= layer 0 (proj fused in) =================
    mfma_gemm2<KP / 32, true><<<mb64, 256, 0, stream>>>(
        x, Wf0, bc, as0, ad0, F, als, ald, N);
    aggregate_fused<false, false><<<nb4, 256, 0, stream>>>(csrs, rend, deg, F,
        als, ald, b0, ln_g, ln_b, nullptr, Ab, nullptr, nullptr, nullptr, nullptr, N);

    // ================= layer 1 =================
    mfma_gemm2<F1 / 32, false><<<mb64, 256, 0, stream>>>(
        Ab, Wf1, nullptr, as1, ad1, F, als, ald, N);
    aggregate_fused<true, true><<<nb4, 256, 0, stream>>>(csrs, rend, deg, F,
        als, ald, b1, ln_g, ln_b, Ab, nullptr, W2, as2, ad2, nf2, N);

    // ================= layer 2 =================
    layer2_fused<<<nb4, 256, 0, stream>>>(csrs, rend, deg, nf2, b2, out, N);
}